// Round 9
// baseline (697.989 us; speedup 1.0000x reference)
//
#include <hip/hip_runtime.h>
#include <stdint.h>

#define HH 112
#define WW 112
#define CC 512
#define BB 4
#define LLEN (HH*WW)
#define NTOK (BB*LLEN)   // 50176
#define NHEADS 8
#define HD 64
#define HIDDEN 2048

typedef __bf16 bf16x8 __attribute__((ext_vector_type(8)));
typedef float f32x4 __attribute__((ext_vector_type(4)));
typedef long i64;

__device__ __forceinline__ unsigned short f2bf(float x) {
  uint32_t u = __float_as_uint(x);
  u += 0x7fffu + ((u >> 16) & 1u);
  return (unsigned short)(u >> 16);
}
__device__ __forceinline__ float bf2f(unsigned short h) {
  return __uint_as_float((uint32_t)h << 16);
}
// pack 4 f32 -> 4 fp8 e4m3 (OCP on gfx950) in one int
__device__ __forceinline__ int cvt4_fp8(float a, float b, float c, float d) {
  int r = 0;
  r = __builtin_amdgcn_cvt_pk_fp8_f32(a, b, r, false);
  r = __builtin_amdgcn_cvt_pk_fp8_f32(c, d, r, true);
  return r;
}

// async global->LDS, 16B per lane; lds dest must be wave-uniform base
__device__ __forceinline__ void gload16(const void* gptr, void* lptr) {
  __builtin_amdgcn_global_load_lds(
      (const __attribute__((address_space(1))) void*)gptr,
      (__attribute__((address_space(3))) void*)lptr,
      16, 0, 0);
}

#define WAITV3() asm volatile("s_waitcnt vmcnt(3)" ::: "memory")
#define WAITV0() asm volatile("s_waitcnt vmcnt(0)" ::: "memory")
#define BAR() __builtin_amdgcn_s_barrier()
#define WAITL() do { asm volatile("s_waitcnt lgkmcnt(0)" ::: "memory"); \
                     __builtin_amdgcn_sched_barrier(0); } while (0)

// ---------------- weight transpose (K,N) f32 -> (N,K) bf16 ----------------
__global__ __launch_bounds__(256) void wtranspose_kernel(
    const float* __restrict__ w, unsigned short* __restrict__ wt, int K, int N) {
  int idx = blockIdx.x * 256 + threadIdx.x;
  if (idx >= K * N) return;
  int k = idx / N, n = idx - k * N;
  wt[(size_t)n * K + k] = f2bf(w[idx]);
}

// ---------------- weight transpose (K,N) f32 -> (N,K) fp8, scaled x32 --------
__global__ __launch_bounds__(256) void wtranspose8_kernel(
    const float* __restrict__ w, unsigned char* __restrict__ wt, int K, int N) {
  int idx = blockIdx.x * 256 + threadIdx.x;   // index over OUTPUT (coalesced)
  if (idx >= K * N) return;
  int n = idx / K, k = idx - n * K;
  float v = w[(size_t)k * N + n] * 32.f;
  int r = __builtin_amdgcn_cvt_pk_fp8_f32(v, v, 0, false);
  wt[idx] = (unsigned char)r;
}

// ---------------- depthwise 3x3 conv + bias + residual ----------------
__global__ __launch_bounds__(256) void cpe_kernel(
    const float* __restrict__ x, const float* __restrict__ w,
    const float* __restrict__ bias, float* __restrict__ out) {
  int tid = blockIdx.x * 256 + threadIdx.x;
  int c = (tid & 127) << 2;      // channel chunk of 4
  int pix = tid >> 7;
  int xx = pix % WW; int t2 = pix / WW; int yy = t2 % HH; int bb = t2 / HH;
  float4 bv = *(const float4*)(&bias[c]);
  float ax = bv.x, ay = bv.y, az = bv.z, aw = bv.w;
  #pragma unroll
  for (int ky = 0; ky < 3; ky++) {
    int y = yy + ky - 1;
    if ((unsigned)y >= (unsigned)HH) continue;
    #pragma unroll
    for (int kx = 0; kx < 3; kx++) {
      int x2 = xx + kx - 1;
      if ((unsigned)x2 >= (unsigned)WW) continue;
      const float4 v = *(const float4*)(&x[(((size_t)bb * HH + y) * WW + x2) * CC + c]);
      const float4 wv = *(const float4*)(&w[(ky * 3 + kx) * CC + c]);
      ax = fmaf(v.x, wv.x, ax); ay = fmaf(v.y, wv.y, ay);
      az = fmaf(v.z, wv.z, az); aw = fmaf(v.w, wv.w, aw);
    }
  }
  size_t o = (size_t)pix * CC + c;
  const float4 xv = *(const float4*)(&x[o]);
  float4 r; r.x = xv.x + ax; r.y = xv.y + ay; r.z = xv.z + az; r.w = xv.w + aw;
  *(float4*)(&out[o]) = r;
}

// ---------------- LayerNorm (C=512), one wave per token ----------------
template <int OUT8>
__global__ __launch_bounds__(256) void ln_kernel(
    const float* __restrict__ in, const float* __restrict__ g,
    const float* __restrict__ b, unsigned short* __restrict__ out,
    unsigned char* __restrict__ out8) {
  int token = (blockIdx.x * 256 + threadIdx.x) >> 6;
  int lane = threadIdx.x & 63;
  const float* row = in + (size_t)token * CC;
  float4 v0 = *(const float4*)(row + lane * 8);
  float4 v1 = *(const float4*)(row + lane * 8 + 4);
  float s = v0.x + v0.y + v0.z + v0.w + v1.x + v1.y + v1.z + v1.w;
  float ss = v0.x*v0.x + v0.y*v0.y + v0.z*v0.z + v0.w*v0.w
           + v1.x*v1.x + v1.y*v1.y + v1.z*v1.z + v1.w*v1.w;
  #pragma unroll
  for (int o = 32; o; o >>= 1) { s += __shfl_xor(s, o, 64); ss += __shfl_xor(ss, o, 64); }
  float mu = s * (1.f / CC);
  float var = ss * (1.f / CC) - mu * mu;
  float rs = rsqrtf(var + 1e-5f);
  float4 g0 = *(const float4*)(&g[lane * 8]);
  float4 g1 = *(const float4*)(&g[lane * 8 + 4]);
  float4 b0 = *(const float4*)(&b[lane * 8]);
  float4 b1 = *(const float4*)(&b[lane * 8 + 4]);
  float o8[8];
  o8[0] = (v0.x - mu) * rs * g0.x + b0.x;
  o8[1] = (v0.y - mu) * rs * g0.y + b0.y;
  o8[2] = (v0.z - mu) * rs * g0.z + b0.z;
  o8[3] = (v0.w - mu) * rs * g0.w + b0.w;
  o8[4] = (v1.x - mu) * rs * g1.x + b1.x;
  o8[5] = (v1.y - mu) * rs * g1.y + b1.y;
  o8[6] = (v1.z - mu) * rs * g1.z + b1.z;
  o8[7] = (v1.w - mu) * rs * g1.w + b1.w;
  if (OUT8) {
    uint2 pk;
    pk.x = (uint32_t)cvt4_fp8(o8[0], o8[1], o8[2], o8[3]);
    pk.y = (uint32_t)cvt4_fp8(o8[4], o8[5], o8[6], o8[7]);
    *(uint2*)(&out8[(size_t)token * CC + lane * 8]) = pk;
  } else {
    uint4 pk;
    pk.x = (uint32_t)f2bf(o8[0]) | ((uint32_t)f2bf(o8[1]) << 16);
    pk.y = (uint32_t)f2bf(o8[2]) | ((uint32_t)f2bf(o8[3]) << 16);
    pk.z = (uint32_t)f2bf(o8[4]) | ((uint32_t)f2bf(o8[5]) << 16);
    pk.w = (uint32_t)f2bf(o8[6]) | ((uint32_t)f2bf(o8[7]) << 16);
    *(uint4*)(&out[(size_t)token * CC + lane * 8]) = pk;
  }
}

// ---- bf16 MFMA GEMM: 2-buf (48KB, 3 blk/CU), post-barrier restage, vmcnt(3) ----
// MODE 0: out bf16 = C + bias; MODE 1: out f32 = C+bias+res; MODE 2: bf16 gelu
#define BM 256
#define BN 128
#define BK 32

template <int MODE>
__global__ __launch_bounds__(512) void gemm_kernel(
    const unsigned short* __restrict__ A, const unsigned short* __restrict__ BT,
    const float* __restrict__ bias, const float* __restrict__ res,
    float* __restrict__ outF, unsigned short* __restrict__ outB,
    int M, int N, int K) {
  __shared__ unsigned char ldsb[49152];   // A bufs @0,16K ; B bufs @32K,40K
  int nwg = gridDim.x * gridDim.y;
  int flat = blockIdx.y * gridDim.x + blockIdx.x;
  int swz = (flat & 7) * (nwg >> 3) + (flat >> 3);
  int bx = swz % gridDim.x, by = swz / gridDim.x;
  const int bm = by * BM, bn = bx * BN;
  const int t = threadIdx.x;
  const int wid = t >> 6, lane = t & 63;
  const int wr = wid >> 1, wc = wid & 1;        // 4x2 wave grid
  const int lr = lane & 15;
  const int lk = (((lane >> 4) ^ ((lane >> 1) & 3)) & 3) * 8;
  const int srow = t >> 2;
  const int scol = (((t & 3) ^ ((t >> 3) & 3)) & 3) * 8;
  const size_t arow0 = (size_t)(bm + srow) * K + scol;
  const size_t arow1 = (size_t)(bm + 128 + srow) * K + scol;
  const size_t brow  = (size_t)(bn + srow) * K + scol;
  const int ldso = wid * 1024;   // byte offset within a buf

#define STG(b, kt) do { \
    gload16(&A[arow0 + (kt)], ldsb + (b) * 16384 + ldso); \
    gload16(&A[arow1 + (kt)], ldsb + (b) * 16384 + 8192 + ldso); \
    gload16(&BT[brow + (kt)], ldsb + 32768 + (b) * 8192 + ldso); } while (0)

  f32x4 acc[4][4] = {};
  const int nt = K / BK;

  STG(0, 0);
  STG(1, BK);

  for (int tile = 0; tile < nt - 1; ++tile) {
    WAITV3(); BAR();
    const unsigned short* as = (const unsigned short*)(ldsb + (tile & 1) * 16384);
    const unsigned short* bs = (const unsigned short*)(ldsb + 32768 + (tile & 1) * 8192);
    bf16x8 af[4], bfr[4];
    #pragma unroll
    for (int i = 0; i < 4; i++)
      af[i] = *(const bf16x8*)(&as[(wr * 64 + i * 16 + lr) * BK + lk]);
    #pragma unroll
    for (int j = 0; j < 4; j++)
      bfr[j] = *(const bf16x8*)(&bs[(wc * 64 + j * 16 + lr) * BK + lk]);
    WAITL();
    BAR();   // all waves done reading buf (tile&1) -> safe to restage it
    if (tile + 2 < nt) STG(tile & 1, (tile + 2) * BK);
    __builtin_amdgcn_s_setprio(1);
    #pragma unroll
    for (int i = 0; i < 4; i++)
      #pragma unroll
      for (int j = 0; j < 4; j++)
        acc[i][j] = __builtin_amdgcn_mfma_f32_16x16x32_bf16(af[i], bfr[j], acc[i][j], 0, 0, 0);
    __builtin_amdgcn_s_setprio(0);
  }
  {
    WAITV0(); BAR();
    const unsigned short* as = (const unsigned short*)(ldsb + ((nt - 1) & 1) * 16384);
    const unsigned short* bs = (const unsigned short*)(ldsb + 32768 + ((nt - 1) & 1) * 8192);
    bf16x8 af[4], bfr[4];
    #pragma unroll
    for (int i = 0; i < 4; i++)
      af[i] = *(const bf16x8*)(&as[(wr * 64 + i * 16 + lr) * BK + lk]);
    #pragma unroll
    for (int j = 0; j < 4; j++)
      bfr[j] = *(const bf16x8*)(&bs[(wc * 64 + j * 16 + lr) * BK + lk]);
    WAITL();
    #pragma unroll
    for (int i = 0; i < 4; i++)
      #pragma unroll
      for (int j = 0; j < 4; j++)
        acc[i][j] = __builtin_amdgcn_mfma_f32_16x16x32_bf16(af[i], bfr[j], acc[i][j], 0, 0, 0);
  }
#undef STG

  // ---- epilogue: restage acc via LDS -> coalesced vector stores ----
  {
    float* eps = (float*)ldsb;                // 64*132*4 = 33.8KB < 48KB
    const int erow = t >> 3;
    const int ecol0 = (t & 7) * 16;
    const int wrow = wr * 16 + (lane >> 4) * 4;
    const int wcol = wc * 64 + lr;
    const int gr_base = bm + (erow >> 4) * 64 + (erow & 15);
    const int gc0 = bn + ecol0;
    float bv[16];
    #pragma unroll
    for (int c4 = 0; c4 < 4; c4++)
      *(float4*)&bv[c4 * 4] = *(const float4*)&bias[gc0 + c4 * 4];
    #pragma unroll
    for (int i = 0; i < 4; i++) {
      __syncthreads();
      #pragma unroll
      for (int j = 0; j < 4; j++)
        #pragma unroll
        for (int r = 0; r < 4; r++)
          eps[(wrow + r) * 132 + wcol + j * 16] = acc[i][j][r];
      __syncthreads();
      float vv[16];
      #pragma unroll
      for (int c4 = 0; c4 < 4; c4++)
        *(float4*)&vv[c4 * 4] = *(const float4*)&eps[erow * 132 + ecol0 + c4 * 4];
      const size_t off = (size_t)(gr_base + i * 16) * N + gc0;
      if (MODE == 1) {
        #pragma unroll
        for (int c4 = 0; c4 < 4; c4++) {
          float4 rv = *(const float4*)&res[off + c4 * 4];
          float4 ov;
          ov.x = vv[c4*4+0] + bv[c4*4+0] + rv.x;
          ov.y = vv[c4*4+1] + bv[c4*4+1] + rv.y;
          ov.z = vv[c4*4+2] + bv[c4*4+2] + rv.z;
          ov.w = vv[c4*4+3] + bv[c4*4+3] + rv.w;
          *(float4*)&outF[off + c4 * 4] = ov;
        }
      } else {
        unsigned short ob[16];
        #pragma unroll
        for (int c = 0; c < 16; c++) {
          float v = vv[c] + bv[c];
          if (MODE == 2) {
            float a2 = v * v;
            float w = v * fmaf(a2, -0.1029436f, -2.3024849f);
            float sg = __builtin_amdgcn_rcpf(1.f + __builtin_amdgcn_exp2f(w));
            v = v * sg;
          }
          ob[c] = f2bf(v);
        }
        *(uint4*)&outB[off]     = *(uint4*)&ob[0];
        *(uint4*)&outB[off + 8] = *(uint4*)&ob[8];
      }
    }
  }
}

// ==== fp8 e4m3 MFMA GEMM (MLP): 2-buf (48KB, 3 blk/CU), same ledger, BK=64 ====
#define BK8 64

template <int MODE>
__global__ __launch_bounds__(512) void gemm8_kernel(
    const unsigned char* __restrict__ A, const unsigned char* __restrict__ BT,
    const float* __restrict__ bias, const float* __restrict__ res,
    float* __restrict__ outF, unsigned char* __restrict__ outB8,
    int M, int N, int K) {
  __shared__ unsigned char ldsb[49152];   // A bufs @0,16K ; B bufs @32K,40K
  int nwg = gridDim.x * gridDim.y;
  int flat = blockIdx.y * gridDim.x + blockIdx.x;
  int swz = (flat & 7) * (nwg >> 3) + (flat >> 3);
  int bx = swz % gridDim.x, by = swz / gridDim.x;
  const int bm = by * BM, bn = bx * BN;
  const int t = threadIdx.x;
  const int wid = t >> 6, lane = t & 63;
  const int wr = wid >> 1, wc = wid & 1;
  const int lr = lane & 15, g = lane >> 4;
  const int swr = (lr >> 1) & 3;
  const int rb0 = (((g >> 1)      ) ^ swr) * 16 + (g & 1) * 8;   // ks=0
  const int rb1 = (((g >> 1) + 2) ^ swr) * 16 + (g & 1) * 8;     // ks=1
  const int srow = t >> 2;
  const int scol = (((t & 3) ^ ((t >> 3) & 3)) & 3) * 16;
  const size_t arow0 = (size_t)(bm + srow) * K + scol;
  const size_t arow1 = (size_t)(bm + 128 + srow) * K + scol;
  const size_t brow  = (size_t)(bn + srow) * K + scol;
  const int ldso = wid * 1024;

#define STG8(b, kt) do { \
    gload16(&A[arow0 + (kt)], ldsb + (b) * 16384 + ldso); \
    gload16(&A[arow1 + (kt)], ldsb + (b) * 16384 + 8192 + ldso); \
    gload16(&BT[brow + (kt)], ldsb + 32768 + (b) * 8192 + ldso); } while (0)

  f32x4 acc[4][4] = {};
  const int nt = K / BK8;

  STG8(0, 0);
  STG8(1, BK8);

  for (int tile = 0; tile < nt - 1; ++tile) {
    WAITV3(); BAR();
    const unsigned char* as = ldsb + (tile & 1) * 16384;
    const unsigned char* bs = ldsb + 32768 + (tile & 1) * 8192;
    i64 af0[4], af1[4], bf0[4], bf1[4];
    #pragma unroll
    for (int i = 0; i < 4; i++) {
      const unsigned char* p = &as[(wr * 64 + i * 16 + lr) * BK8];
      af0[i] = *(const i64*)(p + rb0);
      af1[i] = *(const i64*)(p + rb1);
    }
    #pragma unroll
    for (int j = 0; j < 4; j++) {
      const unsigned char* p = &bs[(wc * 64 + j * 16 + lr) * BK8];
      bf0[j] = *(const i64*)(p + rb0);
      bf1[j] = *(const i64*)(p + rb1);
    }
    WAITL();
    BAR();
    if (tile + 2 < nt) STG8(tile & 1, (tile + 2) * BK8);
    __builtin_amdgcn_s_setprio(1);
    #pragma unroll
    for (int i = 0; i < 4; i++)
      #pragma unroll
      for (int j = 0; j < 4; j++) {
        acc[i][j] = __builtin_amdgcn_mfma_f32_16x16x32_fp8_fp8(af0[i], bf0[j], acc[i][j], 0, 0, 0);
        acc[i][j] = __builtin_amdgcn_mfma_f32_16x16x32_fp8_fp8(af1[i], bf1[j], acc[i][j], 0, 0, 0);
      }
    __builtin_amdgcn_s_setprio(0);
  }
  {
    WAITV0(); BAR();
    const unsigned char* as = ldsb + ((nt - 1) & 1) * 16384;
    const unsigned char* bs = ldsb + 32768 + ((nt - 1) & 1) * 8192;
    i64 af0[4], af1[4], bf0[4], bf1[4];
    #pragma unroll
    for (int i = 0; i < 4; i++) {
      const unsigned char* p = &as[(wr * 64 + i * 16 + lr) * BK8];
      af0[i] = *(const i64*)(p + rb0);
      af1[i] = *(const i64*)(p + rb1);
    }
    #pragma unroll
    for (int j = 0; j < 4; j++) {
      const unsigned char* p = &bs[(wc * 64 + j * 16 + lr) * BK8];
      bf0[j] = *(const i64*)(p + rb0);
      bf1[j] = *(const i64*)(p + rb1);
    }
    WAITL();
    #pragma unroll
    for (int i = 0; i < 4; i++)
      #pragma unroll
      for (int j = 0; j < 4; j++) {
        acc[i][j] = __builtin_amdgcn_mfma_f32_16x16x32_fp8_fp8(af0[i], bf0[j], acc[i][j], 0, 0, 0);
        acc[i][j] = __builtin_amdgcn_mfma_f32_16x16x32_fp8_fp8(af1[i], bf1[j], acc[i][j], 0, 0, 0);
      }
  }
#undef STG8

  // ---- epilogue (restaged, vectorized), acc scaled by 1/32 ----
  {
    const float SC = 0.03125f;
    float* eps = (float*)ldsb;
    const int erow = t >> 3;
    const int ecol0 = (t & 7) * 16;
    const int wrow = wr * 16 + (lane >> 4) * 4;
    const int wcol = wc * 64 + lr;
    const int gr_base = bm + (erow >> 4) * 64 + (erow & 15);
    const int gc0 = bn + ecol0;
    float bv[16];
    #pragma unroll
    for (int c4 = 0; c4 < 4; c4++)
      *(float4*)&bv[c4 * 4] = *(const float4*)&bias[gc0 + c4 * 4];
    #pragma unroll
    for (int i = 0; i < 4; i++) {
      __syncthreads();
      #pragma unroll
      for (int j = 0; j < 4; j++)
        #pragma unroll
        for (int r = 0; r < 4; r++)
          eps[(wrow + r) * 132 + wcol + j * 16] = acc[i][j][r];
      __syncthreads();
      float vv[16];
      #pragma unroll
      for (int c4 = 0; c4 < 4; c4++)
        *(float4*)&vv[c4 * 4] = *(const float4*)&eps[erow * 132 + ecol0 + c4 * 4];
      const size_t off = (size_t)(gr_base + i * 16) * N + gc0;
      if (MODE == 1) {
        #pragma unroll
        for (int c4 = 0; c4 < 4; c4++) {
          float4 rv = *(const float4*)&res[off + c4 * 4];
          float4 ov;
          ov.x = vv[c4*4+0] * SC + bv[c4*4+0] + rv.x;
          ov.y = vv[c4*4+1] * SC + bv[c4*4+1] + rv.y;
          ov.z = vv[c4*4+2] * SC + bv[c4*4+2] + rv.z;
          ov.w = vv[c4*4+3] * SC + bv[c4*4+3] + rv.w;
          *(float4*)&outF[off + c4 * 4] = ov;
        }
      } else {
        float gv[16];
        #pragma unroll
        for (int c = 0; c < 16; c++) {
          float v = vv[c] * SC + bv[c];
          float a2 = v * v;
          float w = v * fmaf(a2, -0.1029436f, -2.3024849f);
          float sg = __builtin_amdgcn_rcpf(1.f + __builtin_amdgcn_exp2f(w));
          gv[c] = v * sg;
        }
        uint4 pk;
        pk.x = (uint32_t)cvt4_fp8(gv[0],  gv[1],  gv[2],  gv[3]);
        pk.y = (uint32_t)cvt4_fp8(gv[4],  gv[5],  gv[6],  gv[7]);
        pk.z = (uint32_t)cvt4_fp8(gv[8],  gv[9],  gv[10], gv[11]);
        pk.w = (uint32_t)cvt4_fp8(gv[12], gv[13], gv[14], gv[15]);
        *(uint4*)&outB8[off] = pk;
      }
    }
  }
}

// ---------------- MFMA window attention: 1 wave per (window, head) ----------------
#define WNS 68

__global__ __launch_bounds__(64) void attn_mfma_kernel(
    const unsigned short* __restrict__ qkv, unsigned short* __restrict__ out) {
  __shared__ unsigned short VT[64 * WNS];   // V^T: [d][k]
  __shared__ unsigned short Ps[64 * WNS];   // P:   [q][k]
  const int task = blockIdx.x;
  const int win = task >> 3, h = task & 7;
  const int b = win >> 8, wy = (win >> 4) & 15, wx = win & 15;
  const int lane = threadIdx.x;
  const int lr = lane & 15, g = lane >> 4;

  auto tokof = [&](int r) {
    int rr = r > 48 ? 48 : r;
    int y = rr / 7, x2 = rr - y * 7;
    return (size_t)(b * LLEN + (wy * 7 + y) * WW + wx * 7 + x2);
  };

  {
    size_t vbase = tokof(lane) * 1536 + h * 64 + 1024;
    bool valid = lane <= 48;
    #pragma unroll
    for (int c = 0; c < 8; c++) {
      uint4 v = *(const uint4*)(&qkv[vbase + c * 8]);
      const unsigned short* pv = (const unsigned short*)&v;
      #pragma unroll
      for (int e = 0; e < 8; e++)
        VT[(c * 8 + e) * WNS + lane] = valid ? pv[e] : (unsigned short)0;
    }
  }

  size_t tok[4];
  #pragma unroll
  for (int i2 = 0; i2 < 4; i2++) tok[i2] = tokof(i2 * 16 + lr);
  bf16x8 Qf[4][2], Kf[4][2];
  #pragma unroll
  for (int i2 = 0; i2 < 4; i2++) {
    size_t base = tok[i2] * 1536 + h * 64 + g * 8;
    #pragma unroll
    for (int ks = 0; ks < 2; ks++) {
      Qf[i2][ks] = *(const bf16x8*)(&qkv[base + ks * 32]);
      Kf[i2][ks] = *(const bf16x8*)(&qkv[base + 512 + ks * 32]);
    }
  }

  f32x4 acc[4][4] = {};
  #pragma unroll
  for (int ks = 0; ks < 2; ks++)
    #pragma unroll
    for (int i2 = 0; i2 < 4; i2++)
      #pragma unroll
      for (int j = 0; j < 4; j++)
        acc[i2][j] = __builtin_amdgcn_mfma_f32_16x16x32_bf16(Kf[i2][ks], Qf[j][ks], acc[i2][j], 0, 0, 0);

  #pragma unroll
  for (int j = 0; j < 4; j++) {
    float mx = -1e30f;
    #pragma unroll
    for (int i2 = 0; i2 < 4; i2++)
      #pragma unroll
      for (int r = 0; r < 4; r++) {
        int k = 16 * i2 + 4 * g + r;
        mx = fmaxf(mx, (k <= 48) ? acc[i2][j][r] : -1e30f);
      }
    mx = fmaxf(mx, __shfl_xor(mx, 16, 64));
    mx = fmaxf(mx, __shfl_xor(mx, 32, 64));
    float p[4][4];
    float sum = 0.f;
    #pragma unroll
    for (int i2 = 0; i2 < 4; i2++)
      #pragma unroll
      for (int r = 0; r < 4; r++) {
        int k = 16 * i2 + 4 * g + r;
        float e = (k <= 48) ? __expf(0.125f * (acc[i2][j][r] - mx)) : 0.f;
        p[i2][r] = e; sum += e;
      }
    sum += __shfl_xor(sum, 16, 64);
    sum += __shfl_xor(sum, 32, 64);
    float inv = 1.f / sum;
    int q = 16 * j + lr;
    #pragma unroll
    for (int i2 = 0; i2 < 4; i2++) {
      uint2 w;
      w.x = (uint32_t)f2bf(p[i2][0] * inv) | ((uint32_t)f2bf(p[i2][1] * inv) << 16);
      w.y = (uint32_t)f2bf(p[i2][2] * inv) | ((uint32_t)f2bf(p[i2][3] * inv) << 16);
      *(uint2*)(&Ps[q * WNS + 16 * i2 + 4 * g]) = w;
    }
  }

  __syncthreads();

  f32x4 o[4][4] = {};
  #pragma unroll
  for (int ks = 0; ks < 2; ks++) {
    bf16x8 Pf[4], Vf[4];
    #pragma unroll
    for (int i2 = 0; i2 < 4; i2++) {
      int base = (16 * i2 + lr) * WNS + ks * 32 + g * 8;
      uint2 lo = *(const uint2*)(&Ps[base]);
      uint2 hi = *(const uint2*)(&Ps[base + 4]);
      uint4 u; u.x = lo.x; u.y = lo.y; u.z = hi.x; u.w = hi.y;
      Pf[i2] = *(bf16x8*)&u;
    }
    #pragma unroll
    for (int j = 0; j < 4; j++) {
      int base = (16 * j + lr) * WNS + ks * 32 + g * 8;
      uint2 lo = *(const uint2*)(&VT[base]);
      uint2 hi = *(const uint2*)(&VT[base + 4]);
      uint4 u; u.x = lo.x; u.y = lo.y; u.z = hi.x; u.w = hi.y;
      Vf[j] = *(bf16x8*)&u;
    }
    #pragma unroll
    for (int i2 = 0; i2 < 4; i2++)
      #pragma unroll
      for (int j = 0; j < 4; j++)
        o[i2][j] = __builtin_amdgcn_mfma_f32_16x16x32_bf16(Pf[i2], Vf[j], o[i2][j], 0, 0, 0);
  }

  #pragma unroll
  for (int i2 = 0; i2 < 4; i2++)
    #pragma unroll
    for (int r = 0; r < 4; r++) {
      int q = 16 * i2 + 4 * g + r;
      if (q <= 48) {
        size_t obase = tokof(q) * 512 + h * 64 + lr;
        #pragma unroll
        for (int j = 0; j < 4; j++)
          out[obase + 16 * j] = f2bf(o[i2][j][r]);
      }
    }
}

extern "C" void kernel_launch(void* const* d_in, const int* in_sizes, int n_in,
                              void* d_out, int out_size, void* d_ws, size_t ws_size,
                              hipStream_t stream) {
  const float* x      = (const float*)d_in[0];
  const float* cpe0_w = (const float*)d_in[1];
  const float* cpe0_b = (const float*)d_in[2];
  const float* cpe1_w = (const float*)d_in[3];
  const float* cpe1_b = (const float*)d_in[4];
  const float* ln1_g  = (const float*)d_in[5];
  const float* ln1_b  = (const float*)d_in[6];
  const float* ln2_g  = (const float*)d_in[7];
  const float* ln2_b  = (const float*)d_in[8];
  const float* qkv_w  = (const float*)d_in[9];
  const float* qkv_b  = (const float*)d_in[10];
  const float* proj_w = (const float*)d_in[11];
  const float* proj_b = (const float*)d_in[12];
  const float* fc1_w  = (const float*)d_in[13];
  const float* fc1_b  = (const float*)d_in[14];
  const float* fc2_w  = (const float*)d_in[15];
  const float* fc2_b  = (const float*)d_in[16];
  float* out = (float*)d_out;
  char* ws = (char*)d_ws;

  unsigned short* qkvwT  = (unsigned short*)(ws + 0);           // 1536x512 bf16
  unsigned short* projwT = (unsigned short*)(ws + 1572864);     // 512x512 bf16
  unsigned char*  fc1wT8 = (unsigned char*)(ws + 2097152);      // 2048x512 fp8
  unsigned char*  fc2wT8 = (unsigned char*)(ws + 4194304);      // 512x2048 fp8
  float*          shortc = (float*)(ws + 6291456);              // 50176x512 f32
  unsigned short* lnb    = (unsigned short*)(ws + 109051904);   // 50176x512 bf16
  unsigned char*  lnb8   = (unsigned char*)(ws + 109051904);    // overlay (ln2)
  unsigned short* qkvb   = (unsigned short*)(ws + 160432128);   // 50176x1536 bf16
  unsigned short* attnb  = (unsigned short*)(ws + 314572800);   // 50176x512 bf16
  unsigned char*  gelub8 = (unsigned char*)(ws + 160432128);    // overlay qkvb
  float* h2 = out;                 // reuse d_out as h2 scratch

  wtranspose_kernel<<<(512 * 1536 + 255) / 256, 256, 0, stream>>>(qkv_w, qkvwT, 512, 1536);
  wtranspose_kernel<<<(512 * 512 + 255) / 256, 256, 0, stream>>>(proj_w, projwT, 512, 512);
  wtranspose8_kernel<<<(512 * 2048 + 255) / 256, 256, 0, stream>>>(fc1_w, fc1wT8, 512, 2048);
  wtranspose8_kernel<<<(2048 * 512 + 255) / 256, 256, 0, stream>>>(fc2_w, fc2wT8, 2048, 512);

  const int pixblocks = (BB * HH * WW * 128) / 256;   // 25088
  cpe_kernel<<<pixblocks, 256, 0, stream>>>(x, cpe0_w, cpe0_b, shortc);
  ln_kernel<0><<<NTOK / 4, 256, 0, stream>>>(shortc, ln1_g, ln1_b, lnb, nullptr);
  gemm_kernel<0><<<dim3(12, 196), 512, 0, stream>>>(lnb, qkvwT, qkv_b, nullptr,
                                                    nullptr, qkvb, NTOK, 1536, 512);
  attn_mfma_kernel<<<8192, 64, 0, stream>>>(qkvb, attnb);
  gemm_kernel<1><<<dim3(4, 196), 512, 0, stream>>>(attnb, projwT, proj_b, shortc,
                                                   shortc, nullptr, NTOK, 512, 512);
  cpe_kernel<<<pixblocks, 256, 0, stream>>>(shortc, cpe1_w, cpe1_b, h2);
  ln_kernel<1><<<NTOK / 4, 256, 0, stream>>>(h2, ln2_g, ln2_b, nullptr, lnb8);
  gemm8_kernel<2><<<dim3(16, 196), 512, 0, stream>>>(lnb8, fc1wT8, fc1_b, nullptr,
                                                     nullptr, gelub8, NTOK, 2048, 512);
  gemm8_kernel<1><<<dim3(4, 196), 512, 0, stream>>>(gelub8, fc2wT8, fc2_b, h2,
                                                    out, nullptr, NTOK, 512, 2048);
}

// Round 10
// 635.400 us; speedup vs baseline: 1.0985x; 1.0985x over previous
//
#include <hip/hip_runtime.h>
#include <stdint.h>

#define HH 112
#define WW 112
#define CC 512
#define BB 4
#define LLEN (HH*WW)
#define NTOK (BB*LLEN)   // 50176
#define NHEADS 8
#define HD 64
#define HIDDEN 2048

typedef __bf16 bf16x8 __attribute__((ext_vector_type(8)));
typedef float f32x4 __attribute__((ext_vector_type(4)));
typedef long i64;

__device__ __forceinline__ unsigned short f2bf(float x) {
  uint32_t u = __float_as_uint(x);
  u += 0x7fffu + ((u >> 16) & 1u);
  return (unsigned short)(u >> 16);
}
__device__ __forceinline__ float bf2f(unsigned short h) {
  return __uint_as_float((uint32_t)h << 16);
}
__device__ __forceinline__ int cvt4_fp8(float a, float b, float c, float d) {
  int r = 0;
  r = __builtin_amdgcn_cvt_pk_fp8_f32(a, b, r, false);
  r = __builtin_amdgcn_cvt_pk_fp8_f32(c, d, r, true);
  return r;
}

__device__ __forceinline__ void gload16(const void* gptr, void* lptr) {
  __builtin_amdgcn_global_load_lds(
      (const __attribute__((address_space(1))) void*)gptr,
      (__attribute__((address_space(3))) void*)lptr,
      16, 0, 0);
}

#define WAITV3() asm volatile("s_waitcnt vmcnt(3)" ::: "memory")
#define WAITV0() asm volatile("s_waitcnt vmcnt(0)" ::: "memory")
#define BAR() __builtin_amdgcn_s_barrier()
#define WAITL() do { asm volatile("s_waitcnt lgkmcnt(0)" ::: "memory"); \
                     __builtin_amdgcn_sched_barrier(0); } while (0)

// ---------------- weight transpose (K,N) f32 -> (N,K) bf16 ----------------
__global__ __launch_bounds__(256) void wtranspose_kernel(
    const float* __restrict__ w, unsigned short* __restrict__ wt, int K, int N) {
  int idx = blockIdx.x * 256 + threadIdx.x;
  if (idx >= K * N) return;
  int k = idx / N, n = idx - k * N;
  wt[(size_t)n * K + k] = f2bf(w[idx]);
}

// ---------------- weight transpose (K,N) f32 -> (N,K) fp8, scaled x32 --------
__global__ __launch_bounds__(256) void wtranspose8_kernel(
    const float* __restrict__ w, unsigned char* __restrict__ wt, int K, int N) {
  int idx = blockIdx.x * 256 + threadIdx.x;   // index over OUTPUT (coalesced)
  if (idx >= K * N) return;
  int n = idx / K, k = idx - n * K;
  float v = w[(size_t)k * N + n] * 32.f;
  int r = __builtin_amdgcn_cvt_pk_fp8_f32(v, v, 0, false);
  wt[idx] = (unsigned char)r;
}

// ------- depthwise 3x3 conv + bias + residual; INBF/OUTBF select dtypes -------
template <int INBF, int OUTBF>
__global__ __launch_bounds__(256) void cpe_kernel(
    const void* __restrict__ xin, const float* __restrict__ w,
    const float* __restrict__ bias, void* __restrict__ outp) {
  int tid = blockIdx.x * 256 + threadIdx.x;
  int c = (tid & 127) << 2;      // channel chunk of 4
  int pix = tid >> 7;
  int xx = pix % WW; int t2 = pix / WW; int yy = t2 % HH; int bb = t2 / HH;
  float4 bv = *(const float4*)(&bias[c]);
  float ax = bv.x, ay = bv.y, az = bv.z, aw = bv.w;
  auto ld = [&](size_t eo) -> float4 {
    float4 v;
    if (INBF) {
      uint2 u = *(const uint2*)(&((const unsigned short*)xin)[eo]);
      v.x = bf2f((unsigned short)(u.x & 0xffff));
      v.y = bf2f((unsigned short)(u.x >> 16));
      v.z = bf2f((unsigned short)(u.y & 0xffff));
      v.w = bf2f((unsigned short)(u.y >> 16));
    } else {
      v = *(const float4*)(&((const float*)xin)[eo]);
    }
    return v;
  };
  #pragma unroll
  for (int ky = 0; ky < 3; ky++) {
    int y = yy + ky - 1;
    if ((unsigned)y >= (unsigned)HH) continue;
    #pragma unroll
    for (int kx = 0; kx < 3; kx++) {
      int x2 = xx + kx - 1;
      if ((unsigned)x2 >= (unsigned)WW) continue;
      float4 v = ld((((size_t)bb * HH + y) * WW + x2) * CC + c);
      const float4 wv = *(const float4*)(&w[(ky * 3 + kx) * CC + c]);
      ax = fmaf(v.x, wv.x, ax); ay = fmaf(v.y, wv.y, ay);
      az = fmaf(v.z, wv.z, az); aw = fmaf(v.w, wv.w, aw);
    }
  }
  size_t o = (size_t)pix * CC + c;
  float4 xv = ld(o);
  float rx = xv.x + ax, ry = xv.y + ay, rz = xv.z + az, rw = xv.w + aw;
  if (OUTBF) {
    uint2 pk;
    pk.x = (uint32_t)f2bf(rx) | ((uint32_t)f2bf(ry) << 16);
    pk.y = (uint32_t)f2bf(rz) | ((uint32_t)f2bf(rw) << 16);
    *(uint2*)(&((unsigned short*)outp)[o]) = pk;
  } else {
    float4 r; r.x = rx; r.y = ry; r.z = rz; r.w = rw;
    *(float4*)(&((float*)outp)[o]) = r;
  }
}

// ------- LayerNorm (C=512), one wave/token, fp8 e4m3 out; INBF selects input ----
template <int INBF>
__global__ __launch_bounds__(256) void ln_kernel(
    const void* __restrict__ in, const float* __restrict__ g,
    const float* __restrict__ b, unsigned char* __restrict__ out8) {
  int token = (blockIdx.x * 256 + threadIdx.x) >> 6;
  int lane = threadIdx.x & 63;
  float v[8];
  if (INBF) {
    uint4 u = *(const uint4*)(&((const unsigned short*)in)[(size_t)token * CC + lane * 8]);
    v[0] = bf2f((unsigned short)(u.x & 0xffff)); v[1] = bf2f((unsigned short)(u.x >> 16));
    v[2] = bf2f((unsigned short)(u.y & 0xffff)); v[3] = bf2f((unsigned short)(u.y >> 16));
    v[4] = bf2f((unsigned short)(u.z & 0xffff)); v[5] = bf2f((unsigned short)(u.z >> 16));
    v[6] = bf2f((unsigned short)(u.w & 0xffff)); v[7] = bf2f((unsigned short)(u.w >> 16));
  } else {
    const float* row = (const float*)in + (size_t)token * CC;
    float4 a = *(const float4*)(row + lane * 8);
    float4 c4 = *(const float4*)(row + lane * 8 + 4);
    v[0] = a.x; v[1] = a.y; v[2] = a.z; v[3] = a.w;
    v[4] = c4.x; v[5] = c4.y; v[6] = c4.z; v[7] = c4.w;
  }
  float s = 0.f, ss = 0.f;
  #pragma unroll
  for (int i = 0; i < 8; i++) { s += v[i]; ss += v[i] * v[i]; }
  #pragma unroll
  for (int o = 32; o; o >>= 1) { s += __shfl_xor(s, o, 64); ss += __shfl_xor(ss, o, 64); }
  float mu = s * (1.f / CC);
  float var = ss * (1.f / CC) - mu * mu;
  float rs = rsqrtf(var + 1e-5f);
  float4 g0 = *(const float4*)(&g[lane * 8]);
  float4 g1 = *(const float4*)(&g[lane * 8 + 4]);
  float4 b0 = *(const float4*)(&b[lane * 8]);
  float4 b1 = *(const float4*)(&b[lane * 8 + 4]);
  float o8[8];
  o8[0] = (v[0] - mu) * rs * g0.x + b0.x;
  o8[1] = (v[1] - mu) * rs * g0.y + b0.y;
  o8[2] = (v[2] - mu) * rs * g0.z + b0.z;
  o8[3] = (v[3] - mu) * rs * g0.w + b0.w;
  o8[4] = (v[4] - mu) * rs * g1.x + b1.x;
  o8[5] = (v[5] - mu) * rs * g1.y + b1.y;
  o8[6] = (v[6] - mu) * rs * g1.z + b1.z;
  o8[7] = (v[7] - mu) * rs * g1.w + b1.w;
  uint2 pk;
  pk.x = (uint32_t)cvt4_fp8(o8[0], o8[1], o8[2], o8[3]);
  pk.y = (uint32_t)cvt4_fp8(o8[4], o8[5], o8[6], o8[7]);
  *(uint2*)(&out8[(size_t)token * CC + lane * 8]) = pk;
}

// ---- proj GEMM (bf16): 2-buf, post-barrier restage, vmcnt(3), T2 swizzle ----
// out bf16 = C + bias + res(bf16)   [in-place on res allowed]
#define BM 256
#define BN 128
#define BK 32

__global__ __launch_bounds__(512) void gemm_proj_kernel(
    const unsigned short* __restrict__ A, const unsigned short* __restrict__ BT,
    const float* __restrict__ bias, const unsigned short* __restrict__ resB,
    unsigned short* __restrict__ outB, int M, int N, int K) {
  __shared__ unsigned char ldsb[49152];
  int nwg = gridDim.x * gridDim.y;
  int flat = blockIdx.y * gridDim.x + blockIdx.x;
  int swz = (flat & 7) * (nwg >> 3) + (flat >> 3);
  int bx = swz % gridDim.x, by = swz / gridDim.x;
  const int bm = by * BM, bn = bx * BN;
  const int t = threadIdx.x;
  const int wid = t >> 6, lane = t & 63;
  const int wr = wid >> 1, wc = wid & 1;
  const int lr = lane & 15;
  const int lk = (((lane >> 4) ^ ((lane >> 1) & 3)) & 3) * 8;
  const int srow = t >> 2;
  const int scol = (((t & 3) ^ ((t >> 3) & 3)) & 3) * 8;
  const size_t arow0 = (size_t)(bm + srow) * K + scol;
  const size_t arow1 = (size_t)(bm + 128 + srow) * K + scol;
  const size_t brow  = (size_t)(bn + srow) * K + scol;
  const int ldso = wid * 1024;

#define STG(b, kt) do { \
    gload16(&A[arow0 + (kt)], ldsb + (b) * 16384 + ldso); \
    gload16(&A[arow1 + (kt)], ldsb + (b) * 16384 + 8192 + ldso); \
    gload16(&BT[brow + (kt)], ldsb + 32768 + (b) * 8192 + ldso); } while (0)

  f32x4 acc[4][4] = {};
  const int nt = K / BK;

  STG(0, 0);
  STG(1, BK);

  for (int tile = 0; tile < nt - 1; ++tile) {
    WAITV3(); BAR();
    const unsigned short* as = (const unsigned short*)(ldsb + (tile & 1) * 16384);
    const unsigned short* bs = (const unsigned short*)(ldsb + 32768 + (tile & 1) * 8192);
    bf16x8 af[4], bfr[4];
    #pragma unroll
    for (int i = 0; i < 4; i++)
      af[i] = *(const bf16x8*)(&as[(wr * 64 + i * 16 + lr) * BK + lk]);
    #pragma unroll
    for (int j = 0; j < 4; j++)
      bfr[j] = *(const bf16x8*)(&bs[(wc * 64 + j * 16 + lr) * BK + lk]);
    WAITL();
    BAR();
    if (tile + 2 < nt) STG(tile & 1, (tile + 2) * BK);
    __builtin_amdgcn_s_setprio(1);
    #pragma unroll
    for (int i = 0; i < 4; i++)
      #pragma unroll
      for (int j = 0; j < 4; j++)
        acc[i][j] = __builtin_amdgcn_mfma_f32_16x16x32_bf16(af[i], bfr[j], acc[i][j], 0, 0, 0);
    __builtin_amdgcn_s_setprio(0);
  }
  {
    WAITV0(); BAR();
    const unsigned short* as = (const unsigned short*)(ldsb + ((nt - 1) & 1) * 16384);
    const unsigned short* bs = (const unsigned short*)(ldsb + 32768 + ((nt - 1) & 1) * 8192);
    bf16x8 af[4], bfr[4];
    #pragma unroll
    for (int i = 0; i < 4; i++)
      af[i] = *(const bf16x8*)(&as[(wr * 64 + i * 16 + lr) * BK + lk]);
    #pragma unroll
    for (int j = 0; j < 4; j++)
      bfr[j] = *(const bf16x8*)(&bs[(wc * 64 + j * 16 + lr) * BK + lk]);
    WAITL();
    #pragma unroll
    for (int i = 0; i < 4; i++)
      #pragma unroll
      for (int j = 0; j < 4; j++)
        acc[i][j] = __builtin_amdgcn_mfma_f32_16x16x32_bf16(af[i], bfr[j], acc[i][j], 0, 0, 0);
  }
#undef STG

  // epilogue: restage via LDS; out = acc + bias + res(bf16) -> bf16
  {
    float* eps = (float*)ldsb;
    const int erow = t >> 3;
    const int ecol0 = (t & 7) * 16;
    const int wrow = wr * 16 + (lane >> 4) * 4;
    const int wcol = wc * 64 + lr;
    const int gr_base = bm + (erow >> 4) * 64 + (erow & 15);
    const int gc0 = bn + ecol0;
    float bv[16];
    #pragma unroll
    for (int c4 = 0; c4 < 4; c4++)
      *(float4*)&bv[c4 * 4] = *(const float4*)&bias[gc0 + c4 * 4];
    #pragma unroll
    for (int i = 0; i < 4; i++) {
      __syncthreads();
      #pragma unroll
      for (int j = 0; j < 4; j++)
        #pragma unroll
        for (int r = 0; r < 4; r++)
          eps[(wrow + r) * 132 + wcol + j * 16] = acc[i][j][r];
      __syncthreads();
      float vv[16];
      #pragma unroll
      for (int c4 = 0; c4 < 4; c4++)
        *(float4*)&vv[c4 * 4] = *(const float4*)&eps[erow * 132 + ecol0 + c4 * 4];
      const size_t off = (size_t)(gr_base + i * 16) * N + gc0;
      uint4 r0 = *(const uint4*)&resB[off];
      uint4 r1 = *(const uint4*)&resB[off + 8];
      const uint32_t* rp = (const uint32_t*)&r0;
      unsigned short ob[16];
      #pragma unroll
      for (int c = 0; c < 8; c++) {
        uint32_t u = rp[c >> 1];   // r0 words 0..3, then r1
        float rv = bf2f((unsigned short)((c & 1) ? (u >> 16) : (u & 0xffff)));
        ob[c] = f2bf(vv[c] + bv[c] + rv);
      }
      const uint32_t* rp1 = (const uint32_t*)&r1;
      #pragma unroll
      for (int c = 0; c < 8; c++) {
        uint32_t u = rp1[c >> 1];
        float rv = bf2f((unsigned short)((c & 1) ? (u >> 16) : (u & 0xffff)));
        ob[8 + c] = f2bf(vv[8 + c] + bv[8 + c] + rv);
      }
      *(uint4*)&outB[off]     = *(uint4*)&ob[0];
      *(uint4*)&outB[off + 8] = *(uint4*)&ob[8];
    }
  }
}

// ==== fp8 e4m3 MFMA GEMM: 2-buf, vmcnt(3), BK=64; weights pre-scaled x32 ====
// MODE 0: out bf16 = C*s + bias          (qkv)
// MODE 1: out f32  = C*s + bias + res    (fc2)
// MODE 2: out fp8  = gelu(C*s + bias)    (fc1)
#define BK8 64

template <int MODE>
__global__ __launch_bounds__(512) void gemm8_kernel(
    const unsigned char* __restrict__ A, const unsigned char* __restrict__ BT,
    const float* __restrict__ bias, const float* __restrict__ res,
    float* __restrict__ outF, unsigned char* __restrict__ outB8,
    unsigned short* __restrict__ outB16, int M, int N, int K) {
  __shared__ unsigned char ldsb[49152];
  int nwg = gridDim.x * gridDim.y;
  int flat = blockIdx.y * gridDim.x + blockIdx.x;
  int swz = (flat & 7) * (nwg >> 3) + (flat >> 3);
  int bx = swz % gridDim.x, by = swz / gridDim.x;
  const int bm = by * BM, bn = bx * BN;
  const int t = threadIdx.x;
  const int wid = t >> 6, lane = t & 63;
  const int wr = wid >> 1, wc = wid & 1;
  const int lr = lane & 15, g = lane >> 4;
  const int swr = (lr >> 1) & 3;
  const int rb0 = (((g >> 1)      ) ^ swr) * 16 + (g & 1) * 8;
  const int rb1 = (((g >> 1) + 2) ^ swr) * 16 + (g & 1) * 8;
  const int srow = t >> 2;
  const int scol = (((t & 3) ^ ((t >> 3) & 3)) & 3) * 16;
  const size_t arow0 = (size_t)(bm + srow) * K + scol;
  const size_t arow1 = (size_t)(bm + 128 + srow) * K + scol;
  const size_t brow  = (size_t)(bn + srow) * K + scol;
  const int ldso = wid * 1024;

#define STG8(b, kt) do { \
    gload16(&A[arow0 + (kt)], ldsb + (b) * 16384 + ldso); \
    gload16(&A[arow1 + (kt)], ldsb + (b) * 16384 + 8192 + ldso); \
    gload16(&BT[brow + (kt)], ldsb + 32768 + (b) * 8192 + ldso); } while (0)

  f32x4 acc[4][4] = {};
  const int nt = K / BK8;

  STG8(0, 0);
  STG8(1, BK8);

  for (int tile = 0; tile < nt - 1; ++tile) {
    WAITV3(); BAR();
    const unsigned char* as = ldsb + (tile & 1) * 16384;
    const unsigned char* bs = ldsb + 32768 + (tile & 1) * 8192;
    i64 af0[4], af1[4], bf0[4], bf1[4];
    #pragma unroll
    for (int i = 0; i < 4; i++) {
      const unsigned char* p = &as[(wr * 64 + i * 16 + lr) * BK8];
      af0[i] = *(const i64*)(p + rb0);
      af1[i] = *(const i64*)(p + rb1);
    }
    #pragma unroll
    for (int j = 0; j < 4; j++) {
      const unsigned char* p = &bs[(wc * 64 + j * 16 + lr) * BK8];
      bf0[j] = *(const i64*)(p + rb0);
      bf1[j] = *(const i64*)(p + rb1);
    }
    WAITL();
    BAR();
    if (tile + 2 < nt) STG8(tile & 1, (tile + 2) * BK8);
    __builtin_amdgcn_s_setprio(1);
    #pragma unroll
    for (int i = 0; i < 4; i++)
      #pragma unroll
      for (int j = 0; j < 4; j++) {
        acc[i][j] = __builtin_amdgcn_mfma_f32_16x16x32_fp8_fp8(af0[i], bf0[j], acc[i][j], 0, 0, 0);
        acc[i][j] = __builtin_amdgcn_mfma_f32_16x16x32_fp8_fp8(af1[i], bf1[j], acc[i][j], 0, 0, 0);
      }
    __builtin_amdgcn_s_setprio(0);
  }
  {
    WAITV0(); BAR();
    const unsigned char* as = ldsb + ((nt - 1) & 1) * 16384;
    const unsigned char* bs = ldsb + 32768 + ((nt - 1) & 1) * 8192;
    i64 af0[4], af1[4], bf0[4], bf1[4];
    #pragma unroll
    for (int i = 0; i < 4; i++) {
      const unsigned char* p = &as[(wr * 64 + i * 16 + lr) * BK8];
      af0[i] = *(const i64*)(p + rb0);
      af1[i] = *(const i64*)(p + rb1);
    }
    #pragma unroll
    for (int j = 0; j < 4; j++) {
      const unsigned char* p = &bs[(wc * 64 + j * 16 + lr) * BK8];
      bf0[j] = *(const i64*)(p + rb0);
      bf1[j] = *(const i64*)(p + rb1);
    }
    WAITL();
    #pragma unroll
    for (int i = 0; i < 4; i++)
      #pragma unroll
      for (int j = 0; j < 4; j++) {
        acc[i][j] = __builtin_amdgcn_mfma_f32_16x16x32_fp8_fp8(af0[i], bf0[j], acc[i][j], 0, 0, 0);
        acc[i][j] = __builtin_amdgcn_mfma_f32_16x16x32_fp8_fp8(af1[i], bf1[j], acc[i][j], 0, 0, 0);
      }
  }
#undef STG8

  // ---- epilogue (restaged, vectorized), acc scaled by 1/32 ----
  {
    const float SC = 0.03125f;
    float* eps = (float*)ldsb;
    const int erow = t >> 3;
    const int ecol0 = (t & 7) * 16;
    const int wrow = wr * 16 + (lane >> 4) * 4;
    const int wcol = wc * 64 + lr;
    const int gr_base = bm + (erow >> 4) * 64 + (erow & 15);
    const int gc0 = bn + ecol0;
    float bv[16];
    #pragma unroll
    for (int c4 = 0; c4 < 4; c4++)
      *(float4*)&bv[c4 * 4] = *(const float4*)&bias[gc0 + c4 * 4];
    #pragma unroll
    for (int i = 0; i < 4; i++) {
      __syncthreads();
      #pragma unroll
      for (int j = 0; j < 4; j++)
        #pragma unroll
        for (int r = 0; r < 4; r++)
          eps[(wrow + r) * 132 + wcol + j * 16] = acc[i][j][r];
      __syncthreads();
      float vv[16];
      #pragma unroll
      for (int c4 = 0; c4 < 4; c4++)
        *(float4*)&vv[c4 * 4] = *(const float4*)&eps[erow * 132 + ecol0 + c4 * 4];
      const size_t off = (size_t)(gr_base + i * 16) * N + gc0;
      if (MODE == 1) {
        #pragma unroll
        for (int c4 = 0; c4 < 4; c4++) {
          float4 rv = *(const float4*)&res[off + c4 * 4];
          float4 ov;
          ov.x = vv[c4*4+0] * SC + bv[c4*4+0] + rv.x;
          ov.y = vv[c4*4+1] * SC + bv[c4*4+1] + rv.y;
          ov.z = vv[c4*4+2] * SC + bv[c4*4+2] + rv.z;
          ov.w = vv[c4*4+3] * SC + bv[c4*4+3] + rv.w;
          *(float4*)&outF[off + c4 * 4] = ov;
        }
      } else if (MODE == 0) {
        unsigned short ob[16];
        #pragma unroll
        for (int c = 0; c < 16; c++)
          ob[c] = f2bf(vv[c] * SC + bv[c]);
        *(uint4*)&outB16[off]     = *(uint4*)&ob[0];
        *(uint4*)&outB16[off + 8] = *(uint4*)&ob[8];
      } else {
        float gv[16];
        #pragma unroll
        for (int c = 0; c < 16; c++) {
          float v = vv[c] * SC + bv[c];
          float a2 = v * v;
          float w = v * fmaf(a2, -0.1029436f, -2.3024849f);
          float sg = __builtin_amdgcn_rcpf(1.f + __builtin_amdgcn_exp2f(w));
          gv[c] = v * sg;
        }
        uint4 pk;
        pk.x = (uint32_t)cvt4_fp8(gv[0],  gv[1],  gv[2],  gv[3]);
        pk.y = (uint32_t)cvt4_fp8(gv[4],  gv[5],  gv[6],  gv[7]);
        pk.z = (uint32_t)cvt4_fp8(gv[8],  gv[9],  gv[10], gv[11]);
        pk.w = (uint32_t)cvt4_fp8(gv[12], gv[13], gv[14], gv[15]);
        *(uint4*)&outB8[off] = pk;
      }
    }
  }
}

// ---------------- MFMA window attention: 1 wave per (window, head) ----------------
#define WNS 68

__global__ __launch_bounds__(64) void attn_mfma_kernel(
    const unsigned short* __restrict__ qkv, unsigned short* __restrict__ out) {
  __shared__ unsigned short VT[64 * WNS];   // V^T: [d][k]
  __shared__ unsigned short Ps[64 * WNS];   // P:   [q][k]
  const int task = blockIdx.x;
  const int win = task >> 3, h = task & 7;
  const int b = win >> 8, wy = (win >> 4) & 15, wx = win & 15;
  const int lane = threadIdx.x;
  const int lr = lane & 15, g = lane >> 4;

  auto tokof = [&](int r) {
    int rr = r > 48 ? 48 : r;
    int y = rr / 7, x2 = rr - y * 7;
    return (size_t)(b * LLEN + (wy * 7 + y) * WW + wx * 7 + x2);
  };

  {
    size_t vbase = tokof(lane) * 1536 + h * 64 + 1024;
    bool valid = lane <= 48;
    #pragma unroll
    for (int c = 0; c < 8; c++) {
      uint4 v = *(const uint4*)(&qkv[vbase + c * 8]);
      const unsigned short* pv = (const unsigned short*)&v;
      #pragma unroll
      for (int e = 0; e < 8; e++)
        VT[(c * 8 + e) * WNS + lane] = valid ? pv[e] : (unsigned short)0;
    }
  }

  size_t tok[4];
  #pragma unroll
  for (int i2 = 0; i2 < 4; i2++) tok[i2] = tokof(i2 * 16 + lr);
  bf16x8 Qf[4][2], Kf[4][2];
  #pragma unroll
  for (int i2 = 0; i2 < 4; i2++) {
    size_t base = tok[i2] * 1536 + h * 64 + g * 8;
    #pragma unroll
    for (int ks = 0; ks < 2; ks++) {
      Qf[i2][ks] = *(const bf16x8*)(&qkv[base + ks * 32]);
      Kf[i2][ks] = *(const bf16x8*)(&qkv[base + 512 + ks * 32]);
    }
  }

  f32x4 acc[4][4] = {};
  #pragma unroll
  for (int ks = 0; ks < 2; ks++)
    #pragma unroll
    for (int i2 = 0; i2 < 4; i2++)
      #pragma unroll
      for (int j = 0; j < 4; j++)
        acc[i2][j] = __builtin_amdgcn_mfma_f32_16x16x32_bf16(Kf[i2][ks], Qf[j][ks], acc[i2][j], 0, 0, 0);

  #pragma unroll
  for (int j = 0; j < 4; j++) {
    float mx = -1e30f;
    #pragma unroll
    for (int i2 = 0; i2 < 4; i2++)
      #pragma unroll
      for (int r = 0; r < 4; r++) {
        int k = 16 * i2 + 4 * g + r;
        mx = fmaxf(mx, (k <= 48) ? acc[i2][j][r] : -1e30f);
      }
    mx = fmaxf(mx, __shfl_xor(mx, 16, 64));
    mx = fmaxf(mx, __shfl_xor(mx, 32, 64));
    float p[4][4];
    float sum = 0.f;
    #pragma unroll
    for (int i2 = 0; i2 < 4; i2++)
      #pragma unroll
      for (int r = 0; r < 4; r++) {
        int k = 16 * i2 + 4 * g + r;
        float e = (k <= 48) ? __expf(0.125f * (acc[i2][j][r] - mx)) : 0.f;
        p[i2][r] = e; sum += e;
      }
    sum += __shfl_xor(sum, 16, 64);
    sum += __shfl_xor(sum, 32, 64);
    float inv = 1.f / sum;
    int q = 16 * j + lr;
    #pragma unroll
    for (int i2 = 0; i2 < 4; i2++) {
      uint2 w;
      w.x = (uint32_t)f2bf(p[i2][0] * inv) | ((uint32_t)f2bf(p[i2][1] * inv) << 16);
      w.y = (uint32_t)f2bf(p[i2][2] * inv) | ((uint32_t)f2bf(p[i2][3] * inv) << 16);
      *(uint2*)(&Ps[q * WNS + 16 * i2 + 4 * g]) = w;
    }
  }

  __syncthreads();

  f32x4 o[4][4] = {};
  #pragma unroll
  for (int ks = 0; ks < 2; ks++) {
    bf16x8 Pf[4], Vf[4];
    #pragma unroll
    for (int i2 = 0; i2 < 4; i2++) {
      int base = (16 * i2 + lr) * WNS + ks * 32 + g * 8;
      uint2 lo = *(const uint2*)(&Ps[base]);
      uint2 hi = *(const uint2*)(&Ps[base + 4]);
      uint4 u; u.x = lo.x; u.y = lo.y; u.z = hi.x; u.w = hi.y;
      Pf[i2] = *(bf16x8*)&u;
    }
    #pragma unroll
    for (int j = 0; j < 4; j++) {
      int base = (16 * j + lr) * WNS + ks * 32 + g * 8;
      uint2 lo = *(const uint2*)(&VT[base]);
      uint2 hi = *(const uint2*)(&VT[base + 4]);
      uint4 u; u.x = lo.x; u.y = lo.y; u.z = hi.x; u.w = hi.y;
      Vf[j] = *(bf16x8*)&u;
    }
    #pragma unroll
    for (int i2 = 0; i2 < 4; i2++)
      #pragma unroll
      for (int j = 0; j < 4; j++)
        o[i2][j] = __builtin_amdgcn_mfma_f32_16x16x32_bf16(Pf[i2], Vf[j], o[i2][j], 0, 0, 0);
  }

  #pragma unroll
  for (int i2 = 0; i2 < 4; i2++)
    #pragma unroll
    for (int r = 0; r < 4; r++) {
      int q = 16 * i2 + 4 * g + r;
      if (q <= 48) {
        size_t obase = tokof(q) * 512 + h * 64 + lr;
        #pragma unroll
        for (int j = 0; j < 4; j++)
          out[obase + 16 * j] = f2bf(o[i2][j][r]);
      }
    }
}

extern "C" void kernel_launch(void* const* d_in, const int* in_sizes, int n_in,
                              void* d_out, int out_size, void* d_ws, size_t ws_size,
                              hipStream_t stream) {
  const float* x      = (const float*)d_in[0];
  const float* cpe0_w = (const float*)d_in[1];
  const float* cpe0_b = (const float*)d_in[2];
  const float* cpe1_w = (const float*)d_in[3];
  const float* cpe1_b = (const float*)d_in[4];
  const float* ln1_g  = (const float*)d_in[5];
  const float* ln1_b  = (const float*)d_in[6];
  const float* ln2_g  = (const float*)d_in[7];
  const float* ln2_b  = (const float*)d_in[8];
  const float* qkv_w  = (const float*)d_in[9];
  const float* qkv_b  = (const float*)d_in[10];
  const float* proj_w = (const float*)d_in[11];
  const float* proj_b = (const float*)d_in[12];
  const float* fc1_w  = (const float*)d_in[13];
  const float* fc1_b  = (const float*)d_in[14];
  const float* fc2_w  = (const float*)d_in[15];
  const float* fc2_b  = (const float*)d_in[16];
  float* out = (float*)d_out;
  char* ws = (char*)d_ws;

  unsigned char*  qkvwT8 = (unsigned char*)(ws + 0);            // 1536x512 fp8
  unsigned short* projwT = (unsigned short*)(ws + 1572864);     // 512x512 bf16
  unsigned char*  fc1wT8 = (unsigned char*)(ws + 2097152);      // 2048x512 fp8
  unsigned char*  fc2wT8 = (unsigned char*)(ws + 4194304);      // 512x2048 fp8
  unsigned short* shortcB = (unsigned short*)(ws + 6291456);    // 50176x512 bf16
  unsigned char*  lnb8   = (unsigned char*)(ws + 109051904);    // 50176x512 fp8
  unsigned short* qkvb   = (unsigned short*)(ws + 160432128);   // 50176x1536 bf16
  unsigned short* attnb  = (unsigned short*)(ws + 314572800);   // 50176x512 bf16
  unsigned char*  gelub8 = (unsigned char*)(ws + 160432128);    // overlay qkvb
  float* h2 = out;                 // d_out doubles as h2 (f32)

  wtranspose8_kernel<<<(512 * 1536 + 255) / 256, 256, 0, stream>>>(qkv_w, qkvwT8, 512, 1536);
  wtranspose_kernel<<<(512 * 512 + 255) / 256, 256, 0, stream>>>(proj_w, projwT, 512, 512);
  wtranspose8_kernel<<<(512 * 2048 + 255) / 256, 256, 0, stream>>>(fc1_w, fc1wT8, 512, 2048);
  wtranspose8_kernel<<<(2048 * 512 + 255) / 256, 256, 0, stream>>>(fc2_w, fc2wT8, 2048, 512);

  const int pixblocks = (BB * HH * WW * 128) / 256;   // 25088
  // shortcut = x + dwconv(x)  (f32 in -> bf16 out)
  cpe_kernel<0, 1><<<pixblocks, 256, 0, stream>>>(x, cpe0_w, cpe0_b, shortcB);
  // ln1: bf16 in -> fp8 out
  ln_kernel<1><<<NTOK / 4, 256, 0, stream>>>(shortcB, ln1_g, ln1_b, lnb8);
  // qkv (fp8): out bf16
  gemm8_kernel<0><<<dim3(12, 196), 512, 0, stream>>>(lnb8, qkvwT8, qkv_b, nullptr,
                                                     nullptr, nullptr, qkvb, NTOK, 1536, 512);
  attn_mfma_kernel<<<8192, 64, 0, stream>>>(qkvb, attnb);
  // h = shortcut + attn@proj_w + b  (bf16 res, bf16 out, in-place on shortcB)
  gemm_proj_kernel<<<dim3(4, 196), 512, 0, stream>>>(attnb, projwT, proj_b, shortcB,
                                                     shortcB, NTOK, 512, 512);
  // h2 = h + dwconv(h)  (bf16 in -> f32 out = d_out)
  cpe_kernel<1, 0><<<pixblocks, 256, 0, stream>>>(shortcB, cpe1_w, cpe1_b, h2);
  // ln2: f32 in -> fp8 out
  ln_kernel<0><<<NTOK / 4, 256, 0, stream>>>(h2, ln2_g, ln2_b, lnb8);
  // fc1 (fp8): gelu -> fp8
  gemm8_kernel<2><<<dim3(16, 196), 512, 0, stream>>>(lnb8, fc1wT8, fc1_b, nullptr,
                                                     nullptr, gelub8, nullptr, NTOK, 2048, 512);
  // fc2 (fp8): f32 out + h2 residual
  gemm8_kernel<1><<<dim3(4, 196), 512, 0, stream>>>(gelub8, fc2wT8, fc2_b, h2,
                                                    out, nullptr, nullptr, NTOK, 512, 2048);
}

// Round 11
// 584.582 us; speedup vs baseline: 1.1940x; 1.0869x over previous
//
#include <hip/hip_runtime.h>
#include <stdint.h>

#define HH 112
#define WW 112
#define CC 512
#define BB 4
#define LLEN (HH*WW)
#define NTOK (BB*LLEN)   // 50176
#define NHEADS 8
#define HD 64
#define HIDDEN 2048

typedef __bf16 bf16x8 __attribute__((ext_vector_type(8)));
typedef float f32x4 __attribute__((ext_vector_type(4)));
typedef long i64;

__device__ __forceinline__ unsigned short f2bf(float x) {
  uint32_t u = __float_as_uint(x);
  u += 0x7fffu + ((u >> 16) & 1u);
  return (unsigned short)(u >> 16);
}
__device__ __forceinline__ float bf2f(unsigned short h) {
  return __uint_as_float((uint32_t)h << 16);
}
__device__ __forceinline__ int cvt4_fp8(float a, float b, float c, float d) {
  int r = 0;
  r = __builtin_amdgcn_cvt_pk_fp8_f32(a, b, r, false);
  r = __builtin_amdgcn_cvt_pk_fp8_f32(c, d, r, true);
  return r;
}

__device__ __forceinline__ void gload16(const void* gptr, void* lptr) {
  __builtin_amdgcn_global_load_lds(
      (const __attribute__((address_space(1))) void*)gptr,
      (__attribute__((address_space(3))) void*)lptr,
      16, 0, 0);
}

#define WAITV3() asm volatile("s_waitcnt vmcnt(3)" ::: "memory")
#define WAITV0() asm volatile("s_waitcnt vmcnt(0)" ::: "memory")
#define BAR() __builtin_amdgcn_s_barrier()
#define WAITL() do { asm volatile("s_waitcnt lgkmcnt(0)" ::: "memory"); \
                     __builtin_amdgcn_sched_barrier(0); } while (0)

// ---------------- weight transpose (K,N) f32 -> (N,K) fp8, scaled x32 --------
__global__ __launch_bounds__(256) void wtranspose8_kernel(
    const float* __restrict__ w, unsigned char* __restrict__ wt, int K, int N) {
  int idx = blockIdx.x * 256 + threadIdx.x;   // index over OUTPUT (coalesced)
  if (idx >= K * N) return;
  int n = idx / K, k = idx - n * K;
  float v = w[(size_t)k * N + n] * 32.f;
  int r = __builtin_amdgcn_cvt_pk_fp8_f32(v, v, 0, false);
  wt[idx] = (unsigned char)r;
}

// ------- depthwise 3x3 conv + bias + residual; INBF/OUTBF select dtypes -------
template <int INBF, int OUTBF>
__global__ __launch_bounds__(256) void cpe_kernel(
    const void* __restrict__ xin, const float* __restrict__ w,
    const float* __restrict__ bias, void* __restrict__ outp) {
  int tid = blockIdx.x * 256 + threadIdx.x;
  int c = (tid & 127) << 2;      // channel chunk of 4
  int pix = tid >> 7;
  int xx = pix % WW; int t2 = pix / WW; int yy = t2 % HH; int bb = t2 / HH;
  float4 bv = *(const float4*)(&bias[c]);
  float ax = bv.x, ay = bv.y, az = bv.z, aw = bv.w;
  auto ld = [&](size_t eo) -> float4 {
    float4 v;
    if (INBF) {
      uint2 u = *(const uint2*)(&((const unsigned short*)xin)[eo]);
      v.x = bf2f((unsigned short)(u.x & 0xffff));
      v.y = bf2f((unsigned short)(u.x >> 16));
      v.z = bf2f((unsigned short)(u.y & 0xffff));
      v.w = bf2f((unsigned short)(u.y >> 16));
    } else {
      v = *(const float4*)(&((const float*)xin)[eo]);
    }
    return v;
  };
  #pragma unroll
  for (int ky = 0; ky < 3; ky++) {
    int y = yy + ky - 1;
    if ((unsigned)y >= (unsigned)HH) continue;
    #pragma unroll
    for (int kx = 0; kx < 3; kx++) {
      int x2 = xx + kx - 1;
      if ((unsigned)x2 >= (unsigned)WW) continue;
      float4 v = ld((((size_t)bb * HH + y) * WW + x2) * CC + c);
      const float4 wv = *(const float4*)(&w[(ky * 3 + kx) * CC + c]);
      ax = fmaf(v.x, wv.x, ax); ay = fmaf(v.y, wv.y, ay);
      az = fmaf(v.z, wv.z, az); aw = fmaf(v.w, wv.w, aw);
    }
  }
  size_t o = (size_t)pix * CC + c;
  float4 xv = ld(o);
  float rx = xv.x + ax, ry = xv.y + ay, rz = xv.z + az, rw = xv.w + aw;
  if (OUTBF) {
    uint2 pk;
    pk.x = (uint32_t)f2bf(rx) | ((uint32_t)f2bf(ry) << 16);
    pk.y = (uint32_t)f2bf(rz) | ((uint32_t)f2bf(rw) << 16);
    *(uint2*)(&((unsigned short*)outp)[o]) = pk;
  } else {
    float4 r; r.x = rx; r.y = ry; r.z = rz; r.w = rw;
    *(float4*)(&((float*)outp)[o]) = r;
  }
}

// ------- LayerNorm (C=512), one wave/token, fp8 e4m3 out; INBF selects input ----
template <int INBF>
__global__ __launch_bounds__(256) void ln_kernel(
    const void* __restrict__ in, const float* __restrict__ g,
    const float* __restrict__ b, unsigned char* __restrict__ out8) {
  int token = (blockIdx.x * 256 + threadIdx.x) >> 6;
  int lane = threadIdx.x & 63;
  float v[8];
  if (INBF) {
    uint4 u = *(const uint4*)(&((const unsigned short*)in)[(size_t)token * CC + lane * 8]);
    v[0] = bf2f((unsigned short)(u.x & 0xffff)); v[1] = bf2f((unsigned short)(u.x >> 16));
    v[2] = bf2f((unsigned short)(u.y & 0xffff)); v[3] = bf2f((unsigned short)(u.y >> 16));
    v[4] = bf2f((unsigned short)(u.z & 0xffff)); v[5] = bf2f((unsigned short)(u.z >> 16));
    v[6] = bf2f((unsigned short)(u.w & 0xffff)); v[7] = bf2f((unsigned short)(u.w >> 16));
  } else {
    const float* row = (const float*)in + (size_t)token * CC;
    float4 a = *(const float4*)(row + lane * 8);
    float4 c4 = *(const float4*)(row + lane * 8 + 4);
    v[0] = a.x; v[1] = a.y; v[2] = a.z; v[3] = a.w;
    v[4] = c4.x; v[5] = c4.y; v[6] = c4.z; v[7] = c4.w;
  }
  float s = 0.f, ss = 0.f;
  #pragma unroll
  for (int i = 0; i < 8; i++) { s += v[i]; ss += v[i] * v[i]; }
  #pragma unroll
  for (int o = 32; o; o >>= 1) { s += __shfl_xor(s, o, 64); ss += __shfl_xor(ss, o, 64); }
  float mu = s * (1.f / CC);
  float var = ss * (1.f / CC) - mu * mu;
  float rs = rsqrtf(var + 1e-5f);
  float4 g0 = *(const float4*)(&g[lane * 8]);
  float4 g1 = *(const float4*)(&g[lane * 8 + 4]);
  float4 b0 = *(const float4*)(&b[lane * 8]);
  float4 b1 = *(const float4*)(&b[lane * 8 + 4]);
  float o8[8];
  o8[0] = (v[0] - mu) * rs * g0.x + b0.x;
  o8[1] = (v[1] - mu) * rs * g0.y + b0.y;
  o8[2] = (v[2] - mu) * rs * g0.z + b0.z;
  o8[3] = (v[3] - mu) * rs * g0.w + b0.w;
  o8[4] = (v[4] - mu) * rs * g1.x + b1.x;
  o8[5] = (v[5] - mu) * rs * g1.y + b1.y;
  o8[6] = (v[6] - mu) * rs * g1.z + b1.z;
  o8[7] = (v[7] - mu) * rs * g1.w + b1.w;
  uint2 pk;
  pk.x = (uint32_t)cvt4_fp8(o8[0], o8[1], o8[2], o8[3]);
  pk.y = (uint32_t)cvt4_fp8(o8[4], o8[5], o8[6], o8[7]);
  *(uint2*)(&out8[(size_t)token * CC + lane * 8]) = pk;
}

// ==== fp8 e4m3 MFMA GEMM: 2-buf, vmcnt(3), BK=64; weights pre-scaled x32 ====
// MODE 0: out fp8  = C*s + bias           (qkv)
// MODE 1: out f32  = C*s + bias + res_f32 (fc2)
// MODE 2: out fp8  = gelu(C*s + bias)     (fc1)
// MODE 3: out bf16 = C*s + bias + res_bf16 (proj, in-place on res)
#define BM 256
#define BN 128
#define BK8 64

template <int MODE>
__global__ __launch_bounds__(512) void gemm8_kernel(
    const unsigned char* __restrict__ A, const unsigned char* __restrict__ BT,
    const float* __restrict__ bias, const float* __restrict__ res,
    const unsigned short* __restrict__ resB,
    float* __restrict__ outF, unsigned char* __restrict__ outB8,
    unsigned short* __restrict__ outB16, int M, int N, int K) {
  __shared__ unsigned char ldsb[49152];
  int nwg = gridDim.x * gridDim.y;
  int flat = blockIdx.y * gridDim.x + blockIdx.x;
  int swz = (flat & 7) * (nwg >> 3) + (flat >> 3);
  int bx = swz % gridDim.x, by = swz / gridDim.x;
  const int bm = by * BM, bn = bx * BN;
  const int t = threadIdx.x;
  const int wid = t >> 6, lane = t & 63;
  const int wr = wid >> 1, wc = wid & 1;
  const int lr = lane & 15, g = lane >> 4;
  const int swr = (lr >> 1) & 3;
  const int rb0 = (((g >> 1)      ) ^ swr) * 16 + (g & 1) * 8;
  const int rb1 = (((g >> 1) + 2) ^ swr) * 16 + (g & 1) * 8;
  const int srow = t >> 2;
  const int scol = (((t & 3) ^ ((t >> 3) & 3)) & 3) * 16;
  const size_t arow0 = (size_t)(bm + srow) * K + scol;
  const size_t arow1 = (size_t)(bm + 128 + srow) * K + scol;
  const size_t brow  = (size_t)(bn + srow) * K + scol;
  const int ldso = wid * 1024;

#define STG8(b, kt) do { \
    gload16(&A[arow0 + (kt)], ldsb + (b) * 16384 + ldso); \
    gload16(&A[arow1 + (kt)], ldsb + (b) * 16384 + 8192 + ldso); \
    gload16(&BT[brow + (kt)], ldsb + 32768 + (b) * 8192 + ldso); } while (0)

  f32x4 acc[4][4] = {};
  const int nt = K / BK8;

  STG8(0, 0);
  STG8(1, BK8);

  for (int tile = 0; tile < nt - 1; ++tile) {
    WAITV3(); BAR();
    const unsigned char* as = ldsb + (tile & 1) * 16384;
    const unsigned char* bs = ldsb + 32768 + (tile & 1) * 8192;
    i64 af0[4], af1[4], bf0[4], bf1[4];
    #pragma unroll
    for (int i = 0; i < 4; i++) {
      const unsigned char* p = &as[(wr * 64 + i * 16 + lr) * BK8];
      af0[i] = *(const i64*)(p + rb0);
      af1[i] = *(const i64*)(p + rb1);
    }
    #pragma unroll
    for (int j = 0; j < 4; j++) {
      const unsigned char* p = &bs[(wc * 64 + j * 16 + lr) * BK8];
      bf0[j] = *(const i64*)(p + rb0);
      bf1[j] = *(const i64*)(p + rb1);
    }
    WAITL();
    BAR();
    if (tile + 2 < nt) STG8(tile & 1, (tile + 2) * BK8);
    __builtin_amdgcn_s_setprio(1);
    #pragma unroll
    for (int i = 0; i < 4; i++)
      #pragma unroll
      for (int j = 0; j < 4; j++) {
        acc[i][j] = __builtin_amdgcn_mfma_f32_16x16x32_fp8_fp8(af0[i], bf0[j], acc[i][j], 0, 0, 0);
        acc[i][j] = __builtin_amdgcn_mfma_f32_16x16x32_fp8_fp8(af1[i], bf1[j], acc[i][j], 0, 0, 0);
      }
    __builtin_amdgcn_s_setprio(0);
  }
  {
    WAITV0(); BAR();
    const unsigned char* as = ldsb + ((nt - 1) & 1) * 16384;
    const unsigned char* bs = ldsb + 32768 + ((nt - 1) & 1) * 8192;
    i64 af0[4], af1[4], bf0[4], bf1[4];
    #pragma unroll
    for (int i = 0; i < 4; i++) {
      const unsigned char* p = &as[(wr * 64 + i * 16 + lr) * BK8];
      af0[i] = *(const i64*)(p + rb0);
      af1[i] = *(const i64*)(p + rb1);
    }
    #pragma unroll
    for (int j = 0; j < 4; j++) {
      const unsigned char* p = &bs[(wc * 64 + j * 16 + lr) * BK8];
      bf0[j] = *(const i64*)(p + rb0);
      bf1[j] = *(const i64*)(p + rb1);
    }
    WAITL();
    #pragma unroll
    for (int i = 0; i < 4; i++)
      #pragma unroll
      for (int j = 0; j < 4; j++) {
        acc[i][j] = __builtin_amdgcn_mfma_f32_16x16x32_fp8_fp8(af0[i], bf0[j], acc[i][j], 0, 0, 0);
        acc[i][j] = __builtin_amdgcn_mfma_f32_16x16x32_fp8_fp8(af1[i], bf1[j], acc[i][j], 0, 0, 0);
      }
  }
#undef STG8

  // ---- epilogue (restaged, vectorized), acc scaled by 1/32 ----
  {
    const float SC = 0.03125f;
    float* eps = (float*)ldsb;
    const int erow = t >> 3;
    const int ecol0 = (t & 7) * 16;
    const int wrow = wr * 16 + (lane >> 4) * 4;
    const int wcol = wc * 64 + lr;
    const int gr_base = bm + (erow >> 4) * 64 + (erow & 15);
    const int gc0 = bn + ecol0;
    float bv[16];
    #pragma unroll
    for (int c4 = 0; c4 < 4; c4++)
      *(float4*)&bv[c4 * 4] = *(const float4*)&bias[gc0 + c4 * 4];
    #pragma unroll
    for (int i = 0; i < 4; i++) {
      __syncthreads();
      #pragma unroll
      for (int j = 0; j < 4; j++)
        #pragma unroll
        for (int r = 0; r < 4; r++)
          eps[(wrow + r) * 132 + wcol + j * 16] = acc[i][j][r];
      __syncthreads();
      float vv[16];
      #pragma unroll
      for (int c4 = 0; c4 < 4; c4++)
        *(float4*)&vv[c4 * 4] = *(const float4*)&eps[erow * 132 + ecol0 + c4 * 4];
      const size_t off = (size_t)(gr_base + i * 16) * N + gc0;
      if (MODE == 1) {
        #pragma unroll
        for (int c4 = 0; c4 < 4; c4++) {
          float4 rv = *(const float4*)&res[off + c4 * 4];
          float4 ov;
          ov.x = vv[c4*4+0] * SC + bv[c4*4+0] + rv.x;
          ov.y = vv[c4*4+1] * SC + bv[c4*4+1] + rv.y;
          ov.z = vv[c4*4+2] * SC + bv[c4*4+2] + rv.z;
          ov.w = vv[c4*4+3] * SC + bv[c4*4+3] + rv.w;
          *(float4*)&outF[off + c4 * 4] = ov;
        }
      } else if (MODE == 0) {
        uint4 pk;
        pk.x = (uint32_t)cvt4_fp8(vv[0]*SC+bv[0],  vv[1]*SC+bv[1],  vv[2]*SC+bv[2],  vv[3]*SC+bv[3]);
        pk.y = (uint32_t)cvt4_fp8(vv[4]*SC+bv[4],  vv[5]*SC+bv[5],  vv[6]*SC+bv[6],  vv[7]*SC+bv[7]);
        pk.z = (uint32_t)cvt4_fp8(vv[8]*SC+bv[8],  vv[9]*SC+bv[9],  vv[10]*SC+bv[10], vv[11]*SC+bv[11]);
        pk.w = (uint32_t)cvt4_fp8(vv[12]*SC+bv[12], vv[13]*SC+bv[13], vv[14]*SC+bv[14], vv[15]*SC+bv[15]);
        *(uint4*)&outB8[off] = pk;
      } else if (MODE == 3) {
        uint4 r0 = *(const uint4*)&resB[off];
        uint4 r1 = *(const uint4*)&resB[off + 8];
        unsigned short ob[16];
        const uint32_t* rp = (const uint32_t*)&r0;
        #pragma unroll
        for (int c = 0; c < 8; c++) {
          uint32_t u = rp[c >> 1];
          float rv = bf2f((unsigned short)((c & 1) ? (u >> 16) : (u & 0xffff)));
          ob[c] = f2bf(vv[c] * SC + bv[c] + rv);
        }
        const uint32_t* rp1 = (const uint32_t*)&r1;
        #pragma unroll
        for (int c = 0; c < 8; c++) {
          uint32_t u = rp1[c >> 1];
          float rv = bf2f((unsigned short)((c & 1) ? (u >> 16) : (u & 0xffff)));
          ob[8 + c] = f2bf(vv[8 + c] * SC + bv[8 + c] + rv);
        }
        *(uint4*)&outB16[off]     = *(uint4*)&ob[0];
        *(uint4*)&outB16[off + 8] = *(uint4*)&ob[8];
      } else {
        float gv[16];
        #pragma unroll
        for (int c = 0; c < 16; c++) {
          float v = vv[c] * SC + bv[c];
          float a2 = v * v;
          float w = v * fmaf(a2, -0.1029436f, -2.3024849f);
          float sg = __builtin_amdgcn_rcpf(1.f + __builtin_amdgcn_exp2f(w));
          gv[c] = v * sg;
        }
        uint4 pk;
        pk.x = (uint32_t)cvt4_fp8(gv[0],  gv[1],  gv[2],  gv[3]);
        pk.y = (uint32_t)cvt4_fp8(gv[4],  gv[5],  gv[6],  gv[7]);
        pk.z = (uint32_t)cvt4_fp8(gv[8],  gv[9],  gv[10], gv[11]);
        pk.w = (uint32_t)cvt4_fp8(gv[12], gv[13], gv[14], gv[15]);
        *(uint4*)&outB8[off] = pk;
      }
    }
  }
}

// -------- fp8 MFMA window attention: 1 wave per (window, head), all-fp8 IO -------
#define WNS8 72   // byte stride: 64B data + 8 pad, 8-aligned

__global__ __launch_bounds__(64) void attn_mfma8_kernel(
    const unsigned char* __restrict__ qkv, unsigned char* __restrict__ out) {
  __shared__ unsigned char VT[64 * WNS8];   // V^T: [d][k] fp8
  __shared__ unsigned char Ps[64 * WNS8];   // P:   [q][k] fp8
  const int task = blockIdx.x;
  const int win = task >> 3, h = task & 7;
  const int b = win >> 8, wy = (win >> 4) & 15, wx = win & 15;
  const int lane = threadIdx.x;
  const int lr = lane & 15, g = lane >> 4;

  auto tokof = [&](int r) {
    int rr = r > 48 ? 48 : r;
    int y = rr / 7, x2 = rr - y * 7;
    return (size_t)(b * LLEN + (wy * 7 + y) * WW + wx * 7 + x2);
  };

  // ---- stage V^T (fp8 bytes; lane = k/token, rows = d) ----
  {
    size_t vbase = tokof(lane) * 1536 + 1024 + h * 64;
    bool valid = lane <= 48;
    #pragma unroll
    for (int c = 0; c < 4; c++) {
      uint4 v = *(const uint4*)(&qkv[vbase + c * 16]);
      const unsigned char* pv = (const unsigned char*)&v;
      #pragma unroll
      for (int e = 0; e < 16; e++)
        VT[(c * 16 + e) * WNS8 + lane] = valid ? pv[e] : (unsigned char)0;
    }
  }

  // ---- Q,K fragments from global (8 bytes per (tile,ks): k = ks*32 + g*8 + 0..7)
  size_t tok[4];
  #pragma unroll
  for (int i2 = 0; i2 < 4; i2++) tok[i2] = tokof(i2 * 16 + lr);
  i64 Qf[4][2], Kf[4][2];
  #pragma unroll
  for (int i2 = 0; i2 < 4; i2++) {
    size_t base = tok[i2] * 1536 + h * 64 + g * 8;
    #pragma unroll
    for (int ks = 0; ks < 2; ks++) {
      Qf[i2][ks] = *(const i64*)(&qkv[base + ks * 32]);
      Kf[i2][ks] = *(const i64*)(&qkv[base + 512 + ks * 32]);
    }
  }

  // ---- S^T = K·Q^T (fp8 MFMA): acc[i=k-tile][j=q-tile]
  f32x4 acc[4][4] = {};
  #pragma unroll
  for (int ks = 0; ks < 2; ks++)
    #pragma unroll
    for (int i2 = 0; i2 < 4; i2++)
      #pragma unroll
      for (int j = 0; j < 4; j++)
        acc[i2][j] = __builtin_amdgcn_mfma_f32_16x16x32_fp8_fp8(Kf[i2][ks], Qf[j][ks], acc[i2][j], 0, 0, 0);

  // ---- softmax over k; P stored fp8 into Ps[q][k]
  #pragma unroll
  for (int j = 0; j < 4; j++) {
    float mx = -1e30f;
    #pragma unroll
    for (int i2 = 0; i2 < 4; i2++)
      #pragma unroll
      for (int r = 0; r < 4; r++) {
        int k = 16 * i2 + 4 * g + r;
        mx = fmaxf(mx, (k <= 48) ? acc[i2][j][r] : -1e30f);
      }
    mx = fmaxf(mx, __shfl_xor(mx, 16, 64));
    mx = fmaxf(mx, __shfl_xor(mx, 32, 64));
    float p[4][4];
    float sum = 0.f;
    #pragma unroll
    for (int i2 = 0; i2 < 4; i2++)
      #pragma unroll
      for (int r = 0; r < 4; r++) {
        int k = 16 * i2 + 4 * g + r;
        float e = (k <= 48) ? __expf(0.125f * (acc[i2][j][r] - mx)) : 0.f;
        p[i2][r] = e; sum += e;
      }
    sum += __shfl_xor(sum, 16, 64);
    sum += __shfl_xor(sum, 32, 64);
    float inv = 1.f / sum;
    int q = 16 * j + lr;
    #pragma unroll
    for (int i2 = 0; i2 < 4; i2++) {
      uint32_t w = (uint32_t)cvt4_fp8(p[i2][0] * inv, p[i2][1] * inv,
                                      p[i2][2] * inv, p[i2][3] * inv);
      *(uint32_t*)(&Ps[q * WNS8 + 16 * i2 + 4 * g]) = w;
    }
  }

  __syncthreads();   // VT + Ps writes -> reads fence

  // ---- O = P·V (fp8 MFMA): A = Ps[q][k], B^T = VT[d][k]
  f32x4 o[4][4] = {};
  #pragma unroll
  for (int ks = 0; ks < 2; ks++) {
    i64 Pf[4], Vf[4];
    #pragma unroll
    for (int i2 = 0; i2 < 4; i2++)
      Pf[i2] = *(const i64*)(&Ps[(16 * i2 + lr) * WNS8 + ks * 32 + g * 8]);
    #pragma unroll
    for (int j = 0; j < 4; j++)
      Vf[j] = *(const i64*)(&VT[(16 * j + lr) * WNS8 + ks * 32 + g * 8]);
    #pragma unroll
    for (int i2 = 0; i2 < 4; i2++)
      #pragma unroll
      for (int j = 0; j < 4; j++)
        o[i2][j] = __builtin_amdgcn_mfma_f32_16x16x32_fp8_fp8(Pf[i2], Vf[j], o[i2][j], 0, 0, 0);
  }

  // ---- store O rows q<49 as fp8
  #pragma unroll
  for (int i2 = 0; i2 < 4; i2++)
    #pragma unroll
    for (int r = 0; r < 4; r++) {
      int q = 16 * i2 + 4 * g + r;
      if (q <= 48) {
        size_t obase = tokof(q) * 512 + h * 64 + lr;
        #pragma unroll
        for (int j = 0; j < 4; j++) {
          float v = o[i2][j][r];
          int rr = __builtin_amdgcn_cvt_pk_fp8_f32(v, v, 0, false);
          out[obase + 16 * j] = (unsigned char)rr;
        }
      }
    }
}

extern "C" void kernel_launch(void* const* d_in, const int* in_sizes, int n_in,
                              void* d_out, int out_size, void* d_ws, size_t ws_size,
                              hipStream_t stream) {
  const float* x      = (const float*)d_in[0];
  const float* cpe0_w = (const float*)d_in[1];
  const float* cpe0_b = (const float*)d_in[2];
  const float* cpe1_w = (const float*)d_in[3];
  const float* cpe1_b = (const float*)d_in[4];
  const float* ln1_g  = (const float*)d_in[5];
  const float* ln1_b  = (const float*)d_in[6];
  const float* ln2_g  = (const float*)d_in[7];
  const float* ln2_b  = (const float*)d_in[8];
  const float* qkv_w  = (const float*)d_in[9];
  const float* qkv_b  = (const float*)d_in[10];
  const float* proj_w = (const float*)d_in[11];
  const float* proj_b = (const float*)d_in[12];
  const float* fc1_w  = (const float*)d_in[13];
  const float* fc1_b  = (const float*)d_in[14];
  const float* fc2_w  = (const float*)d_in[15];
  const float* fc2_b  = (const float*)d_in[16];
  float* out = (float*)d_out;
  char* ws = (char*)d_ws;

  unsigned char*  qkvwT8 = (unsigned char*)(ws + 0);            // 1536x512 fp8
  unsigned char*  projwT8 = (unsigned char*)(ws + 1048576);     // 512x512 fp8
  unsigned char*  fc1wT8 = (unsigned char*)(ws + 2097152);      // 2048x512 fp8
  unsigned char*  fc2wT8 = (unsigned char*)(ws + 4194304);      // 512x2048 fp8
  unsigned short* shortcB = (unsigned short*)(ws + 6291456);    // 50176x512 bf16
  unsigned char*  lnb8   = (unsigned char*)(ws + 109051904);    // 50176x512 fp8
  unsigned char*  qkvb8  = (unsigned char*)(ws + 160432128);    // 50176x1536 fp8
  unsigned char*  attnb8 = (unsigned char*)(ws + 314572800);    // 50176x512 fp8
  unsigned char*  gelub8 = (unsigned char*)(ws + 160432128);    // overlay qkvb8
  float* h2 = out;                 // d_out doubles as h2 (f32)

  wtranspose8_kernel<<<(512 * 1536 + 255) / 256, 256, 0, stream>>>(qkv_w, qkvwT8, 512, 1536);
  wtranspose8_kernel<<<(512 * 512 + 255) / 256, 256, 0, stream>>>(proj_w, projwT8, 512, 512);
  wtranspose8_kernel<<<(512 * 2048 + 255) / 256, 256, 0, stream>>>(fc1_w, fc1wT8, 512, 2048);
  wtranspose8_kernel<<<(2048 * 512 + 255) / 256, 256, 0, stream>>>(fc2_w, fc2wT8, 2048, 512);

  const int pixblocks = (BB * HH * WW * 128) / 256;   // 25088
  // shortcut = x + dwconv(x)  (f32 in -> bf16 out)
  cpe_kernel<0, 1><<<pixblocks, 256, 0, stream>>>(x, cpe0_w, cpe0_b, shortcB);
  // ln1: bf16 in -> fp8 out
  ln_kernel<1><<<NTOK / 4, 256, 0, stream>>>(shortcB, ln1_g, ln1_b, lnb8);
  // qkv (fp8 in/out)
  gemm8_kernel<0><<<dim3(12, 196), 512, 0, stream>>>(lnb8, qkvwT8, qkv_b, nullptr,
      nullptr, nullptr, qkvb8, nullptr, NTOK, 1536, 512);
  // window attention, all-fp8
  attn_mfma8_kernel<<<8192, 64, 0, stream>>>(qkvb8, attnb8);
  // h = shortcut + attn@proj_w + b  (fp8 A, bf16 res/out in-place)
  gemm8_kernel<3><<<dim3(4, 196), 512, 0, stream>>>(attnb8, projwT8, proj_b, nullptr,
      shortcB, nullptr, nullptr, shortcB, NTOK, 512, 512);
  // h2 = h + dwconv(h)  (bf16 in -> f32 out = d_out)
  cpe_kernel<1, 0><<<pixblocks, 256, 0, stream>>>(shortcB, cpe1_w, cpe1_b, h2);
  // ln2: f32 in -> fp8 out
  ln_kernel<0><<<NTOK / 4, 256, 0, stream>>>(h2, ln2_g, ln2_b, lnb8);
  // fc1 (fp8): gelu -> fp8
  gemm8_kernel<2><<<dim3(16, 196), 512, 0, stream>>>(lnb8, fc1wT8, fc1_b, nullptr,
      nullptr, nullptr, gelub8, nullptr, NTOK, 2048, 512);
  // fc2 (fp8): f32 out + h2 residual
  gemm8_kernel<1><<<dim3(4, 196), 512, 0, stream>>>(gelub8, fc2wT8, fc2_b, h2,
      nullptr, out, nullptr, nullptr, NTOK, 512, 2048);
}

// Round 12
// 558.706 us; speedup vs baseline: 1.2493x; 1.0463x over previous
//
#include <hip/hip_runtime.h>
#include <stdint.h>

#define HH 112
#define WW 112
#define CC 512
#define BB 4
#define LLEN (HH*WW)
#define NTOK (BB*LLEN)   // 50176
#define NHEADS 8
#define HD 64
#define HIDDEN 2048

typedef __bf16 bf16x8 __attribute__((ext_vector_type(8)));
typedef float f32x4 __attribute__((ext_vector_type(4)));
typedef int i32x8 __attribute__((ext_vector_type(8)));
typedef long i64;

__device__ __forceinline__ unsigned short f2bf(float x) {
  uint32_t u = __float_as_uint(x);
  u += 0x7fffu + ((u >> 16) & 1u);
  return (unsigned short)(u >> 16);
}
__device__ __forceinline__ float bf2f(unsigned short h) {
  return __uint_as_float((uint32_t)h << 16);
}
__device__ __forceinline__ int cvt4_fp8(float a, float b, float c, float d) {
  int r = 0;
  r = __builtin_amdgcn_cvt_pk_fp8_f32(a, b, r, false);
  r = __builtin_amdgcn_cvt_pk_fp8_f32(c, d, r, true);
  return r;
}

__device__ __forceinline__ void gload16(const void* gptr, void* lptr) {
  __builtin_amdgcn_global_load_lds(
      (const __attribute__((address_space(1))) void*)gptr,
      (__attribute__((address_space(3))) void*)lptr,
      16, 0, 0);
}

#define WAITV3() asm volatile("s_waitcnt vmcnt(3)" ::: "memory")
#define WAITV8() asm volatile("s_waitcnt vmcnt(8)" ::: "memory")
#define WAITV0() asm volatile("s_waitcnt vmcnt(0)" ::: "memory")
#define BAR() __builtin_amdgcn_s_barrier()
#define WAITL() do { asm volatile("s_waitcnt lgkmcnt(0)" ::: "memory"); \
                     __builtin_amdgcn_sched_barrier(0); } while (0)

// ---------------- weight transpose (K,N) f32 -> (N,K) fp8, scaled x32 --------
__global__ __launch_bounds__(256) void wtranspose8_kernel(
    const float* __restrict__ w, unsigned char* __restrict__ wt, int K, int N) {
  int idx = blockIdx.x * 256 + threadIdx.x;   // index over OUTPUT (coalesced)
  if (idx >= K * N) return;
  int n = idx / K, k = idx - n * K;
  float v = w[(size_t)k * N + n] * 32.f;
  int r = __builtin_amdgcn_cvt_pk_fp8_f32(v, v, 0, false);
  wt[idx] = (unsigned char)r;
}

// ------- depthwise 3x3 conv + bias + residual; INBF/OUTBF select dtypes -------
template <int INBF, int OUTBF>
__global__ __launch_bounds__(256) void cpe_kernel(
    const void* __restrict__ xin, const float* __restrict__ w,
    const float* __restrict__ bias, void* __restrict__ outp) {
  int tid = blockIdx.x * 256 + threadIdx.x;
  int c = (tid & 127) << 2;      // channel chunk of 4
  int pix = tid >> 7;
  int xx = pix % WW; int t2 = pix / WW; int yy = t2 % HH; int bb = t2 / HH;
  float4 bv = *(const float4*)(&bias[c]);
  float ax = bv.x, ay = bv.y, az = bv.z, aw = bv.w;
  auto ld = [&](size_t eo) -> float4 {
    float4 v;
    if (INBF) {
      uint2 u = *(const uint2*)(&((const unsigned short*)xin)[eo]);
      v.x = bf2f((unsigned short)(u.x & 0xffff));
      v.y = bf2f((unsigned short)(u.x >> 16));
      v.z = bf2f((unsigned short)(u.y & 0xffff));
      v.w = bf2f((unsigned short)(u.y >> 16));
    } else {
      v = *(const float4*)(&((const float*)xin)[eo]);
    }
    return v;
  };
  #pragma unroll
  for (int ky = 0; ky < 3; ky++) {
    int y = yy + ky - 1;
    if ((unsigned)y >= (unsigned)HH) continue;
    #pragma unroll
    for (int kx = 0; kx < 3; kx++) {
      int x2 = xx + kx - 1;
      if ((unsigned)x2 >= (unsigned)WW) continue;
      float4 v = ld((((size_t)bb * HH + y) * WW + x2) * CC + c);
      const float4 wv = *(const float4*)(&w[(ky * 3 + kx) * CC + c]);
      ax = fmaf(v.x, wv.x, ax); ay = fmaf(v.y, wv.y, ay);
      az = fmaf(v.z, wv.z, az); aw = fmaf(v.w, wv.w, aw);
    }
  }
  size_t o = (size_t)pix * CC + c;
  float4 xv = ld(o);
  float rx = xv.x + ax, ry = xv.y + ay, rz = xv.z + az, rw = xv.w + aw;
  if (OUTBF) {
    uint2 pk;
    pk.x = (uint32_t)f2bf(rx) | ((uint32_t)f2bf(ry) << 16);
    pk.y = (uint32_t)f2bf(rz) | ((uint32_t)f2bf(rw) << 16);
    *(uint2*)(&((unsigned short*)outp)[o]) = pk;
  } else {
    float4 r; r.x = rx; r.y = ry; r.z = rz; r.w = rw;
    *(float4*)(&((float*)outp)[o]) = r;
  }
}

// ------- LayerNorm (C=512), one wave/token, fp8 e4m3 out; INBF selects input ----
template <int INBF>
__global__ __launch_bounds__(256) void ln_kernel(
    const void* __restrict__ in, const float* __restrict__ g,
    const float* __restrict__ b, unsigned char* __restrict__ out8) {
  int token = (blockIdx.x * 256 + threadIdx.x) >> 6;
  int lane = threadIdx.x & 63;
  float v[8];
  if (INBF) {
    uint4 u = *(const uint4*)(&((const unsigned short*)in)[(size_t)token * CC + lane * 8]);
    v[0] = bf2f((unsigned short)(u.x & 0xffff)); v[1] = bf2f((unsigned short)(u.x >> 16));
    v[2] = bf2f((unsigned short)(u.y & 0xffff)); v[3] = bf2f((unsigned short)(u.y >> 16));
    v[4] = bf2f((unsigned short)(u.z & 0xffff)); v[5] = bf2f((unsigned short)(u.z >> 16));
    v[6] = bf2f((unsigned short)(u.w & 0xffff)); v[7] = bf2f((unsigned short)(u.w >> 16));
  } else {
    const float* row = (const float*)in + (size_t)token * CC;
    float4 a = *(const float4*)(row + lane * 8);
    float4 c4 = *(const float4*)(row + lane * 8 + 4);
    v[0] = a.x; v[1] = a.y; v[2] = a.z; v[3] = a.w;
    v[4] = c4.x; v[5] = c4.y; v[6] = c4.z; v[7] = c4.w;
  }
  float s = 0.f, ss = 0.f;
  #pragma unroll
  for (int i = 0; i < 8; i++) { s += v[i]; ss += v[i] * v[i]; }
  #pragma unroll
  for (int o = 32; o; o >>= 1) { s += __shfl_xor(s, o, 64); ss += __shfl_xor(ss, o, 64); }
  float mu = s * (1.f / CC);
  float var = ss * (1.f / CC) - mu * mu;
  float rs = rsqrtf(var + 1e-5f);
  float4 g0 = *(const float4*)(&g[lane * 8]);
  float4 g1 = *(const float4*)(&g[lane * 8 + 4]);
  float4 b0 = *(const float4*)(&b[lane * 8]);
  float4 b1 = *(const float4*)(&b[lane * 8 + 4]);
  float o8[8];
  o8[0] = (v[0] - mu) * rs * g0.x + b0.x;
  o8[1] = (v[1] - mu) * rs * g0.y + b0.y;
  o8[2] = (v[2] - mu) * rs * g0.z + b0.z;
  o8[3] = (v[3] - mu) * rs * g0.w + b0.w;
  o8[4] = (v[4] - mu) * rs * g1.x + b1.x;
  o8[5] = (v[5] - mu) * rs * g1.y + b1.y;
  o8[6] = (v[6] - mu) * rs * g1.z + b1.z;
  o8[7] = (v[7] - mu) * rs * g1.w + b1.w;
  uint2 pk;
  pk.x = (uint32_t)cvt4_fp8(o8[0], o8[1], o8[2], o8[3]);
  pk.y = (uint32_t)cvt4_fp8(o8[4], o8[5], o8[6], o8[7]);
  *(uint2*)(&out8[(size_t)token * CC + lane * 8]) = pk;
}

// ==== fp8 GEMM (non-MX), BM256/BN128/BK64 — kept for proj (MODE 3 only) ====
#define BM 256
#define BN 128
#define BK8 64

template <int MODE>
__global__ __launch_bounds__(512) void gemm8_kernel(
    const unsigned char* __restrict__ A, const unsigned char* __restrict__ BT,
    const float* __restrict__ bias, const unsigned short* __restrict__ resB,
    unsigned short* __restrict__ outB16, int M, int N, int K) {
  __shared__ unsigned char ldsb[49152];
  int nwg = gridDim.x * gridDim.y;
  int flat = blockIdx.y * gridDim.x + blockIdx.x;
  int swz = (flat & 7) * (nwg >> 3) + (flat >> 3);
  int bx = swz % gridDim.x, by = swz / gridDim.x;
  const int bm = by * BM, bn = bx * BN;
  const int t = threadIdx.x;
  const int wid = t >> 6, lane = t & 63;
  const int wr = wid >> 1, wc = wid & 1;
  const int lr = lane & 15, g = lane >> 4;
  const int swr = (lr >> 1) & 3;
  const int rb0 = (((g >> 1)      ) ^ swr) * 16 + (g & 1) * 8;
  const int rb1 = (((g >> 1) + 2) ^ swr) * 16 + (g & 1) * 8;
  const int srow = t >> 2;
  const int scol = (((t & 3) ^ ((t >> 3) & 3)) & 3) * 16;
  const size_t arow0 = (size_t)(bm + srow) * K + scol;
  const size_t arow1 = (size_t)(bm + 128 + srow) * K + scol;
  const size_t brow  = (size_t)(bn + srow) * K + scol;
  const int ldso = wid * 1024;

#define STG8(b, kt) do { \
    gload16(&A[arow0 + (kt)], ldsb + (b) * 16384 + ldso); \
    gload16(&A[arow1 + (kt)], ldsb + (b) * 16384 + 8192 + ldso); \
    gload16(&BT[brow + (kt)], ldsb + 32768 + (b) * 8192 + ldso); } while (0)

  f32x4 acc[4][4] = {};
  const int nt = K / BK8;

  STG8(0, 0);
  STG8(1, BK8);

  for (int tile = 0; tile < nt - 1; ++tile) {
    WAITV3(); BAR();
    const unsigned char* as = ldsb + (tile & 1) * 16384;
    const unsigned char* bs = ldsb + 32768 + (tile & 1) * 8192;
    i64 af0[4], af1[4], bf0[4], bf1[4];
    #pragma unroll
    for (int i = 0; i < 4; i++) {
      const unsigned char* p = &as[(wr * 64 + i * 16 + lr) * BK8];
      af0[i] = *(const i64*)(p + rb0);
      af1[i] = *(const i64*)(p + rb1);
    }
    #pragma unroll
    for (int j = 0; j < 4; j++) {
      const unsigned char* p = &bs[(wc * 64 + j * 16 + lr) * BK8];
      bf0[j] = *(const i64*)(p + rb0);
      bf1[j] = *(const i64*)(p + rb1);
    }
    WAITL();
    BAR();
    if (tile + 2 < nt) STG8(tile & 1, (tile + 2) * BK8);
    __builtin_amdgcn_s_setprio(1);
    #pragma unroll
    for (int i = 0; i < 4; i++)
      #pragma unroll
      for (int j = 0; j < 4; j++) {
        acc[i][j] = __builtin_amdgcn_mfma_f32_16x16x32_fp8_fp8(af0[i], bf0[j], acc[i][j], 0, 0, 0);
        acc[i][j] = __builtin_amdgcn_mfma_f32_16x16x32_fp8_fp8(af1[i], bf1[j], acc[i][j], 0, 0, 0);
      }
    __builtin_amdgcn_s_setprio(0);
  }
  {
    WAITV0(); BAR();
    const unsigned char* as = ldsb + ((nt - 1) & 1) * 16384;
    const unsigned char* bs = ldsb + 32768 + ((nt - 1) & 1) * 8192;
    i64 af0[4], af1[4], bf0[4], bf1[4];
    #pragma unroll
    for (int i = 0; i < 4; i++) {
      const unsigned char* p = &as[(wr * 64 + i * 16 + lr) * BK8];
      af0[i] = *(const i64*)(p + rb0);
      af1[i] = *(const i64*)(p + rb1);
    }
    #pragma unroll
    for (int j = 0; j < 4; j++) {
      const unsigned char* p = &bs[(wc * 64 + j * 16 + lr) * BK8];
      bf0[j] = *(const i64*)(p + rb0);
      bf1[j] = *(const i64*)(p + rb1);
    }
    WAITL();
    #pragma unroll
    for (int i = 0; i < 4; i++)
      #pragma unroll
      for (int j = 0; j < 4; j++) {
        acc[i][j] = __builtin_amdgcn_mfma_f32_16x16x32_fp8_fp8(af0[i], bf0[j], acc[i][j], 0, 0, 0);
        acc[i][j] = __builtin_amdgcn_mfma_f32_16x16x32_fp8_fp8(af1[i], bf1[j], acc[i][j], 0, 0, 0);
      }
  }
#undef STG8

  // ---- epilogue (restaged): MODE 3: out bf16 = acc/32 + bias + res_bf16 ----
  {
    const float SC = 0.03125f;
    float* eps = (float*)ldsb;
    const int erow = t >> 3;
    const int ecol0 = (t & 7) * 16;
    const int wrow = wr * 16 + (lane >> 4) * 4;
    const int wcol = wc * 64 + lr;
    const int gr_base = bm + (erow >> 4) * 64 + (erow & 15);
    const int gc0 = bn + ecol0;
    float bv[16];
    #pragma unroll
    for (int c4 = 0; c4 < 4; c4++)
      *(float4*)&bv[c4 * 4] = *(const float4*)&bias[gc0 + c4 * 4];
    #pragma unroll
    for (int i = 0; i < 4; i++) {
      __syncthreads();
      #pragma unroll
      for (int j = 0; j < 4; j++)
        #pragma unroll
        for (int r = 0; r < 4; r++)
          eps[(wrow + r) * 132 + wcol + j * 16] = acc[i][j][r];
      __syncthreads();
      float vv[16];
      #pragma unroll
      for (int c4 = 0; c4 < 4; c4++)
        *(float4*)&vv[c4 * 4] = *(const float4*)&eps[erow * 132 + ecol0 + c4 * 4];
      const size_t off = (size_t)(gr_base + i * 16) * N + gc0;
      uint4 r0 = *(const uint4*)&resB[off];
      uint4 r1 = *(const uint4*)&resB[off + 8];
      unsigned short ob[16];
      const uint32_t* rp = (const uint32_t*)&r0;
      #pragma unroll
      for (int c = 0; c < 8; c++) {
        uint32_t u = rp[c >> 1];
        float rv = bf2f((unsigned short)((c & 1) ? (u >> 16) : (u & 0xffff)));
        ob[c] = f2bf(vv[c] * SC + bv[c] + rv);
      }
      const uint32_t* rp1 = (const uint32_t*)&r1;
      #pragma unroll
      for (int c = 0; c < 8; c++) {
        uint32_t u = rp1[c >> 1];
        float rv = bf2f((unsigned short)((c & 1) ? (u >> 16) : (u & 0xffff)));
        ob[8 + c] = f2bf(vv[8 + c] * SC + bv[8 + c] + rv);
      }
      *(uint4*)&outB16[off]     = *(uint4*)&ob[0];
      *(uint4*)&outB16[off + 8] = *(uint4*)&ob[8];
    }
  }
}

// ==== MX-scaled fp8 GEMM: 16x16x128 f8f6f4 (unit scales), BM128/BN128/BKpair128 ====
// 256 thr = 4 waves (2x2). 2-buf pair (64KB, 2 blk/CU), restage-after-barrier,
// counted vmcnt(8). LDS[row][chunk c] = global[row][c ^ (row&7)] (16B chunks, 8/row).
// MODE 0: out fp8 = C/32 + bias (qkv); MODE 1: out f32 = C/32+bias+res (fc2);
// MODE 2: out fp8 = gelu(C/32 + bias) (fc1)
__device__ __forceinline__ i32x8 ld_frag128(const unsigned char* base, int row, int g, int lrm7) {
  const uint4 lo = *(const uint4*)(base + row * 128 + (((2 * g)     ^ lrm7) * 16));
  const uint4 hi = *(const uint4*)(base + row * 128 + (((2 * g + 1) ^ lrm7) * 16));
  i32x8 r;
  r[0] = lo.x; r[1] = lo.y; r[2] = lo.z; r[3] = lo.w;
  r[4] = hi.x; r[5] = hi.y; r[6] = hi.z; r[7] = hi.w;
  return r;
}

template <int MODE>
__global__ __launch_bounds__(256) void gemm8mx_kernel(
    const unsigned char* __restrict__ A, const unsigned char* __restrict__ BT,
    const float* __restrict__ bias, const float* __restrict__ res,
    float* __restrict__ outF, unsigned char* __restrict__ outB8,
    int M, int N, int K) {
  __shared__ unsigned char ldsb[65536];   // A pairbufs @0,16K ; B @32K,48K
  const int SCALE1 = 0x7F7F7F7F;          // e8m0 127 in every byte = x1.0
  int nwg = gridDim.x * gridDim.y;
  int flat = blockIdx.y * gridDim.x + blockIdx.x;
  int swz = (flat & 7) * (nwg >> 3) + (flat >> 3);
  int bx = swz % gridDim.x, by = swz / gridDim.x;
  const int bm = by * 128, bn = bx * 128;
  const int t = threadIdx.x;
  const int wid = t >> 6, lane = t & 63;
  const int wr = wid >> 1, wc = wid & 1;          // 2x2 wave grid, 64x64 per wave
  const int lr = lane & 15, g = lane >> 4, lrm7 = lane & 7;
  // staging: wave w gload q stages rows (w*4+q)*8 + (lane>>3), chunk lane&7 (16B)
  const int wq0 = wid * 4096;                     // LDS byte base for q=0
  const int scol = (((lane & 7) ^ ((lane >> 3) & 7)) & 7) * 16;
  const size_t aB0 = (size_t)(bm + wid * 32 + ((t >> 3) & 7)) * K + scol;
  const size_t bB0 = (size_t)(bn + wid * 32 + ((t >> 3) & 7)) * K + scol;

#define STGMX(p, kt) do { \
    _Pragma("unroll") for (int q_ = 0; q_ < 4; q_++) { \
      gload16(&A[aB0 + (size_t)q_ * 8 * K + (kt)],  ldsb + (p) * 16384 + wq0 + q_ * 1024); \
      gload16(&BT[bB0 + (size_t)q_ * 8 * K + (kt)], ldsb + 32768 + (p) * 16384 + wq0 + q_ * 1024); \
    } } while (0)

  f32x4 acc[4][4] = {};
  const int npt = K / 128;

  STGMX(0, 0);
  STGMX(1, 128);

  for (int pt = 0; pt < npt - 1; ++pt) {
    WAITV8(); BAR();
    const unsigned char* as = ldsb + (pt & 1) * 16384;
    const unsigned char* bs = ldsb + 32768 + (pt & 1) * 16384;
    i32x8 af[4], bf[4];
    #pragma unroll
    for (int i = 0; i < 4; i++)
      af[i] = ld_frag128(as, wr * 64 + i * 16 + lr, g, lrm7);
    #pragma unroll
    for (int j = 0; j < 4; j++)
      bf[j] = ld_frag128(bs, wc * 64 + j * 16 + lr, g, lrm7);
    WAITL();
    BAR();
    if (pt + 2 < npt) STGMX(pt & 1, (pt + 2) * 128);
    __builtin_amdgcn_s_setprio(1);
    #pragma unroll
    for (int i = 0; i < 4; i++)
      #pragma unroll
      for (int j = 0; j < 4; j++)
        acc[i][j] = __builtin_amdgcn_mfma_scale_f32_16x16x128_f8f6f4(
            af[i], bf[j], acc[i][j], 0, 0, 0, SCALE1, 0, SCALE1);
    __builtin_amdgcn_s_setprio(0);
  }
  {
    WAITV0(); BAR();
    const unsigned char* as = ldsb + ((npt - 1) & 1) * 16384;
    const unsigned char* bs = ldsb + 32768 + ((npt - 1) & 1) * 16384;
    i32x8 af[4], bf[4];
    #pragma unroll
    for (int i = 0; i < 4; i++)
      af[i] = ld_frag128(as, wr * 64 + i * 16 + lr, g, lrm7);
    #pragma unroll
    for (int j = 0; j < 4; j++)
      bf[j] = ld_frag128(bs, wc * 64 + j * 16 + lr, g, lrm7);
    WAITL();
    #pragma unroll
    for (int i = 0; i < 4; i++)
      #pragma unroll
      for (int j = 0; j < 4; j++)
        acc[i][j] = __builtin_amdgcn_mfma_scale_f32_16x16x128_f8f6f4(
            af[i], bf[j], acc[i][j], 0, 0, 0, SCALE1, 0, SCALE1);
  }
#undef STGMX

  // ---- epilogue: 2 passes of 64 rows x 128 cols via LDS restage ----
  {
    const float SC = 0.03125f;
    float* eps = (float*)ldsb;              // 64*132*4 = 33.8KB < 64KB
    const int erow = t >> 2;                // 0..63
    const int cb = (t & 3) * 4;             // col base; cols cb + c*16
    float4 bv4[8];
    #pragma unroll
    for (int c = 0; c < 8; c++)
      bv4[c] = *(const float4*)&bias[bn + cb + c * 16];
    #pragma unroll
    for (int p = 0; p < 2; p++) {
      __syncthreads();
      if (wr == p) {
        #pragma unroll
        for (int i = 0; i < 4; i++)
          #pragma unroll
          for (int j = 0; j < 4; j++)
            #pragma unroll
            for (int r = 0; r < 4; r++)
              eps[(i * 16 + g * 4 + r) * 132 + wc * 64 + j * 16 + lr] = acc[i][j][r];
      }
      __syncthreads();
      const size_t rowoff = (size_t)(bm + p * 64 + erow) * N + bn + cb;
      #pragma unroll
      for (int c = 0; c < 8; c++) {
        float4 vv = *(const float4*)&eps[erow * 132 + cb + c * 16];
        float v0 = vv.x * SC + bv4[c].x;
        float v1 = vv.y * SC + bv4[c].y;
        float v2 = vv.z * SC + bv4[c].z;
        float v3 = vv.w * SC + bv4[c].w;
        if (MODE == 1) {
          float4 rv = *(const float4*)&res[rowoff + c * 16];
          float4 ov;
          ov.x = v0 + rv.x; ov.y = v1 + rv.y; ov.z = v2 + rv.z; ov.w = v3 + rv.w;
          *(float4*)&outF[rowoff + c * 16] = ov;
        } else if (MODE == 0) {
          *(uint32_t*)&outB8[rowoff + c * 16] = (uint32_t)cvt4_fp8(v0, v1, v2, v3);
        } else {
          float gv[4];
          float vin[4] = {v0, v1, v2, v3};
          #pragma unroll
          for (int e = 0; e < 4; e++) {
            float v = vin[e];
            float a2 = v * v;
            float w = v * fmaf(a2, -0.1029436f, -2.3024849f);
            float sg = __builtin_amdgcn_rcpf(1.f + __builtin_amdgcn_exp2f(w));
            gv[e] = v * sg;
          }
          *(uint32_t*)&outB8[rowoff + c * 16] = (uint32_t)cvt4_fp8(gv[0], gv[1], gv[2], gv[3]);
        }
      }
    }
  }
}

// -------- fp8 MFMA window attention: 1 wave per (window, head), all-fp8 IO -------
#define WNS8 72   // byte stride: 64B data + 8 pad, 8-aligned

__global__ __launch_bounds__(64) void attn_mfma8_kernel(
    const unsigned char* __restrict__ qkv, unsigned char* __restrict__ out) {
  __shared__ unsigned char VT[64 * WNS8];   // V^T: [d][k] fp8
  __shared__ unsigned char Ps[64 * WNS8];   // P:   [q][k] fp8
  const int task = blockIdx.x;
  const int win = task >> 3, h = task & 7;
  const int b = win >> 8, wy = (win >> 4) & 15, wx = win & 15;
  const int lane = threadIdx.x;
  const int lr = lane & 15, g = lane >> 4;

  auto tokof = [&](int r) {
    int rr = r > 48 ? 48 : r;
    int y = rr / 7, x2 = rr - y * 7;
    return (size_t)(b * LLEN + (wy * 7 + y) * WW + wx * 7 + x2);
  };

  {
    size_t vbase = tokof(lane) * 1536 + 1024 + h * 64;
    bool valid = lane <= 48;
    #pragma unroll
    for (int c = 0; c < 4; c++) {
      uint4 v = *(const uint4*)(&qkv[vbase + c * 16]);
      const unsigned char* pv = (const unsigned char*)&v;
      #pragma unroll
      for (int e = 0; e < 16; e++)
        VT[(c * 16 + e) * WNS8 + lane] = valid ? pv[e] : (unsigned char)0;
    }
  }

  size_t tok[4];
  #pragma unroll
  for (int i2 = 0; i2 < 4; i2++) tok[i2] = tokof(i2 * 16 + lr);
  i64 Qf[4][2], Kf[4][2];
  #pragma unroll
  for (int i2 = 0; i2 < 4; i2++) {
    size_t base = tok[i2] * 1536 + h * 64 + g * 8;
    #pragma unroll
    for (int ks = 0; ks < 2; ks++) {
      Qf[i2][ks] = *(const i64*)(&qkv[base + ks * 32]);
      Kf[i2][ks] = *(const i64*)(&qkv[base + 512 + ks * 32]);
    }
  }

  f32x4 acc[4][4] = {};
  #pragma unroll
  for (int ks = 0; ks < 2; ks++)
    #pragma unroll
    for (int i2 = 0; i2 < 4; i2++)
      #pragma unroll
      for (int j = 0; j < 4; j++)
        acc[i2][j] = __builtin_amdgcn_mfma_f32_16x16x32_fp8_fp8(Kf[i2][ks], Qf[j][ks], acc[i2][j], 0, 0, 0);

  #pragma unroll
  for (int j = 0; j < 4; j++) {
    float mx = -1e30f;
    #pragma unroll
    for (int i2 = 0; i2 < 4; i2++)
      #pragma unroll
      for (int r = 0; r < 4; r++) {
        int k = 16 * i2 + 4 * g + r;
        mx = fmaxf(mx, (k <= 48) ? acc[i2][j][r] : -1e30f);
      }
    mx = fmaxf(mx, __shfl_xor(mx, 16, 64));
    mx = fmaxf(mx, __shfl_xor(mx, 32, 64));
    float p[4][4];
    float sum = 0.f;
    #pragma unroll
    for (int i2 = 0; i2 < 4; i2++)
      #pragma unroll
      for (int r = 0; r < 4; r++) {
        int k = 16 * i2 + 4 * g + r;
        float e = (k <= 48) ? __expf(0.125f * (acc[i2][j][r] - mx)) : 0.f;
        p[i2][r] = e; sum += e;
      }
    sum += __shfl_xor(sum, 16, 64);
    sum += __shfl_xor(sum, 32, 64);
    float inv = 1.f / sum;
    int q = 16 * j + lr;
    #pragma unroll
    for (int i2 = 0; i2 < 4; i2++) {
      uint32_t w = (uint32_t)cvt4_fp8(p[i2][0] * inv, p[i2][1] * inv,
                                      p[i2][2] * inv, p[i2][3] * inv);
      *(uint32_t*)(&Ps[q * WNS8 + 16 * i2 + 4 * g]) = w;
    }
  }

  __syncthreads();

  f32x4 o[4][4] = {};
  #pragma unroll
  for (int ks = 0; ks < 2; ks++) {
    i64 Pf[4], Vf[4];
    #pragma unroll
    for (int i2 = 0; i2 < 4; i2++)
      Pf[i2] = *(const i64*)(&Ps[(16 * i2 + lr) * WNS8 + ks * 32 + g * 8]);
    #pragma unroll
    for (int j = 0; j < 4; j++)
      Vf[j] = *(const i64*)(&VT[(16 * j + lr) * WNS8 + ks * 32 + g * 8]);
    #pragma unroll
    for (int i2 = 0; i2 < 4; i2++)
      #pragma unroll
      for (int j = 0; j < 4; j++)
        o[i2][j] = __builtin_amdgcn_mfma_f32_16x16x32_fp8_fp8(Pf[i2], Vf[j], o[i2][j], 0, 0, 0);
  }

  #pragma unroll
  for (int i2 = 0; i2 < 4; i2++)
    #pragma unroll
    for (int r = 0; r < 4; r++) {
      int q = 16 * i2 + 4 * g + r;
      if (q <= 48) {
        size_t obase = tokof(q) * 512 + h * 64 + lr;
        #pragma unroll
        for (int j = 0; j < 4; j++) {
          float v = o[i2][j][r];
          int rr = __builtin_amdgcn_cvt_pk_fp8_f32(v, v, 0, false);
          out[obase + 16 * j] = (unsigned char)rr;
        }
      }
    }
}

extern "C" void kernel_launch(void* const* d_in, const int* in_sizes, int n_in,
                              void* d_out, int out_size, void* d_ws, size_t ws_size,
                              hipStream_t stream) {
  const float* x      = (const float*)d_in[0];
  const float* cpe0_w = (const float*)d_in[1];
  const float* cpe0_b = (const float*)d_in[2];
  const float* cpe1_w = (const float*)d_in[3];
  const float* cpe1_b = (const float*)d_in[4];
  const float* ln1_g  = (const float*)d_in[5];
  const float* ln1_b  = (const float*)d_in[6];
  const float* ln2_g  = (const float*)d_in[7];
  const float* ln2_b  = (const float*)d_in[8];
  const float* qkv_w  = (const float*)d_in[9];
  const float* qkv_b  = (const float*)d_in[10];
  const float* proj_w = (const float*)d_in[11];
  const float* proj_b = (const float*)d_in[12];
  const float* fc1_w  = (const float*)d_in[13];
  const float* fc1_b  = (const float*)d_in[14];
  const float* fc2_w  = (const float*)d_in[15];
  const float* fc2_b  = (const float*)d_in[16];
  float* out = (float*)d_out;
  char* ws = (char*)d_ws;

  unsigned char*  qkvwT8 = (unsigned char*)(ws + 0);            // 1536x512 fp8
  unsigned char*  projwT8 = (unsigned char*)(ws + 1048576);     // 512x512 fp8
  unsigned char*  fc1wT8 = (unsigned char*)(ws + 2097152);      // 2048x512 fp8
  unsigned char*  fc2wT8 = (unsigned char*)(ws + 4194304);      // 512x2048 fp8
  unsigned short* shortcB = (unsigned short*)(ws + 6291456);    // 50176x512 bf16
  unsigned char*  lnb8   = (unsigned char*)(ws + 109051904);    // 50176x512 fp8
  unsigned char*  qkvb8  = (unsigned char*)(ws + 160432128);    // 50176x1536 fp8
  unsigned char*  attnb8 = (unsigned char*)(ws + 314572800);    // 50176x512 fp8
  unsigned char*  gelub8 = (unsigned char*)(ws + 160432128);    // overlay qkvb8
  float* h2 = out;                 // d_out doubles as h2 (f32)

  wtranspose8_kernel<<<(512 * 1536 + 255) / 256, 256, 0, stream>>>(qkv_w, qkvwT8, 512, 1536);
  wtranspose8_kernel<<<(512 * 512 + 255) / 256, 256, 0, stream>>>(proj_w, projwT8, 512, 512);
  wtranspose8_kernel<<<(512 * 2048 + 255) / 256, 256, 0, stream>>>(fc1_w, fc1wT8, 512, 2048);
  wtranspose8_kernel<<<(2048 * 512 + 255) / 256, 256, 0, stream>>>(fc2_w, fc2wT8, 2048, 512);

  const int pixblocks = (BB * HH * WW * 128) / 256;   // 25088
  // shortcut = x + dwconv(x)  (f32 in -> bf16 out)
  cpe_kernel<0, 1><<<pixblocks, 256, 0, stream>>>(x, cpe0_w, cpe0_b, shortcB);
  // ln1: bf16 in -> fp8 out
  ln_kernel<1><<<NTOK / 4, 256, 0, stream>>>(shortcB, ln1_g, ln1_b, lnb8);
  // qkv (MX fp8): fp8 out
  gemm8mx_kernel<0><<<dim3(12, 392), 256, 0, stream>>>(lnb8, qkvwT8, qkv_b, nullptr,
      nullptr, qkvb8, NTOK, 1536, 512);
  // window attention, all-fp8
  attn_mfma8_kernel<<<8192, 64, 0, stream>>>(qkvb8, attnb8);
  // h = shortcut + attn@proj_w + b  (fp8 A, bf16 res/out in-place; non-MX proven)
  gemm8_kernel<3><<<dim3(4, 196), 512, 0, stream>>>(attnb8, projwT8, proj_b,
      shortcB, shortcB, NTOK, 512, 512);
  // h2 = h + dwconv(h)  (bf16 in -> f32 out = d_out)
  cpe_kernel<1, 0><<<pixblocks, 256, 0, stream>>>(shortcB, cpe1_w, cpe1_b, h2);
  // ln2: f32 in -> fp8 out
  ln_kernel<0><<<NTOK / 4, 256, 0, stream>>>(h2, ln2_g, ln2_b, lnb8);
  // fc1 (MX fp8): gelu -> fp8
  gemm8mx_kernel<2><<<dim3(16, 392), 256, 0, stream>>>(lnb8, fc1wT8, fc1_b, nullptr,
      nullptr, gelub8, NTOK, 2048, 512);
  // fc2 (MX fp8): f32 out + h2 residual
  gemm8mx_kernel<1><<<dim3(4, 392), 256, 0, stream>>>(gelub8, fc2wT8, fc2_b, h2,
      out, nullptr, NTOK, 512, 2048);
}

// Round 13
// 546.882 us; speedup vs baseline: 1.2763x; 1.0216x over previous
//
#include <hip/hip_runtime.h>
#include <stdint.h>

#define HH 112
#define WW 112
#define CC 512
#define BB 4
#define LLEN (HH*WW)
#define NTOK (BB*LLEN)   // 50176
#define NHEADS 8
#define HD 64
#define HIDDEN 2048

typedef __bf16 bf16x8 __attribute__((ext_vector_type(8)));
typedef float f32x4 __attribute__((ext_vector_type(4)));
typedef int i32x8 __attribute__((ext_vector_type(8)));
typedef long i64;

__device__ __forceinline__ unsigned short f2bf(float x) {
  uint32_t u = __float_as_uint(x);
  u += 0x7fffu + ((u >> 16) & 1u);
  return (unsigned short)(u >> 16);
}
__device__ __forceinline__ float bf2f(unsigned short h) {
  return __uint_as_float((uint32_t)h << 16);
}
__device__ __forceinline__ int cvt4_fp8(float a, float b, float c, float d) {
  int r = 0;
  r = __builtin_amdgcn_cvt_pk_fp8_f32(a, b, r, false);
  r = __builtin_amdgcn_cvt_pk_fp8_f32(c, d, r, true);
  return r;
}

__device__ __forceinline__ void gload16(const void* gptr, void* lptr) {
  __builtin_amdgcn_global_load_lds(
      (const __attribute__((address_space(1))) void*)gptr,
      (__attribute__((address_space(3))) void*)lptr,
      16, 0, 0);
}

#define WAITV3() asm volatile("s_waitcnt vmcnt(3)" ::: "memory")
#define WAITV8() asm volatile("s_waitcnt vmcnt(8)" ::: "memory")
#define WAITV0() asm volatile("s_waitcnt vmcnt(0)" ::: "memory")
#define BAR() __builtin_amdgcn_s_barrier()
#define WAITL() do { asm volatile("s_waitcnt lgkmcnt(0)" ::: "memory"); \
                     __builtin_amdgcn_sched_barrier(0); } while (0)

// ---------------- weight transpose (K,N) f32 -> (N,K) fp8, scaled x32 --------
__global__ __launch_bounds__(256) void wtranspose8_kernel(
    const float* __restrict__ w, unsigned char* __restrict__ wt, int K, int N) {
  int idx = blockIdx.x * 256 + threadIdx.x;   // index over OUTPUT (coalesced)
  if (idx >= K * N) return;
  int n = idx / K, k = idx - n * K;
  float v = w[(size_t)k * N + n] * 32.f;
  int r = __builtin_amdgcn_cvt_pk_fp8_f32(v, v, 0, false);
  wt[idx] = (unsigned char)r;
}

// ==== FUSED depthwise 3x3 conv + residual + LayerNorm ====
// INBF: input dtype (0=f32, 1=bf16). OUTBF: conv+res output dtype (1=bf16, 0=f32).
// Always also emits fp8 LN(conv+res) to ln8. 256 thr = 2 pixels x 128 thr (4 ch).
template <int INBF, int OUTBF>
__global__ __launch_bounds__(256) void cpe_ln_kernel(
    const void* __restrict__ xin, const float* __restrict__ w,
    const float* __restrict__ bias, const float* __restrict__ lng,
    const float* __restrict__ lnb, void* __restrict__ outp,
    unsigned char* __restrict__ ln8) {
  __shared__ float red[2][2][2];
  int tid = blockIdx.x * 256 + threadIdx.x;
  int c = (tid & 127) << 2;      // channel chunk of 4
  int pix = tid >> 7;
  int xx = pix % WW; int t2 = pix / WW; int yy = t2 % HH; int bb = t2 / HH;
  float4 bv = *(const float4*)(&bias[c]);
  float ax = bv.x, ay = bv.y, az = bv.z, aw = bv.w;
  auto ld = [&](size_t eo) -> float4 {
    float4 v;
    if (INBF) {
      uint2 u = *(const uint2*)(&((const unsigned short*)xin)[eo]);
      v.x = bf2f((unsigned short)(u.x & 0xffff));
      v.y = bf2f((unsigned short)(u.x >> 16));
      v.z = bf2f((unsigned short)(u.y & 0xffff));
      v.w = bf2f((unsigned short)(u.y >> 16));
    } else {
      v = *(const float4*)(&((const float*)xin)[eo]);
    }
    return v;
  };
  #pragma unroll
  for (int ky = 0; ky < 3; ky++) {
    int y = yy + ky - 1;
    if ((unsigned)y >= (unsigned)HH) continue;
    #pragma unroll
    for (int kx = 0; kx < 3; kx++) {
      int x2 = xx + kx - 1;
      if ((unsigned)x2 >= (unsigned)WW) continue;
      float4 v = ld((((size_t)bb * HH + y) * WW + x2) * CC + c);
      const float4 wv = *(const float4*)(&w[(ky * 3 + kx) * CC + c]);
      ax = fmaf(v.x, wv.x, ax); ay = fmaf(v.y, wv.y, ay);
      az = fmaf(v.z, wv.z, az); aw = fmaf(v.w, wv.w, aw);
    }
  }
  size_t o = (size_t)pix * CC + c;
  float4 xv = ld(o);
  float rx = xv.x + ax, ry = xv.y + ay, rz = xv.z + az, rw = xv.w + aw;
  // main output
  if (OUTBF) {
    uint2 pk;
    pk.x = (uint32_t)f2bf(rx) | ((uint32_t)f2bf(ry) << 16);
    pk.y = (uint32_t)f2bf(rz) | ((uint32_t)f2bf(rw) << 16);
    *(uint2*)(&((unsigned short*)outp)[o]) = pk;
  } else {
    float4 r; r.x = rx; r.y = ry; r.z = rz; r.w = rw;
    *(float4*)(&((float*)outp)[o]) = r;
  }
  // LayerNorm over the 512 channels of this pixel (128 threads, 2 waves)
  float s = rx + ry + rz + rw;
  float ss = rx * rx + ry * ry + rz * rz + rw * rw;
  #pragma unroll
  for (int of = 32; of; of >>= 1) {
    s += __shfl_xor(s, of, 64);
    ss += __shfl_xor(ss, of, 64);
  }
  const int lp = threadIdx.x >> 7;            // local pixel 0/1
  const int half = (threadIdx.x >> 6) & 1;    // wave-half within pixel
  if ((threadIdx.x & 63) == 0) { red[lp][half][0] = s; red[lp][half][1] = ss; }
  __syncthreads();
  float st  = red[lp][0][0] + red[lp][1][0];
  float sst = red[lp][0][1] + red[lp][1][1];
  float mu = st * (1.f / CC);
  float var = sst * (1.f / CC) - mu * mu;
  float rsd = rsqrtf(var + 1e-5f);
  float4 gv = *(const float4*)(&lng[c]);
  float4 b2 = *(const float4*)(&lnb[c]);
  float o0 = (rx - mu) * rsd * gv.x + b2.x;
  float o1 = (ry - mu) * rsd * gv.y + b2.y;
  float o2 = (rz - mu) * rsd * gv.z + b2.z;
  float o3 = (rw - mu) * rsd * gv.w + b2.w;
  *(uint32_t*)(&ln8[o]) = (uint32_t)cvt4_fp8(o0, o1, o2, o3);
}

// ==== fp8 GEMM (non-MX), BM256/BN128/BK64 — proj (MODE 3 only), K templated ====
#define BM 256
#define BN 128
#define BK8 64

template <int MODE, int K>
__global__ __launch_bounds__(512) void gemm8_kernel(
    const unsigned char* __restrict__ A, const unsigned char* __restrict__ BT,
    const float* __restrict__ bias, const unsigned short* __restrict__ resB,
    unsigned short* __restrict__ outB16, int M, int N) {
  __shared__ unsigned char ldsb[49152];
  int nwg = gridDim.x * gridDim.y;
  int flat = blockIdx.y * gridDim.x + blockIdx.x;
  int swz = (flat & 7) * (nwg >> 3) + (flat >> 3);
  int bx = swz % gridDim.x, by = swz / gridDim.x;
  const int bm = by * BM, bn = bx * BN;
  const int t = threadIdx.x;
  const int wid = t >> 6, lane = t & 63;
  const int wr = wid >> 1, wc = wid & 1;
  const int lr = lane & 15, g = lane >> 4;
  const int swr = (lr >> 1) & 3;
  const int rb0 = (((g >> 1)      ) ^ swr) * 16 + (g & 1) * 8;
  const int rb1 = (((g >> 1) + 2) ^ swr) * 16 + (g & 1) * 8;
  const int srow = t >> 2;
  const int scol = (((t & 3) ^ ((t >> 3) & 3)) & 3) * 16;
  const size_t arow0 = (size_t)(bm + srow) * K + scol;
  const size_t arow1 = (size_t)(bm + 128 + srow) * K + scol;
  const size_t brow  = (size_t)(bn + srow) * K + scol;
  const int ldso = wid * 1024;

#define STG8(b, kt) do { \
    gload16(&A[arow0 + (kt)], ldsb + (b) * 16384 + ldso); \
    gload16(&A[arow1 + (kt)], ldsb + (b) * 16384 + 8192 + ldso); \
    gload16(&BT[brow + (kt)], ldsb + 32768 + (b) * 8192 + ldso); } while (0)

  f32x4 acc[4][4] = {};
  constexpr int nt = K / BK8;

  STG8(0, 0);
  STG8(1, BK8);

  #pragma unroll
  for (int tile = 0; tile < nt - 1; ++tile) {
    WAITV3(); BAR();
    const unsigned char* as = ldsb + (tile & 1) * 16384;
    const unsigned char* bs = ldsb + 32768 + (tile & 1) * 8192;
    i64 af0[4], af1[4], bf0[4], bf1[4];
    #pragma unroll
    for (int i = 0; i < 4; i++) {
      const unsigned char* p = &as[(wr * 64 + i * 16 + lr) * BK8];
      af0[i] = *(const i64*)(p + rb0);
      af1[i] = *(const i64*)(p + rb1);
    }
    #pragma unroll
    for (int j = 0; j < 4; j++) {
      const unsigned char* p = &bs[(wc * 64 + j * 16 + lr) * BK8];
      bf0[j] = *(const i64*)(p + rb0);
      bf1[j] = *(const i64*)(p + rb1);
    }
    WAITL();
    BAR();
    if (tile + 2 < nt) STG8(tile & 1, (tile + 2) * BK8);
    __builtin_amdgcn_s_setprio(1);
    #pragma unroll
    for (int i = 0; i < 4; i++)
      #pragma unroll
      for (int j = 0; j < 4; j++) {
        acc[i][j] = __builtin_amdgcn_mfma_f32_16x16x32_fp8_fp8(af0[i], bf0[j], acc[i][j], 0, 0, 0);
        acc[i][j] = __builtin_amdgcn_mfma_f32_16x16x32_fp8_fp8(af1[i], bf1[j], acc[i][j], 0, 0, 0);
      }
    __builtin_amdgcn_s_setprio(0);
  }
  {
    WAITV0(); BAR();
    const unsigned char* as = ldsb + ((nt - 1) & 1) * 16384;
    const unsigned char* bs = ldsb + 32768 + ((nt - 1) & 1) * 8192;
    i64 af0[4], af1[4], bf0[4], bf1[4];
    #pragma unroll
    for (int i = 0; i < 4; i++) {
      const unsigned char* p = &as[(wr * 64 + i * 16 + lr) * BK8];
      af0[i] = *(const i64*)(p + rb0);
      af1[i] = *(const i64*)(p + rb1);
    }
    #pragma unroll
    for (int j = 0; j < 4; j++) {
      const unsigned char* p = &bs[(wc * 64 + j * 16 + lr) * BK8];
      bf0[j] = *(const i64*)(p + rb0);
      bf1[j] = *(const i64*)(p + rb1);
    }
    WAITL();
    #pragma unroll
    for (int i = 0; i < 4; i++)
      #pragma unroll
      for (int j = 0; j < 4; j++) {
        acc[i][j] = __builtin_amdgcn_mfma_f32_16x16x32_fp8_fp8(af0[i], bf0[j], acc[i][j], 0, 0, 0);
        acc[i][j] = __builtin_amdgcn_mfma_f32_16x16x32_fp8_fp8(af1[i], bf1[j], acc[i][j], 0, 0, 0);
      }
  }
#undef STG8

  // ---- epilogue (restaged): MODE 3: out bf16 = acc/32 + bias + res_bf16 ----
  {
    const float SC = 0.03125f;
    float* eps = (float*)ldsb;
    const int erow = t >> 3;
    const int ecol0 = (t & 7) * 16;
    const int wrow = wr * 16 + (lane >> 4) * 4;
    const int wcol = wc * 64 + lr;
    const int gr_base = bm + (erow >> 4) * 64 + (erow & 15);
    const int gc0 = bn + ecol0;
    float bv[16];
    #pragma unroll
    for (int c4 = 0; c4 < 4; c4++)
      *(float4*)&bv[c4 * 4] = *(const float4*)&bias[gc0 + c4 * 4];
    #pragma unroll
    for (int i = 0; i < 4; i++) {
      __syncthreads();
      #pragma unroll
      for (int j = 0; j < 4; j++)
        #pragma unroll
        for (int r = 0; r < 4; r++)
          eps[(wrow + r) * 132 + wcol + j * 16] = acc[i][j][r];
      __syncthreads();
      float vv[16];
      #pragma unroll
      for (int c4 = 0; c4 < 4; c4++)
        *(float4*)&vv[c4 * 4] = *(const float4*)&eps[erow * 132 + ecol0 + c4 * 4];
      const size_t off = (size_t)(gr_base + i * 16) * N + gc0;
      uint4 r0 = *(const uint4*)&resB[off];
      uint4 r1 = *(const uint4*)&resB[off + 8];
      unsigned short ob[16];
      const uint32_t* rp = (const uint32_t*)&r0;
      #pragma unroll
      for (int c = 0; c < 8; c++) {
        uint32_t u = rp[c >> 1];
        float rv = bf2f((unsigned short)((c & 1) ? (u >> 16) : (u & 0xffff)));
        ob[c] = f2bf(vv[c] * SC + bv[c] + rv);
      }
      const uint32_t* rp1 = (const uint32_t*)&r1;
      #pragma unroll
      for (int c = 0; c < 8; c++) {
        uint32_t u = rp1[c >> 1];
        float rv = bf2f((unsigned short)((c & 1) ? (u >> 16) : (u & 0xffff)));
        ob[8 + c] = f2bf(vv[8 + c] * SC + bv[8 + c] + rv);
      }
      *(uint4*)&outB16[off]     = *(uint4*)&ob[0];
      *(uint4*)&outB16[off + 8] = *(uint4*)&ob[8];
    }
  }
}

// ==== MX-scaled fp8 GEMM: 16x16x128 f8f6f4 (unit scales), K templated ====
__device__ __forceinline__ i32x8 ld_frag128(const unsigned char* base, int row, int g, int lrm7) {
  const uint4 lo = *(const uint4*)(base + row * 128 + (((2 * g)     ^ lrm7) * 16));
  const uint4 hi = *(const uint4*)(base + row * 128 + (((2 * g + 1) ^ lrm7) * 16));
  i32x8 r;
  r[0] = lo.x; r[1] = lo.y; r[2] = lo.z; r[3] = lo.w;
  r[4] = hi.x; r[5] = hi.y; r[6] = hi.z; r[7] = hi.w;
  return r;
}

template <int MODE, int K>
__global__ __launch_bounds__(256) void gemm8mx_kernel(
    const unsigned char* __restrict__ A, const unsigned char* __restrict__ BT,
    const float* __restrict__ bias, const float* __restrict__ res,
    float* __restrict__ outF, unsigned char* __restrict__ outB8,
    int M, int N) {
  __shared__ unsigned char ldsb[65536];   // A pairbufs @0,16K ; B @32K,48K
  const int SCALE1 = 0x7F7F7F7F;          // e8m0 127 in every byte = x1.0
  int nwg = gridDim.x * gridDim.y;
  int flat = blockIdx.y * gridDim.x + blockIdx.x;
  int swz = (flat & 7) * (nwg >> 3) + (flat >> 3);
  int bx = swz % gridDim.x, by = swz / gridDim.x;
  const int bm = by * 128, bn = bx * 128;
  const int t = threadIdx.x;
  const int wid = t >> 6, lane = t & 63;
  const int wr = wid >> 1, wc = wid & 1;          // 2x2 wave grid, 64x64 per wave
  const int lr = lane & 15, g = lane >> 4, lrm7 = lane & 7;
  const int wq0 = wid * 4096;                     // LDS byte base for q=0
  const int scol = (((lane & 7) ^ ((lane >> 3) & 7)) & 7) * 16;
  const size_t aB0 = (size_t)(bm + wid * 32 + ((t >> 3) & 7)) * K + scol;
  const size_t bB0 = (size_t)(bn + wid * 32 + ((t >> 3) & 7)) * K + scol;

#define STGMX(p, kt) do { \
    _Pragma("unroll") for (int q_ = 0; q_ < 4; q_++) { \
      gload16(&A[aB0 + (size_t)q_ * 8 * K + (kt)],  ldsb + (p) * 16384 + wq0 + q_ * 1024); \
      gload16(&BT[bB0 + (size_t)q_ * 8 * K + (kt)], ldsb + 32768 + (p) * 16384 + wq0 + q_ * 1024); \
    } } while (0)

  f32x4 acc[4][4] = {};
  constexpr int npt = K / 128;

  STGMX(0, 0);
  STGMX(1, 128);

  #pragma unroll
  for (int pt = 0; pt < npt - 1; ++pt) {
    WAITV8(); BAR();
    const unsigned char* as = ldsb + (pt & 1) * 16384;
    const unsigned char* bs = ldsb + 32768 + (pt & 1) * 16384;
    i32x8 af[4], bf[4];
    #pragma unroll
    for (int i = 0; i < 4; i++)
      af[i] = ld_frag128(as, wr * 64 + i * 16 + lr, g, lrm7);
    #pragma unroll
    for (int j = 0; j < 4; j++)
      bf[j] = ld_frag128(bs, wc * 64 + j * 16 + lr, g, lrm7);
    WAITL();
    BAR();
    if (pt + 2 < npt) STGMX(pt & 1, (pt + 2) * 128);
    __builtin_amdgcn_s_setprio(1);
    #pragma unroll
    for (int i = 0; i < 4; i++)
      #pragma unroll
      for (int j = 0; j < 4; j++)
        acc[i][j] = __builtin_amdgcn_mfma_scale_f32_16x16x128_f8f6f4(
            af[i], bf[j], acc[i][j], 0, 0, 0, SCALE1, 0, SCALE1);
    __builtin_amdgcn_s_setprio(0);
  }
  {
    WAITV0(); BAR();
    const unsigned char* as = ldsb + ((npt - 1) & 1) * 16384;
    const unsigned char* bs = ldsb + 32768 + ((npt - 1) & 1) * 16384;
    i32x8 af[4], bf[4];
    #pragma unroll
    for (int i = 0; i < 4; i++)
      af[i] = ld_frag128(as, wr * 64 + i * 16 + lr, g, lrm7);
    #pragma unroll
    for (int j = 0; j < 4; j++)
      bf[j] = ld_frag128(bs, wc * 64 + j * 16 + lr, g, lrm7);
    WAITL();
    #pragma unroll
    for (int i = 0; i < 4; i++)
      #pragma unroll
      for (int j = 0; j < 4; j++)
        acc[i][j] = __builtin_amdgcn_mfma_scale_f32_16x16x128_f8f6f4(
            af[i], bf[j], acc[i][j], 0, 0, 0, SCALE1, 0, SCALE1);
  }
#undef STGMX

  // ---- epilogue: 2 passes of 64 rows x 128 cols via LDS restage ----
  {
    const float SC = 0.03125f;
    float* eps = (float*)ldsb;              // 64*132*4 = 33.8KB < 64KB
    const int erow = t >> 2;                // 0..63
    const int cb = (t & 3) * 4;             // col base; cols cb + c*16
    float4 bv4[8];
    #pragma unroll
    for (int c = 0; c < 8; c++)
      bv4[c] = *(const float4*)&bias[bn + cb + c * 16];
    #pragma unroll
    for (int p = 0; p < 2; p++) {
      __syncthreads();
      if (wr == p) {
        #pragma unroll
        for (int i = 0; i < 4; i++)
          #pragma unroll
          for (int j = 0; j < 4; j++)
            #pragma unroll
            for (int r = 0; r < 4; r++)
              eps[(i * 16 + g * 4 + r) * 132 + wc * 64 + j * 16 + lr] = acc[i][j][r];
      }
      __syncthreads();
      const size_t rowoff = (size_t)(bm + p * 64 + erow) * N + bn + cb;
      #pragma unroll
      for (int c = 0; c < 8; c++) {
        float4 vv = *(const float4*)&eps[erow * 132 + cb + c * 16];
        float v0 = vv.x * SC + bv4[c].x;
        float v1 = vv.y * SC + bv4[c].y;
        float v2 = vv.z * SC + bv4[c].z;
        float v3 = vv.w * SC + bv4[c].w;
        if (MODE == 1) {
          float4 rv = *(const float4*)&res[rowoff + c * 16];
          float4 ov;
          ov.x = v0 + rv.x; ov.y = v1 + rv.y; ov.z = v2 + rv.z; ov.w = v3 + rv.w;
          *(float4*)&outF[rowoff + c * 16] = ov;
        } else if (MODE == 0) {
          *(uint32_t*)&outB8[rowoff + c * 16] = (uint32_t)cvt4_fp8(v0, v1, v2, v3);
        } else {
          float gv[4];
          float vin[4] = {v0, v1, v2, v3};
          #pragma unroll
          for (int e = 0; e < 4; e++) {
            float v = vin[e];
            float a2 = v * v;
            float w = v * fmaf(a2, -0.1029436f, -2.3024849f);
            float sg = __builtin_amdgcn_rcpf(1.f + __builtin_amdgcn_exp2f(w));
            gv[e] = v * sg;
          }
          *(uint32_t*)&outB8[rowoff + c * 16] = (uint32_t)cvt4_fp8(gv[0], gv[1], gv[2], gv[3]);
        }
      }
    }
  }
}

// -------- fp8 MFMA window attention: 1 wave per (window, head), all-fp8 IO -------
#define WNS8 72   // byte stride: 64B data + 8 pad, 8-aligned

__global__ __launch_bounds__(64) void attn_mfma8_kernel(
    const unsigned char* __restrict__ qkv, unsigned char* __restrict__ out) {
  __shared__ unsigned char VT[64 * WNS8];   // V^T: [d][k] fp8
  __shared__ unsigned char Ps[64 * WNS8];   // P:   [q][k] fp8
  const int task = blockIdx.x;
  const int win = task >> 3, h = task & 7;
  const int b = win >> 8, wy = (win >> 4) & 15, wx = win & 15;
  const int lane = threadIdx.x;
  const int lr = lane & 15, g = lane >> 4;

  auto tokof = [&](int r) {
    int rr = r > 48 ? 48 : r;
    int y = rr / 7, x2 = rr - y * 7;
    return (size_t)(b * LLEN + (wy * 7 + y) * WW + wx * 7 + x2);
  };

  {
    size_t vbase = tokof(lane) * 1536 + 1024 + h * 64;
    bool valid = lane <= 48;
    #pragma unroll
    for (int c = 0; c < 4; c++) {
      uint4 v = *(const uint4*)(&qkv[vbase + c * 16]);
      const unsigned char* pv = (const unsigned char*)&v;
      #pragma unroll
      for (int e = 0; e < 16; e++)
        VT[(c * 16 + e) * WNS8 + lane] = valid ? pv[e] : (unsigned char)0;
    }
  }

  size_t tok[4];
  #pragma unroll
  for (int i2 = 0; i2 < 4; i2++) tok[i2] = tokof(i2 * 16 + lr);
  i64 Qf[4][2], Kf[4][2];
  #pragma unroll
  for (int i2 = 0; i2 < 4; i2++) {
    size_t base = tok[i2] * 1536 + h * 64 + g * 8;
    #pragma unroll
    for (int ks = 0; ks < 2; ks++) {
      Qf[i2][ks] = *(const i64*)(&qkv[base + ks * 32]);
      Kf[i2][ks] = *(const i64*)(&qkv[base + 512 + ks * 32]);
    }
  }

  f32x4 acc[4][4] = {};
  #pragma unroll
  for (int ks = 0; ks < 2; ks++)
    #pragma unroll
    for (int i2 = 0; i2 < 4; i2++)
      #pragma unroll
      for (int j = 0; j < 4; j++)
        acc[i2][j] = __builtin_amdgcn_mfma_f32_16x16x32_fp8_fp8(Kf[i2][ks], Qf[j][ks], acc[i2][j], 0, 0, 0);

  #pragma unroll
  for (int j = 0; j < 4; j++) {
    float mx = -1e30f;
    #pragma unroll
    for (int i2 = 0; i2 < 4; i2++)
      #pragma unroll
      for (int r = 0; r < 4; r++) {
        int k = 16 * i2 + 4 * g + r;
        mx = fmaxf(mx, (k <= 48) ? acc[i2][j][r] : -1e30f);
      }
    mx = fmaxf(mx, __shfl_xor(mx, 16, 64));
    mx = fmaxf(mx, __shfl_xor(mx, 32, 64));
    float p[4][4];
    float sum = 0.f;
    #pragma unroll
    for (int i2 = 0; i2 < 4; i2++)
      #pragma unroll
      for (int r = 0; r < 4; r++) {
        int k = 16 * i2 + 4 * g + r;
        float e = (k <= 48) ? __expf(0.125f * (acc[i2][j][r] - mx)) : 0.f;
        p[i2][r] = e; sum += e;
      }
    sum += __shfl_xor(sum, 16, 64);
    sum += __shfl_xor(sum, 32, 64);
    float inv = 1.f / sum;
    int q = 16 * j + lr;
    #pragma unroll
    for (int i2 = 0; i2 < 4; i2++) {
      uint32_t w = (uint32_t)cvt4_fp8(p[i2][0] * inv, p[i2][1] * inv,
                                      p[i2][2] * inv, p[i2][3] * inv);
      *(uint32_t*)(&Ps[q * WNS8 + 16 * i2 + 4 * g]) = w;
    }
  }

  __syncthreads();

  f32x4 o[4][4] = {};
  #pragma unroll
  for (int ks = 0; ks < 2; ks++) {
    i64 Pf[4], Vf[4];
    #pragma unroll
    for (int i2 = 0; i2 < 4; i2++)
      Pf[i2] = *(const i64*)(&Ps[(16 * i2 + lr) * WNS8 + ks * 32 + g * 8]);
    #pragma unroll
    for (int j = 0; j < 4; j++)
      Vf[j] = *(const i64*)(&VT[(16 * j + lr) * WNS8 + ks * 32 + g * 8]);
    #pragma unroll
    for (int i2 = 0; i2 < 4; i2++)
      #pragma unroll
      for (int j = 0; j < 4; j++)
        o[i2][j] = __builtin_amdgcn_mfma_f32_16x16x32_fp8_fp8(Pf[i2], Vf[j], o[i2][j], 0, 0, 0);
  }

  #pragma unroll
  for (int i2 = 0; i2 < 4; i2++)
    #pragma unroll
    for (int r = 0; r < 4; r++) {
      int q = 16 * i2 + 4 * g + r;
      if (q <= 48) {
        size_t obase = tokof(q) * 512 + h * 64 + lr;
        #pragma unroll
        for (int j = 0; j < 4; j++) {
          float v = o[i2][j][r];
          int rr = __builtin_amdgcn_cvt_pk_fp8_f32(v, v, 0, false);
          out[obase + 16 * j] = (unsigned char)rr;
        }
      }
    }
}

extern "C" void kernel_launch(void* const* d_in, const int* in_sizes, int n_in,
                              void* d_out, int out_size, void* d_ws, size_t ws_size,
                              hipStream_t stream) {
  const float* x      = (const float*)d_in[0];
  const float* cpe0_w = (const float*)d_in[1];
  const float* cpe0_b = (const float*)d_in[2];
  const float* cpe1_w = (const float*)d_in[3];
  const float* cpe1_b = (const float*)d_in[4];
  const float* ln1_g  = (const float*)d_in[5];
  const float* ln1_b  = (const float*)d_in[6];
  const float* ln2_g  = (const float*)d_in[7];
  const float* ln2_b  = (const float*)d_in[8];
  const float* qkv_w  = (const float*)d_in[9];
  const float* qkv_b  = (const float*)d_in[10];
  const float* proj_w = (const float*)d_in[11];
  const float* proj_b = (const float*)d_in[12];
  const float* fc1_w  = (const float*)d_in[13];
  const float* fc1_b  = (const float*)d_in[14];
  const float* fc2_w  = (const float*)d_in[15];
  const float* fc2_b  = (const float*)d_in[16];
  float* out = (float*)d_out;
  char* ws = (char*)d_ws;

  unsigned char*  qkvwT8 = (unsigned char*)(ws + 0);            // 1536x512 fp8
  unsigned char*  projwT8 = (unsigned char*)(ws + 1048576);     // 512x512 fp8
  unsigned char*  fc1wT8 = (unsigned char*)(ws + 2097152);      // 2048x512 fp8
  unsigned char*  fc2wT8 = (unsigned char*)(ws + 4194304);      // 512x2048 fp8
  unsigned short* shortcB = (unsigned short*)(ws + 6291456);    // 50176x512 bf16
  unsigned char*  lnb8   = (unsigned char*)(ws + 109051904);    // 50176x512 fp8
  unsigned char*  qkvb8  = (unsigned char*)(ws + 160432128);    // 50176x1536 fp8
  unsigned char*  attnb8 = (unsigned char*)(ws + 314572800);    // 50176x512 fp8
  unsigned char*  gelub8 = (unsigned char*)(ws + 160432128);    // overlay qkvb8
  float* h2 = out;                 // d_out doubles as h2 (f32)

  wtranspose8_kernel<<<(512 * 1536 + 255) / 256, 256, 0, stream>>>(qkv_w, qkvwT8, 512, 1536);
  wtranspose8_kernel<<<(512 * 512 + 255) / 256, 256, 0, stream>>>(proj_w, projwT8, 512, 512);
  wtranspose8_kernel<<<(512 * 2048 + 255) / 256, 256, 0, stream>>>(fc1_w, fc1wT8, 512, 2048);
  wtranspose8_kernel<<<(2048 * 512 + 255) / 256, 256, 0, stream>>>(fc2_w, fc2wT8, 2048, 512);

  const int pixblocks = (BB * HH * WW * 128) / 256;   // 25088
  // shortcut = x + dwconv(x) -> bf16 ; fused ln1 -> fp8
  cpe_ln_kernel<0, 1><<<pixblocks, 256, 0, stream>>>(x, cpe0_w, cpe0_b,
      ln1_g, ln1_b, shortcB, lnb8);
  // qkv (MX fp8): fp8 out
  gemm8mx_kernel<0, 512><<<dim3(12, 392), 256, 0, stream>>>(lnb8, qkvwT8, qkv_b, nullptr,
      nullptr, qkvb8, NTOK, 1536);
  // window attention, all-fp8
  attn_mfma8_kernel<<<8192, 64, 0, stream>>>(qkvb8, attnb8);
  // h = shortcut + attn@proj_w + b  (fp8 A, bf16 res/out in-place)
  gemm8_kernel<3, 512><<<dim3(4, 196), 512, 0, stream>>>(attnb8, projwT8, proj_b,
      shortcB, shortcB, NTOK, 512);
  // h2 = h + dwconv(h) -> f32 (d_out) ; fused ln2 -> fp8
  cpe_ln_kernel<1, 0><<<pixblocks, 256, 0, stream>>>(shortcB, cpe1_w, cpe1_b,
      ln2_g, ln2_b, h2, lnb8);
  // fc1 (MX fp8): gelu -> fp8
  gemm8mx_kernel<2, 512><<<dim3(16, 392), 256, 0, stream>>>(lnb8, fc1wT8, fc1_b, nullptr,
      nullptr, gelub8, NTOK, 2048);
  // fc2 (MX fp8): f32 out + h2 residual
  gemm8mx_kernel<1, 2048><<<dim3(4, 392), 256, 0, stream>>>(gelub8, fc2wT8, fc2_b, h2,
      out, nullptr, NTOK, 512);
}

// Round 14
// 535.995 us; speedup vs baseline: 1.3022x; 1.0203x over previous
//
#include <hip/hip_runtime.h>
#include <stdint.h>

#define HH 112
#define WW 112
#define CC 512
#define BB 4
#define LLEN (HH*WW)
#define NTOK (BB*LLEN)   // 50176
#define NHEADS 8
#define HD 64
#define HIDDEN 2048

typedef __bf16 bf16x8 __attribute__((ext_vector_type(8)));
typedef float f32x4 __attribute__((ext_vector_type(4)));
typedef int i32x8 __attribute__((ext_vector_type(8)));
typedef long i64;

__device__ __forceinline__ unsigned short f2bf(float x) {
  uint32_t u = __float_as_uint(x);
  u += 0x7fffu + ((u >> 16) & 1u);
  return (unsigned short)(u >> 16);
}
__device__ __forceinline__ float bf2f(unsigned short h) {
  return __uint_as_float((uint32_t)h << 16);
}
__device__ __forceinline__ int cvt4_fp8(float a, float b, float c, float d) {
  int r = 0;
  r = __builtin_amdgcn_cvt_pk_fp8_f32(a, b, r, false);
  r = __builtin_amdgcn_cvt_pk_fp8_f32(c, d, r, true);
  return r;
}

__device__ __forceinline__ void gload16(const void* gptr, void* lptr) {
  __builtin_amdgcn_global_load_lds(
      (const __attribute__((address_space(1))) void*)gptr,
      (__attribute__((address_space(3))) void*)lptr,
      16, 0, 0);
}

#define WAITV3() asm volatile("s_waitcnt vmcnt(3)" ::: "memory")
#define WAITV8() asm volatile("s_waitcnt vmcnt(8)" ::: "memory")
#define WAITV0() asm volatile("s_waitcnt vmcnt(0)" ::: "memory")
#define BAR() __builtin_amdgcn_s_barrier()
#define WAITL() do { asm volatile("s_waitcnt lgkmcnt(0)" ::: "memory"); \
                     __builtin_amdgcn_sched_barrier(0); } while (0)

// ---------------- weight transpose (K,N) f32 -> (N,K) fp8, scaled x32 --------
__global__ __launch_bounds__(256) void wtranspose8_kernel(
    const float* __restrict__ w, unsigned char* __restrict__ wt, int K, int N) {
  int idx = blockIdx.x * 256 + threadIdx.x;   // index over OUTPUT (coalesced)
  if (idx >= K * N) return;
  int n = idx / K, k = idx - n * K;
  float v = w[(size_t)k * N + n] * 32.f;
  int r = __builtin_amdgcn_cvt_pk_fp8_f32(v, v, 0, false);
  wt[idx] = (unsigned char)r;
}

// ==== FUSED depthwise 3x3 conv + residual + LayerNorm ====
// One wave = one pixel; 8 channels/thread. grid (28,112,BB), block 256 (4 pixels).
// INBF: input dtype (0=f32, 1=bf16). OUTBF: conv+res output (1=bf16, 0=f32).
// Also emits fp8 LN(conv+res) to ln8.
template <int INBF, int OUTBF>
__global__ __launch_bounds__(256) void cpe_ln_kernel(
    const void* __restrict__ xin, const float* __restrict__ w,
    const float* __restrict__ bias, const float* __restrict__ lng,
    const float* __restrict__ lnb, void* __restrict__ outp,
    unsigned char* __restrict__ ln8) {
  const int wid = threadIdx.x >> 6;
  const int lane = threadIdx.x & 63;
  const int xx = blockIdx.x * 4 + wid;    // 0..111
  const int yy = blockIdx.y;
  const int bb = blockIdx.z;
  const int c = lane * 8;                 // 8 channels per thread

  float acc[8];
  {
    float4 b0 = *(const float4*)(&bias[c]);
    float4 b1 = *(const float4*)(&bias[c + 4]);
    acc[0] = b0.x; acc[1] = b0.y; acc[2] = b0.z; acc[3] = b0.w;
    acc[4] = b1.x; acc[5] = b1.y; acc[6] = b1.z; acc[7] = b1.w;
  }
  float xv[8];   // center value (residual), captured at ky=kx=1

  #pragma unroll
  for (int ky = 0; ky < 3; ky++) {
    int y = yy + ky - 1;
    bool yok = (unsigned)y < (unsigned)HH;
    #pragma unroll
    for (int kx = 0; kx < 3; kx++) {
      int x2 = xx + kx - 1;
      bool ok = yok && ((unsigned)x2 < (unsigned)WW);
      float v[8];
      if (ok) {
        size_t eo = (((size_t)bb * HH + y) * WW + x2) * CC + c;
        if (INBF) {
          uint4 u = *(const uint4*)(&((const unsigned short*)xin)[eo]);
          v[0] = bf2f((unsigned short)(u.x & 0xffff)); v[1] = bf2f((unsigned short)(u.x >> 16));
          v[2] = bf2f((unsigned short)(u.y & 0xffff)); v[3] = bf2f((unsigned short)(u.y >> 16));
          v[4] = bf2f((unsigned short)(u.z & 0xffff)); v[5] = bf2f((unsigned short)(u.z >> 16));
          v[6] = bf2f((unsigned short)(u.w & 0xffff)); v[7] = bf2f((unsigned short)(u.w >> 16));
        } else {
          float4 a = *(const float4*)(&((const float*)xin)[eo]);
          float4 b = *(const float4*)(&((const float*)xin)[eo + 4]);
          v[0] = a.x; v[1] = a.y; v[2] = a.z; v[3] = a.w;
          v[4] = b.x; v[5] = b.y; v[6] = b.z; v[7] = b.w;
        }
      } else {
        #pragma unroll
        for (int e = 0; e < 8; e++) v[e] = 0.f;
      }
      if (ky == 1 && kx == 1) {
        #pragma unroll
        for (int e = 0; e < 8; e++) xv[e] = v[e];
      }
      float4 w0 = *(const float4*)(&w[(ky * 3 + kx) * CC + c]);
      float4 w1 = *(const float4*)(&w[(ky * 3 + kx) * CC + c + 4]);
      acc[0] = fmaf(v[0], w0.x, acc[0]); acc[1] = fmaf(v[1], w0.y, acc[1]);
      acc[2] = fmaf(v[2], w0.z, acc[2]); acc[3] = fmaf(v[3], w0.w, acc[3]);
      acc[4] = fmaf(v[4], w1.x, acc[4]); acc[5] = fmaf(v[5], w1.y, acc[5]);
      acc[6] = fmaf(v[6], w1.z, acc[6]); acc[7] = fmaf(v[7], w1.w, acc[7]);
    }
  }

  float r[8];
  #pragma unroll
  for (int e = 0; e < 8; e++) r[e] = xv[e] + acc[e];

  const size_t o = (((size_t)bb * HH + yy) * WW + xx) * CC + c;
  if (OUTBF) {
    uint4 pk;
    pk.x = (uint32_t)f2bf(r[0]) | ((uint32_t)f2bf(r[1]) << 16);
    pk.y = (uint32_t)f2bf(r[2]) | ((uint32_t)f2bf(r[3]) << 16);
    pk.z = (uint32_t)f2bf(r[4]) | ((uint32_t)f2bf(r[5]) << 16);
    pk.w = (uint32_t)f2bf(r[6]) | ((uint32_t)f2bf(r[7]) << 16);
    *(uint4*)(&((unsigned short*)outp)[o]) = pk;
  } else {
    float4 r0, r1;
    r0.x = r[0]; r0.y = r[1]; r0.z = r[2]; r0.w = r[3];
    r1.x = r[4]; r1.y = r[5]; r1.z = r[6]; r1.w = r[7];
    *(float4*)(&((float*)outp)[o]) = r0;
    *(float4*)(&((float*)outp)[o + 4]) = r1;
  }

  // LayerNorm across the wave (512 ch = 64 lanes x 8)
  float s = 0.f, ss = 0.f;
  #pragma unroll
  for (int e = 0; e < 8; e++) { s += r[e]; ss += r[e] * r[e]; }
  #pragma unroll
  for (int of = 32; of; of >>= 1) {
    s += __shfl_xor(s, of, 64);
    ss += __shfl_xor(ss, of, 64);
  }
  float mu = s * (1.f / CC);
  float var = ss * (1.f / CC) - mu * mu;
  float rsd = rsqrtf(var + 1e-5f);
  float4 g0 = *(const float4*)(&lng[c]);
  float4 g1 = *(const float4*)(&lng[c + 4]);
  float4 b0 = *(const float4*)(&lnb[c]);
  float4 b1 = *(const float4*)(&lnb[c + 4]);
  float gv[8] = {g0.x, g0.y, g0.z, g0.w, g1.x, g1.y, g1.z, g1.w};
  float bv[8] = {b0.x, b0.y, b0.z, b0.w, b1.x, b1.y, b1.z, b1.w};
  float ov[8];
  #pragma unroll
  for (int e = 0; e < 8; e++) ov[e] = (r[e] - mu) * rsd * gv[e] + bv[e];
  uint2 pk8;
  pk8.x = (uint32_t)cvt4_fp8(ov[0], ov[1], ov[2], ov[3]);
  pk8.y = (uint32_t)cvt4_fp8(ov[4], ov[5], ov[6], ov[7]);
  *(uint2*)(&ln8[o]) = pk8;
}

// ==== fp8 GEMM (non-MX), BM256/BN128/BK64 — proj (MODE 3 only), K templated ====
#define BM 256
#define BN 128
#define BK8 64

template <int MODE, int K>
__global__ __launch_bounds__(512) void gemm8_kernel(
    const unsigned char* __restrict__ A, const unsigned char* __restrict__ BT,
    const float* __restrict__ bias, const unsigned short* __restrict__ resB,
    unsigned short* __restrict__ outB16, int M, int N) {
  __shared__ unsigned char ldsb[49152];
  int nwg = gridDim.x * gridDim.y;
  int flat = blockIdx.y * gridDim.x + blockIdx.x;
  int swz = (flat & 7) * (nwg >> 3) + (flat >> 3);
  int bx = swz % gridDim.x, by = swz / gridDim.x;
  const int bm = by * BM, bn = bx * BN;
  const int t = threadIdx.x;
  const int wid = t >> 6, lane = t & 63;
  const int wr = wid >> 1, wc = wid & 1;
  const int lr = lane & 15, g = lane >> 4;
  const int swr = (lr >> 1) & 3;
  const int rb0 = (((g >> 1)      ) ^ swr) * 16 + (g & 1) * 8;
  const int rb1 = (((g >> 1) + 2) ^ swr) * 16 + (g & 1) * 8;
  const int srow = t >> 2;
  const int scol = (((t & 3) ^ ((t >> 3) & 3)) & 3) * 16;
  const size_t arow0 = (size_t)(bm + srow) * K + scol;
  const size_t arow1 = (size_t)(bm + 128 + srow) * K + scol;
  const size_t brow  = (size_t)(bn + srow) * K + scol;
  const int ldso = wid * 1024;

#define STG8(b, kt) do { \
    gload16(&A[arow0 + (kt)], ldsb + (b) * 16384 + ldso); \
    gload16(&A[arow1 + (kt)], ldsb + (b) * 16384 + 8192 + ldso); \
    gload16(&BT[brow + (kt)], ldsb + 32768 + (b) * 8192 + ldso); } while (0)

  f32x4 acc[4][4] = {};
  constexpr int nt = K / BK8;

  STG8(0, 0);
  STG8(1, BK8);

  #pragma unroll
  for (int tile = 0; tile < nt - 1; ++tile) {
    WAITV3(); BAR();
    const unsigned char* as = ldsb + (tile & 1) * 16384;
    const unsigned char* bs = ldsb + 32768 + (tile & 1) * 8192;
    i64 af0[4], af1[4], bf0[4], bf1[4];
    #pragma unroll
    for (int i = 0; i < 4; i++) {
      const unsigned char* p = &as[(wr * 64 + i * 16 + lr) * BK8];
      af0[i] = *(const i64*)(p + rb0);
      af1[i] = *(const i64*)(p + rb1);
    }
    #pragma unroll
    for (int j = 0; j < 4; j++) {
      const unsigned char* p = &bs[(wc * 64 + j * 16 + lr) * BK8];
      bf0[j] = *(const i64*)(p + rb0);
      bf1[j] = *(const i64*)(p + rb1);
    }
    WAITL();
    BAR();
    if (tile + 2 < nt) STG8(tile & 1, (tile + 2) * BK8);
    __builtin_amdgcn_s_setprio(1);
    #pragma unroll
    for (int i = 0; i < 4; i++)
      #pragma unroll
      for (int j = 0; j < 4; j++) {
        acc[i][j] = __builtin_amdgcn_mfma_f32_16x16x32_fp8_fp8(af0[i], bf0[j], acc[i][j], 0, 0, 0);
        acc[i][j] = __builtin_amdgcn_mfma_f32_16x16x32_fp8_fp8(af1[i], bf1[j], acc[i][j], 0, 0, 0);
      }
    __builtin_amdgcn_s_setprio(0);
  }
  {
    WAITV0(); BAR();
    const unsigned char* as = ldsb + ((nt - 1) & 1) * 16384;
    const unsigned char* bs = ldsb + 32768 + ((nt - 1) & 1) * 8192;
    i64 af0[4], af1[4], bf0[4], bf1[4];
    #pragma unroll
    for (int i = 0; i < 4; i++) {
      const unsigned char* p = &as[(wr * 64 + i * 16 + lr) * BK8];
      af0[i] = *(const i64*)(p + rb0);
      af1[i] = *(const i64*)(p + rb1);
    }
    #pragma unroll
    for (int j = 0; j < 4; j++) {
      const unsigned char* p = &bs[(wc * 64 + j * 16 + lr) * BK8];
      bf0[j] = *(const i64*)(p + rb0);
      bf1[j] = *(const i64*)(p + rb1);
    }
    WAITL();
    #pragma unroll
    for (int i = 0; i < 4; i++)
      #pragma unroll
      for (int j = 0; j < 4; j++) {
        acc[i][j] = __builtin_amdgcn_mfma_f32_16x16x32_fp8_fp8(af0[i], bf0[j], acc[i][j], 0, 0, 0);
        acc[i][j] = __builtin_amdgcn_mfma_f32_16x16x32_fp8_fp8(af1[i], bf1[j], acc[i][j], 0, 0, 0);
      }
  }
#undef STG8

  // ---- epilogue (restaged): MODE 3: out bf16 = acc/32 + bias + res_bf16 ----
  {
    const float SC = 0.03125f;
    float* eps = (float*)ldsb;
    const int erow = t >> 3;
    const int ecol0 = (t & 7) * 16;
    const int wrow = wr * 16 + (lane >> 4) * 4;
    const int wcol = wc * 64 + lr;
    const int gr_base = bm + (erow >> 4) * 64 + (erow & 15);
    const int gc0 = bn + ecol0;
    float bv[16];
    #pragma unroll
    for (int c4 = 0; c4 < 4; c4++)
      *(float4*)&bv[c4 * 4] = *(const float4*)&bias[gc0 + c4 * 4];
    #pragma unroll
    for (int i = 0; i < 4; i++) {
      __syncthreads();
      #pragma unroll
      for (int j = 0; j < 4; j++)
        #pragma unroll
        for (int r = 0; r < 4; r++)
          eps[(wrow + r) * 132 + wcol + j * 16] = acc[i][j][r];
      __syncthreads();
      float vv[16];
      #pragma unroll
      for (int c4 = 0; c4 < 4; c4++)
        *(float4*)&vv[c4 * 4] = *(const float4*)&eps[erow * 132 + ecol0 + c4 * 4];
      const size_t off = (size_t)(gr_base + i * 16) * N + gc0;
      uint4 r0 = *(const uint4*)&resB[off];
      uint4 r1 = *(const uint4*)&resB[off + 8];
      unsigned short ob[16];
      const uint32_t* rp = (const uint32_t*)&r0;
      #pragma unroll
      for (int c = 0; c < 8; c++) {
        uint32_t u = rp[c >> 1];
        float rv = bf2f((unsigned short)((c & 1) ? (u >> 16) : (u & 0xffff)));
        ob[c] = f2bf(vv[c] * SC + bv[c] + rv);
      }
      const uint32_t* rp1 = (const uint32_t*)&r1;
      #pragma unroll
      for (int c = 0; c < 8; c++) {
        uint32_t u = rp1[c >> 1];
        float rv = bf2f((unsigned short)((c & 1) ? (u >> 16) : (u & 0xffff)));
        ob[8 + c] = f2bf(vv[8 + c] * SC + bv[8 + c] + rv);
      }
      *(uint4*)&outB16[off]     = *(uint4*)&ob[0];
      *(uint4*)&outB16[off + 8] = *(uint4*)&ob[8];
    }
  }
}

// ==== MX-scaled fp8 GEMM: 16x16x128 f8f6f4 (unit scales), K templated ====
__device__ __forceinline__ i32x8 ld_frag128(const unsigned char* base, int row, int g, int lrm7) {
  const uint4 lo = *(const uint4*)(base + row * 128 + (((2 * g)     ^ lrm7) * 16));
  const uint4 hi = *(const uint4*)(base + row * 128 + (((2 * g + 1) ^ lrm7) * 16));
  i32x8 r;
  r[0] = lo.x; r[1] = lo.y; r[2] = lo.z; r[3] = lo.w;
  r[4] = hi.x; r[5] = hi.y; r[6] = hi.z; r[7] = hi.w;
  return r;
}

template <int MODE, int K>
__global__ __launch_bounds__(256) void gemm8mx_kernel(
    const unsigned char* __restrict__ A, const unsigned char* __restrict__ BT,
    const float* __restrict__ bias, const float* __restrict__ res,
    float* __restrict__ outF, unsigned char* __restrict__ outB8,
    int M, int N) {
  __shared__ unsigned char ldsb[65536];   // A pairbufs @0,16K ; B @32K,48K
  const int SCALE1 = 0x7F7F7F7F;          // e8m0 127 in every byte = x1.0
  int nwg = gridDim.x * gridDim.y;
  int flat = blockIdx.y * gridDim.x + blockIdx.x;
  int swz = (flat & 7) * (nwg >> 3) + (flat >> 3);
  int bx = swz % gridDim.x, by = swz / gridDim.x;
  const int bm = by * 128, bn = bx * 128;
  const int t = threadIdx.x;
  const int wid = t >> 6, lane = t & 63;
  const int wr = wid >> 1, wc = wid & 1;          // 2x2 wave grid, 64x64 per wave
  const int lr = lane & 15, g = lane >> 4, lrm7 = lane & 7;
  const int wq0 = wid * 4096;                     // LDS byte base for q=0
  const int scol = (((lane & 7) ^ ((lane >> 3) & 7)) & 7) * 16;
  const size_t aB0 = (size_t)(bm + wid * 32 + ((t >> 3) & 7)) * K + scol;
  const size_t bB0 = (size_t)(bn + wid * 32 + ((t >> 3) & 7)) * K + scol;

#define STGMX(p, kt) do { \
    _Pragma("unroll") for (int q_ = 0; q_ < 4; q_++) { \
      gload16(&A[aB0 + (size_t)q_ * 8 * K + (kt)],  ldsb + (p) * 16384 + wq0 + q_ * 1024); \
      gload16(&BT[bB0 + (size_t)q_ * 8 * K + (kt)], ldsb + 32768 + (p) * 16384 + wq0 + q_ * 1024); \
    } } while (0)

  f32x4 acc[4][4] = {};
  constexpr int npt = K / 128;

  STGMX(0, 0);
  STGMX(1, 128);

  #pragma unroll
  for (int pt = 0; pt < npt - 1; ++pt) {
    WAITV8(); BAR();
    const unsigned char* as = ldsb + (pt & 1) * 16384;
    const unsigned char* bs = ldsb + 32768 + (pt & 1) * 16384;
    i32x8 af[4], bf[4];
    #pragma unroll
    for (int i = 0; i < 4; i++)
      af[i] = ld_frag128(as, wr * 64 + i * 16 + lr, g, lrm7);
    #pragma unroll
    for (int j = 0; j < 4; j++)
      bf[j] = ld_frag128(bs, wc * 64 + j * 16 + lr, g, lrm7);
    WAITL();
    BAR();
    if (pt + 2 < npt) STGMX(pt & 1, (pt + 2) * 128);
    __builtin_amdgcn_s_setprio(1);
    #pragma unroll
    for (int i = 0; i < 4; i++)
      #pragma unroll
      for (int j = 0; j < 4; j++)
        acc[i][j] = __builtin_amdgcn_mfma_scale_f32_16x16x128_f8f6f4(
            af[i], bf[j], acc[i][j], 0, 0, 0, SCALE1, 0, SCALE1);
    __builtin_amdgcn_s_setprio(0);
  }
  {
    WAITV0(); BAR();
    const unsigned char* as = ldsb + ((npt - 1) & 1) * 16384;
    const unsigned char* bs = ldsb + 32768 + ((npt - 1) & 1) * 16384;
    i32x8 af[4], bf[4];
    #pragma unroll
    for (int i = 0; i < 4; i++)
      af[i] = ld_frag128(as, wr * 64 + i * 16 + lr, g, lrm7);
    #pragma unroll
    for (int j = 0; j < 4; j++)
      bf[j] = ld_frag128(bs, wc * 64 + j * 16 + lr, g, lrm7);
    WAITL();
    #pragma unroll
    for (int i = 0; i < 4; i++)
      #pragma unroll
      for (int j = 0; j < 4; j++)
        acc[i][j] = __builtin_amdgcn_mfma_scale_f32_16x16x128_f8f6f4(
            af[i], bf[j], acc[i][j], 0, 0, 0, SCALE1, 0, SCALE1);
  }
#undef STGMX

  // ---- epilogue: 2 passes of 64 rows x 128 cols via LDS restage ----
  {
    const float SC = 0.03125f;
    float* eps = (float*)ldsb;              // 64*132*4 = 33.8KB < 64KB
    const int erow = t >> 2;                // 0..63
    const int cb = (t & 3) * 4;             // col base; cols cb + c*16
    float4 bv4[8];
    #pragma unroll
    for (int c = 0; c < 8; c++)
      bv4[c] = *(const float4*)&bias[bn + cb + c * 16];
    #pragma unroll
    for (int p = 0; p < 2; p++) {
      __syncthreads();
      if (wr == p) {
        #pragma unroll
        for (int i = 0; i < 4; i++)
          #pragma unroll
          for (int j = 0; j < 4; j++)
            #pragma unroll
            for (int r = 0; r < 4; r++)
              eps[(i * 16 + g * 4 + r) * 132 + wc * 64 + j * 16 + lr] = acc[i][j][r];
      }
      __syncthreads();
      const size_t rowoff = (size_t)(bm + p * 64 + erow) * N + bn + cb;
      #pragma unroll
      for (int c = 0; c < 8; c++) {
        float4 vv = *(const float4*)&eps[erow * 132 + cb + c * 16];
        float v0 = vv.x * SC + bv4[c].x;
        float v1 = vv.y * SC + bv4[c].y;
        float v2 = vv.z * SC + bv4[c].z;
        float v3 = vv.w * SC + bv4[c].w;
        if (MODE == 1) {
          float4 rv = *(const float4*)&res[rowoff + c * 16];
          float4 ov;
          ov.x = v0 + rv.x; ov.y = v1 + rv.y; ov.z = v2 + rv.z; ov.w = v3 + rv.w;
          *(float4*)&outF[rowoff + c * 16] = ov;
        } else if (MODE == 0) {
          *(uint32_t*)&outB8[rowoff + c * 16] = (uint32_t)cvt4_fp8(v0, v1, v2, v3);
        } else {
          float gv[4];
          float vin[4] = {v0, v1, v2, v3};
          #pragma unroll
          for (int e = 0; e < 4; e++) {
            float v = vin[e];
            float a2 = v * v;
            float w = v * fmaf(a2, -0.1029436f, -2.3024849f);
            float sg = __builtin_amdgcn_rcpf(1.f + __builtin_amdgcn_exp2f(w));
            gv[e] = v * sg;
          }
          *(uint32_t*)&outB8[rowoff + c * 16] = (uint32_t)cvt4_fp8(gv[0], gv[1], gv[2], gv[3]);
        }
      }
    }
  }
}

// -------- fp8 MFMA window attention: 1 wave per (window, head), all-fp8 IO -------
#define WNS8 72   // byte stride: 64B data + 8 pad, 8-aligned

__global__ __launch_bounds__(64) void attn_mfma8_kernel(
    const unsigned char* __restrict__ qkv, unsigned char* __restrict__ out) {
  __shared__ unsigned char VT[64 * WNS8];   // V^T: [d][k] fp8
  __shared__ unsigned char Ps[64 * WNS8];   // P:   [q][k] fp8
  const int task = blockIdx.x;
  const int win = task >> 3, h = task & 7;
  const int b = win >> 8, wy = (win >> 4) & 15, wx = win & 15;
  const int lane = threadIdx.x;
  const int lr = lane & 15, g = lane >> 4;

  auto tokof = [&](int r) {
    int rr = r > 48 ? 48 : r;
    int y = rr / 7, x2 = rr - y * 7;
    return (size_t)(b * LLEN + (wy * 7 + y) * WW + wx * 7 + x2);
  };

  {
    size_t vbase = tokof(lane) * 1536 + 1024 + h * 64;
    bool valid = lane <= 48;
    #pragma unroll
    for (int c = 0; c < 4; c++) {
      uint4 v = *(const uint4*)(&qkv[vbase + c * 16]);
      const unsigned char* pv = (const unsigned char*)&v;
      #pragma unroll
      for (int e = 0; e < 16; e++)
        VT[(c * 16 + e) * WNS8 + lane] = valid ? pv[e] : (unsigned char)0;
    }
  }

  size_t tok[4];
  #pragma unroll
  for (int i2 = 0; i2 < 4; i2++) tok[i2] = tokof(i2 * 16 + lr);
  i64 Qf[4][2], Kf[4][2];
  #pragma unroll
  for (int i2 = 0; i2 < 4; i2++) {
    size_t base = tok[i2] * 1536 + h * 64 + g * 8;
    #pragma unroll
    for (int ks = 0; ks < 2; ks++) {
      Qf[i2][ks] = *(const i64*)(&qkv[base + ks * 32]);
      Kf[i2][ks] = *(const i64*)(&qkv[base + 512 + ks * 32]);
    }
  }

  f32x4 acc[4][4] = {};
  #pragma unroll
  for (int ks = 0; ks < 2; ks++)
    #pragma unroll
    for (int i2 = 0; i2 < 4; i2++)
      #pragma unroll
      for (int j = 0; j < 4; j++)
        acc[i2][j] = __builtin_amdgcn_mfma_f32_16x16x32_fp8_fp8(Kf[i2][ks], Qf[j][ks], acc[i2][j], 0, 0, 0);

  #pragma unroll
  for (int j = 0; j < 4; j++) {
    float mx = -1e30f;
    #pragma unroll
    for (int i2 = 0; i2 < 4; i2++)
      #pragma unroll
      for (int r = 0; r < 4; r++) {
        int k = 16 * i2 + 4 * g + r;
        mx = fmaxf(mx, (k <= 48) ? acc[i2][j][r] : -1e30f);
      }
    mx = fmaxf(mx, __shfl_xor(mx, 16, 64));
    mx = fmaxf(mx, __shfl_xor(mx, 32, 64));
    float p[4][4];
    float sum = 0.f;
    #pragma unroll
    for (int i2 = 0; i2 < 4; i2++)
      #pragma unroll
      for (int r = 0; r < 4; r++) {
        int k = 16 * i2 + 4 * g + r;
        float e = (k <= 48) ? __expf(0.125f * (acc[i2][j][r] - mx)) : 0.f;
        p[i2][r] = e; sum += e;
      }
    sum += __shfl_xor(sum, 16, 64);
    sum += __shfl_xor(sum, 32, 64);
    float inv = 1.f / sum;
    int q = 16 * j + lr;
    #pragma unroll
    for (int i2 = 0; i2 < 4; i2++) {
      uint32_t w = (uint32_t)cvt4_fp8(p[i2][0] * inv, p[i2][1] * inv,
                                      p[i2][2] * inv, p[i2][3] * inv);
      *(uint32_t*)(&Ps[q * WNS8 + 16 * i2 + 4 * g]) = w;
    }
  }

  __syncthreads();

  f32x4 o[4][4] = {};
  #pragma unroll
  for (int ks = 0; ks < 2; ks++) {
    i64 Pf[4], Vf[4];
    #pragma unroll
    for (int i2 = 0; i2 < 4; i2++)
      Pf[i2] = *(const i64*)(&Ps[(16 * i2 + lr) * WNS8 + ks * 32 + g * 8]);
    #pragma unroll
    for (int j = 0; j < 4; j++)
      Vf[j] = *(const i64*)(&VT[(16 * j + lr) * WNS8 + ks * 32 + g * 8]);
    #pragma unroll
    for (int i2 = 0; i2 < 4; i2++)
      #pragma unroll
      for (int j = 0; j < 4; j++)
        o[i2][j] = __builtin_amdgcn_mfma_f32_16x16x32_fp8_fp8(Pf[i2], Vf[j], o[i2][j], 0, 0, 0);
  }

  #pragma unroll
  for (int i2 = 0; i2 < 4; i2++)
    #pragma unroll
    for (int r = 0; r < 4; r++) {
      int q = 16 * i2 + 4 * g + r;
      if (q <= 48) {
        size_t obase = tokof(q) * 512 + h * 64 + lr;
        #pragma unroll
        for (int j = 0; j < 4; j++) {
          float v = o[i2][j][r];
          int rr = __builtin_amdgcn_cvt_pk_fp8_f32(v, v, 0, false);
          out[obase + 16 * j] = (unsigned char)rr;
        }
      }
    }
}

extern "C" void kernel_launch(void* const* d_in, const int* in_sizes, int n_in,
                              void* d_out, int out_size, void* d_ws, size_t ws_size,
                              hipStream_t stream) {
  const float* x      = (const float*)d_in[0];
  const float* cpe0_w = (const float*)d_in[1];
  const float* cpe0_b = (const float*)d_in[2];
  const float* cpe1_w = (const float*)d_in[3];
  const float* cpe1_b = (const float*)d_in[4];
  const float* ln1_g  = (const float*)d_in[5];
  const float* ln1_b  = (const float*)d_in[6];
  const float* ln2_g  = (const float*)d_in[7];
  const float* ln2_b  = (const float*)d_in[8];
  const float* qkv_w  = (const float*)d_in[9];
  const float* qkv_b  = (const float*)d_in[10];
  const float* proj_w = (const float*)d_in[11];
  const float* proj_b = (const float*)d_in[12];
  const float* fc1_w  = (const float*)d_in[13];
  const float* fc1_b  = (const float*)d_in[14];
  const float* fc2_w  = (const float*)d_in[15];
  const float* fc2_b  = (const float*)d_in[16];
  float* out = (float*)d_out;
  char* ws = (char*)d_ws;

  unsigned char*  qkvwT8 = (unsigned char*)(ws + 0);            // 1536x512 fp8
  unsigned char*  projwT8 = (unsigned char*)(ws + 1048576);     // 512x512 fp8
  unsigned char*  fc1wT8 = (unsigned char*)(ws + 2097152);      // 2048x512 fp8
  unsigned char*  fc2wT8 = (unsigned char*)(ws + 4194304);      // 512x2048 fp8
  unsigned short* shortcB = (unsigned short*)(ws + 6291456);    // 50176x512 bf16
  unsigned char*  lnb8   = (unsigned char*)(ws + 109051904);    // 50176x512 fp8
  unsigned char*  qkvb8  = (unsigned char*)(ws + 160432128);    // 50176x1536 fp8
  unsigned char*  attnb8 = (unsigned char*)(ws + 314572800);    // 50176x512 fp8
  unsigned char*  gelub8 = (unsigned char*)(ws + 160432128);    // overlay qkvb8
  float* h2 = out;                 // d_out doubles as h2 (f32)

  wtranspose8_kernel<<<(512 * 1536 + 255) / 256, 256, 0, stream>>>(qkv_w, qkvwT8, 512, 1536);
  wtranspose8_kernel<<<(512 * 512 + 255) / 256, 256, 0, stream>>>(proj_w, projwT8, 512, 512);
  wtranspose8_kernel<<<(512 * 2048 + 255) / 256, 256, 0, stream>>>(fc1_w, fc1wT8, 512, 2048);
  wtranspose8_kernel<<<(2048 * 512 + 255) / 256, 256, 0, stream>>>(fc2_w, fc2wT8, 2048, 512);

  // shortcut = x + dwconv(x) -> bf16 ; fused ln1 -> fp8   (1 wave/pixel)
  cpe_ln_kernel<0, 1><<<dim3(28, 112, BB), 256, 0, stream>>>(x, cpe0_w, cpe0_b,
      ln1_g, ln1_b, shortcB, lnb8);
  // qkv (MX fp8): fp8 out
  gemm8mx_kernel<0, 512><<<dim3(12, 392), 256, 0, stream>>>(lnb8, qkvwT8, qkv_b, nullptr,
      nullptr, qkvb8, NTOK, 1536);
  // window attention, all-fp8
  attn_mfma8_kernel<<<8192, 64, 0, stream>>>(qkvb8, attnb8);
  // h = shortcut + attn@proj_w + b  (fp8 A, bf16 res/out in-place)
  gemm8_kernel<3, 512><<<dim3(4, 196), 512, 0, stream>>>(attnb8, projwT8, proj_b,
      shortcB, shortcB, NTOK, 512);
  // h2 = h + dwconv(h) -> f32 (d_out) ; fused ln2 -> fp8   (1 wave/pixel)
  cpe_ln_kernel<1, 0><<<dim3(28, 112, BB), 256, 0, stream>>>(shortcB, cpe1_w, cpe1_b,
      ln2_g, ln2_b, h2, lnb8);
  // fc1 (MX fp8): gelu -> fp8
  gemm8mx_kernel<2, 512><<<dim3(16, 392), 256, 0, stream>>>(lnb8, fc1wT8, fc1_b, nullptr,
      nullptr, gelub8, NTOK, 2048);
  // fc2 (MX fp8): f32 out + h2 residual
  gemm8mx_kernel<1, 2048><<<dim3(4, 392), 256, 0, stream>>>(gelub8, fc2wT8, fc2_b, h2,
      out, nullptr, NTOK, 512);
}

// Round 15
// 533.029 us; speedup vs baseline: 1.3095x; 1.0056x over previous
//
#include <hip/hip_runtime.h>
#include <stdint.h>

#define HH 112
#define WW 112
#define CC 512
#define BB 4
#define LLEN (HH*WW)
#define NTOK (BB*LLEN)   // 50176
#define NHEADS 8
#define HD 64
#define HIDDEN 2048

typedef __bf16 bf16x8 __attribute__((ext_vector_type(8)));
typedef float f32x4 __attribute__((ext_vector_type(4)));
typedef int i32x8 __attribute__((ext_vector_type(8)));
typedef long i64;

__device__ __forceinline__ unsigned short f2bf(float x) {
  uint32_t u = __float_as_uint(x);
  u += 0x7fffu + ((u >> 16) & 1u);
  return (unsigned short)(u >> 16);
}
__device__ __forceinline__ float bf2f(unsigned short h) {
  return __uint_as_float((uint32_t)h << 16);
}
__device__ __forceinline__ int cvt4_fp8(float a, float b, float c, float d) {
  int r = 0;
  r = __builtin_amdgcn_cvt_pk_fp8_f32(a, b, r, false);
  r = __builtin_amdgcn_cvt_pk_fp8_f32(c, d, r, true);
  return r;
}

__device__ __forceinline__ void gload16(const void* gptr, void* lptr) {
  __builtin_amdgcn_global_load_lds(
      (const __attribute__((address_space(1))) void*)gptr,
      (__attribute__((address_space(3))) void*)lptr,
      16, 0, 0);
}

#define WAITV3() asm volatile("s_waitcnt vmcnt(3)" ::: "memory")
#define WAITV4() asm volatile("s_waitcnt vmcnt(4)" ::: "memory")
#define WAITV0() asm volatile("s_waitcnt vmcnt(0)" ::: "memory")
#define BAR() __builtin_amdgcn_s_barrier()
#define WAITL() do { asm volatile("s_waitcnt lgkmcnt(0)" ::: "memory"); \
                     __builtin_amdgcn_sched_barrier(0); } while (0)

// ---------------- weight transpose (K,N) f32 -> (N,K) fp8, scaled x32 --------
__global__ __launch_bounds__(256) void wtranspose8_kernel(
    const float* __restrict__ w, unsigned char* __restrict__ wt, int K, int N) {
  int idx = blockIdx.x * 256 + threadIdx.x;   // index over OUTPUT (coalesced)
  if (idx >= K * N) return;
  int n = idx / K, k = idx - n * K;
  float v = w[(size_t)k * N + n] * 32.f;
  int r = __builtin_amdgcn_cvt_pk_fp8_f32(v, v, 0, false);
  wt[idx] = (unsigned char)r;
}

// ==== FUSED depthwise 3x3 conv + residual + LayerNorm ====
// One wave = one pixel; 8 channels/thread. grid (28,112,BB), block 256 (4 pixels).
template <int INBF, int OUTBF>
__global__ __launch_bounds__(256) void cpe_ln_kernel(
    const void* __restrict__ xin, const float* __restrict__ w,
    const float* __restrict__ bias, const float* __restrict__ lng,
    const float* __restrict__ lnb, void* __restrict__ outp,
    unsigned char* __restrict__ ln8) {
  const int wid = threadIdx.x >> 6;
  const int lane = threadIdx.x & 63;
  const int xx = blockIdx.x * 4 + wid;    // 0..111
  const int yy = blockIdx.y;
  const int bb = blockIdx.z;
  const int c = lane * 8;                 // 8 channels per thread

  float acc[8];
  {
    float4 b0 = *(const float4*)(&bias[c]);
    float4 b1 = *(const float4*)(&bias[c + 4]);
    acc[0] = b0.x; acc[1] = b0.y; acc[2] = b0.z; acc[3] = b0.w;
    acc[4] = b1.x; acc[5] = b1.y; acc[6] = b1.z; acc[7] = b1.w;
  }
  float xv[8];   // center value (residual), captured at ky=kx=1

  #pragma unroll
  for (int ky = 0; ky < 3; ky++) {
    int y = yy + ky - 1;
    bool yok = (unsigned)y < (unsigned)HH;
    #pragma unroll
    for (int kx = 0; kx < 3; kx++) {
      int x2 = xx + kx - 1;
      bool ok = yok && ((unsigned)x2 < (unsigned)WW);
      float v[8];
      if (ok) {
        size_t eo = (((size_t)bb * HH + y) * WW + x2) * CC + c;
        if (INBF) {
          uint4 u = *(const uint4*)(&((const unsigned short*)xin)[eo]);
          v[0] = bf2f((unsigned short)(u.x & 0xffff)); v[1] = bf2f((unsigned short)(u.x >> 16));
          v[2] = bf2f((unsigned short)(u.y & 0xffff)); v[3] = bf2f((unsigned short)(u.y >> 16));
          v[4] = bf2f((unsigned short)(u.z & 0xffff)); v[5] = bf2f((unsigned short)(u.z >> 16));
          v[6] = bf2f((unsigned short)(u.w & 0xffff)); v[7] = bf2f((unsigned short)(u.w >> 16));
        } else {
          float4 a = *(const float4*)(&((const float*)xin)[eo]);
          float4 b = *(const float4*)(&((const float*)xin)[eo + 4]);
          v[0] = a.x; v[1] = a.y; v[2] = a.z; v[3] = a.w;
          v[4] = b.x; v[5] = b.y; v[6] = b.z; v[7] = b.w;
        }
      } else {
        #pragma unroll
        for (int e = 0; e < 8; e++) v[e] = 0.f;
      }
      if (ky == 1 && kx == 1) {
        #pragma unroll
        for (int e = 0; e < 8; e++) xv[e] = v[e];
      }
      float4 w0 = *(const float4*)(&w[(ky * 3 + kx) * CC + c]);
      float4 w1 = *(const float4*)(&w[(ky * 3 + kx) * CC + c + 4]);
      acc[0] = fmaf(v[0], w0.x, acc[0]); acc[1] = fmaf(v[1], w0.y, acc[1]);
      acc[2] = fmaf(v[2], w0.z, acc[2]); acc[3] = fmaf(v[3], w0.w, acc[3]);
      acc[4] = fmaf(v[4], w1.x, acc[4]); acc[5] = fmaf(v[5], w1.y, acc[5]);
      acc[6] = fmaf(v[6], w1.z, acc[6]); acc[7] = fmaf(v[7], w1.w, acc[7]);
    }
  }

  float r[8];
  #pragma unroll
  for (int e = 0; e < 8; e++) r[e] = xv[e] + acc[e];

  const size_t o = (((size_t)bb * HH + yy) * WW + xx) * CC + c;
  if (OUTBF) {
    uint4 pk;
    pk.x = (uint32_t)f2bf(r[0]) | ((uint32_t)f2bf(r[1]) << 16);
    pk.y = (uint32_t)f2bf(r[2]) | ((uint32_t)f2bf(r[3]) << 16);
    pk.z = (uint32_t)f2bf(r[4]) | ((uint32_t)f2bf(r[5]) << 16);
    pk.w = (uint32_t)f2bf(r[6]) | ((uint32_t)f2bf(r[7]) << 16);
    *(uint4*)(&((unsigned short*)outp)[o]) = pk;
  } else {
    float4 r0, r1;
    r0.x = r[0]; r0.y = r[1]; r0.z = r[2]; r0.w = r[3];
    r1.x = r[4]; r1.y = r[5]; r1.z = r[6]; r1.w = r[7];
    *(float4*)(&((float*)outp)[o]) = r0;
    *(float4*)(&((float*)outp)[o + 4]) = r1;
  }

  // LayerNorm across the wave (512 ch = 64 lanes x 8)
  float s = 0.f, ss = 0.f;
  #pragma unroll
  for (int e = 0; e < 8; e++) { s += r[e]; ss += r[e] * r[e]; }
  #pragma unroll
  for (int of = 32; of; of >>= 1) {
    s += __shfl_xor(s, of, 64);
    ss += __shfl_xor(ss, of, 64);
  }
  float mu = s * (1.f / CC);
  float var = ss * (1.f / CC) - mu * mu;
  float rsd = rsqrtf(var + 1e-5f);
  float4 g0 = *(const float4*)(&lng[c]);
  float4 g1 = *(const float4*)(&lng[c + 4]);
  float4 b0 = *(const float4*)(&lnb[c]);
  float4 b1 = *(const float4*)(&lnb[c + 4]);
  float gv[8] = {g0.x, g0.y, g0.z, g0.w, g1.x, g1.y, g1.z, g1.w};
  float bv[8] = {b0.x, b0.y, b0.z, b0.w, b1.x, b1.y, b1.z, b1.w};
  float ov[8];
  #pragma unroll
  for (int e = 0; e < 8; e++) ov[e] = (r[e] - mu) * rsd * gv[e] + bv[e];
  uint2 pk8;
  pk8.x = (uint32_t)cvt4_fp8(ov[0], ov[1], ov[2], ov[3]);
  pk8.y = (uint32_t)cvt4_fp8(ov[4], ov[5], ov[6], ov[7]);
  *(uint2*)(&ln8[o]) = pk8;
}

// ==== fp8 GEMM (non-MX), BM256/BN128/BK64 — proj (MODE 3 only), K templated ====
#define BM 256
#define BN 128
#define BK8 64

template <int MODE, int K>
__global__ __launch_bounds__(512) void gemm8_kernel(
    const unsigned char* __restrict__ A, const unsigned char* __restrict__ BT,
    const float* __restrict__ bias, const unsigned short* __restrict__ resB,
    unsigned short* __restrict__ outB16, int M, int N) {
  __shared__ unsigned char ldsb[49152];
  int nwg = gridDim.x * gridDim.y;
  int flat = blockIdx.y * gridDim.x + blockIdx.x;
  int swz = (flat & 7) * (nwg >> 3) + (flat >> 3);
  int bx = swz % gridDim.x, by = swz / gridDim.x;
  const int bm = by * BM, bn = bx * BN;
  const int t = threadIdx.x;
  const int wid = t >> 6, lane = t & 63;
  const int wr = wid >> 1, wc = wid & 1;
  const int lr = lane & 15, g = lane >> 4;
  const int swr = (lr >> 1) & 3;
  const int rb0 = (((g >> 1)      ) ^ swr) * 16 + (g & 1) * 8;
  const int rb1 = (((g >> 1) + 2) ^ swr) * 16 + (g & 1) * 8;
  const int srow = t >> 2;
  const int scol = (((t & 3) ^ ((t >> 3) & 3)) & 3) * 16;
  const size_t arow0 = (size_t)(bm + srow) * K + scol;
  const size_t arow1 = (size_t)(bm + 128 + srow) * K + scol;
  const size_t brow  = (size_t)(bn + srow) * K + scol;
  const int ldso = wid * 1024;

#define STG8(b, kt) do { \
    gload16(&A[arow0 + (kt)], ldsb + (b) * 16384 + ldso); \
    gload16(&A[arow1 + (kt)], ldsb + (b) * 16384 + 8192 + ldso); \
    gload16(&BT[brow + (kt)], ldsb + 32768 + (b) * 8192 + ldso); } while (0)

  f32x4 acc[4][4] = {};
  constexpr int nt = K / BK8;

  STG8(0, 0);
  STG8(1, BK8);

  #pragma unroll
  for (int tile = 0; tile < nt - 1; ++tile) {
    WAITV3(); BAR();
    const unsigned char* as = ldsb + (tile & 1) * 16384;
    const unsigned char* bs = ldsb + 32768 + (tile & 1) * 8192;
    i64 af0[4], af1[4], bf0[4], bf1[4];
    #pragma unroll
    for (int i = 0; i < 4; i++) {
      const unsigned char* p = &as[(wr * 64 + i * 16 + lr) * BK8];
      af0[i] = *(const i64*)(p + rb0);
      af1[i] = *(const i64*)(p + rb1);
    }
    #pragma unroll
    for (int j = 0; j < 4; j++) {
      const unsigned char* p = &bs[(wc * 64 + j * 16 + lr) * BK8];
      bf0[j] = *(const i64*)(p + rb0);
      bf1[j] = *(const i64*)(p + rb1);
    }
    WAITL();
    BAR();
    if (tile + 2 < nt) STG8(tile & 1, (tile + 2) * BK8);
    __builtin_amdgcn_s_setprio(1);
    #pragma unroll
    for (int i = 0; i < 4; i++)
      #pragma unroll
      for (int j = 0; j < 4; j++) {
        acc[i][j] = __builtin_amdgcn_mfma_f32_16x16x32_fp8_fp8(af0[i], bf0[j], acc[i][j], 0, 0, 0);
        acc[i][j] = __builtin_amdgcn_mfma_f32_16x16x32_fp8_fp8(af1[i], bf1[j], acc[i][j], 0, 0, 0);
      }
    __builtin_amdgcn_s_setprio(0);
  }
  {
    WAITV0(); BAR();
    const unsigned char* as = ldsb + ((nt - 1) & 1) * 16384;
    const unsigned char* bs = ldsb + 32768 + ((nt - 1) & 1) * 8192;
    i64 af0[4], af1[4], bf0[4], bf1[4];
    #pragma unroll
    for (int i = 0; i < 4; i++) {
      const unsigned char* p = &as[(wr * 64 + i * 16 + lr) * BK8];
      af0[i] = *(const i64*)(p + rb0);
      af1[i] = *(const i64*)(p + rb1);
    }
    #pragma unroll
    for (int j = 0; j < 4; j++) {
      const unsigned char* p = &bs[(wc * 64 + j * 16 + lr) * BK8];
      bf0[j] = *(const i64*)(p + rb0);
      bf1[j] = *(const i64*)(p + rb1);
    }
    WAITL();
    #pragma unroll
    for (int i = 0; i < 4; i++)
      #pragma unroll
      for (int j = 0; j < 4; j++) {
        acc[i][j] = __builtin_amdgcn_mfma_f32_16x16x32_fp8_fp8(af0[i], bf0[j], acc[i][j], 0, 0, 0);
        acc[i][j] = __builtin_amdgcn_mfma_f32_16x16x32_fp8_fp8(af1[i], bf1[j], acc[i][j], 0, 0, 0);
      }
  }
#undef STG8

  // ---- epilogue (restaged): MODE 3: out bf16 = acc/32 + bias + res_bf16 ----
  {
    const float SC = 0.03125f;
    float* eps = (float*)ldsb;
    const int erow = t >> 3;
    const int ecol0 = (t & 7) * 16;
    const int wrow = wr * 16 + (lane >> 4) * 4;
    const int wcol = wc * 64 + lr;
    const int gr_base = bm + (erow >> 4) * 64 + (erow & 15);
    const int gc0 = bn + ecol0;
    float bv[16];
    #pragma unroll
    for (int c4 = 0; c4 < 4; c4++)
      *(float4*)&bv[c4 * 4] = *(const float4*)&bias[gc0 + c4 * 4];
    #pragma unroll
    for (int i = 0; i < 4; i++) {
      __syncthreads();
      #pragma unroll
      for (int j = 0; j < 4; j++)
        #pragma unroll
        for (int r = 0; r < 4; r++)
          eps[(wrow + r) * 132 + wcol + j * 16] = acc[i][j][r];
      __syncthreads();
      float vv[16];
      #pragma unroll
      for (int c4 = 0; c4 < 4; c4++)
        *(float4*)&vv[c4 * 4] = *(const float4*)&eps[erow * 132 + ecol0 + c4 * 4];
      const size_t off = (size_t)(gr_base + i * 16) * N + gc0;
      uint4 r0 = *(const uint4*)&resB[off];
      uint4 r1 = *(const uint4*)&resB[off + 8];
      unsigned short ob[16];
      const uint32_t* rp = (const uint32_t*)&r0;
      #pragma unroll
      for (int c = 0; c < 8; c++) {
        uint32_t u = rp[c >> 1];
        float rv = bf2f((unsigned short)((c & 1) ? (u >> 16) : (u & 0xffff)));
        ob[c] = f2bf(vv[c] * SC + bv[c] + rv);
      }
      const uint32_t* rp1 = (const uint32_t*)&r1;
      #pragma unroll
      for (int c = 0; c < 8; c++) {
        uint32_t u = rp1[c >> 1];
        float rv = bf2f((unsigned short)((c & 1) ? (u >> 16) : (u & 0xffff)));
        ob[8 + c] = f2bf(vv[8 + c] * SC + bv[8 + c] + rv);
      }
      *(uint4*)&outB16[off]     = *(uint4*)&ob[0];
      *(uint4*)&outB16[off + 8] = *(uint4*)&ob[8];
    }
  }
}

// ==== MX-scaled fp8 GEMM: 16x16x128 f8f6f4, 512 thr = 8 waves (2Mx4N) ====
// Tile 128x128, per-wave 64x32. LDS 64KB dbuf, restage-after-barrier, vmcnt(4).
// LDS[row][c] = global[row][c ^ (row&7)] (16B chunks); reader XORs the same.
__device__ __forceinline__ i32x8 ld_frag128(const unsigned char* base, int row, int g, int lrm7) {
  const uint4 lo = *(const uint4*)(base + row * 128 + (((2 * g)     ^ lrm7) * 16));
  const uint4 hi = *(const uint4*)(base + row * 128 + (((2 * g + 1) ^ lrm7) * 16));
  i32x8 r;
  r[0] = lo.x; r[1] = lo.y; r[2] = lo.z; r[3] = lo.w;
  r[4] = hi.x; r[5] = hi.y; r[6] = hi.z; r[7] = hi.w;
  return r;
}

template <int MODE, int K>
__global__ __launch_bounds__(512) void gemm8mx_kernel(
    const unsigned char* __restrict__ A, const unsigned char* __restrict__ BT,
    const float* __restrict__ bias, const float* __restrict__ res,
    float* __restrict__ outF, unsigned char* __restrict__ outB8,
    int M, int N) {
  __shared__ unsigned char ldsb[65536];   // A bufs @0,16K ; B bufs @32K,48K
  const int SCALE1 = 0x7F7F7F7F;          // e8m0 127 in every byte = x1.0
  int nwg = gridDim.x * gridDim.y;
  int flat = blockIdx.y * gridDim.x + blockIdx.x;
  int swz = (flat & 7) * (nwg >> 3) + (flat >> 3);
  int bx = swz % gridDim.x, by = swz / gridDim.x;
  const int bm = by * 128, bn = bx * 128;
  const int t = threadIdx.x;
  const int wid = t >> 6, lane = t & 63;
  const int wr = wid >> 2, wc = wid & 3;          // 2M x 4N wave grid
  const int lr = lane & 15, g = lane >> 4, lrm7 = lane & 7;
  // staging: wave wid, q in {0,1}: rows wid*16 + q*8 + (lane>>3); chunk lane&7.
  const int srow8 = lane >> 3;                    // 0..7
  const int schunk = ((lane & 7) ^ srow8) * 16;
  const size_t aBase = (size_t)(bm + wid * 16 + srow8) * K + schunk;
  const size_t bBase = (size_t)(bn + wid * 16 + srow8) * K + schunk;
  const size_t row8K = (size_t)8 * K;
  const int ldsl = wid * 2048;                    // 2 slices x 1KB per wave

#define STGMX(p, kt) do { \
    gload16(&A[aBase + (kt)],          ldsb + (p) * 16384 + ldsl); \
    gload16(&A[aBase + row8K + (kt)],  ldsb + (p) * 16384 + ldsl + 1024); \
    gload16(&BT[bBase + (kt)],         ldsb + 32768 + (p) * 16384 + ldsl); \
    gload16(&BT[bBase + row8K + (kt)], ldsb + 32768 + (p) * 16384 + ldsl + 1024); } while (0)

  f32x4 acc[4][2] = {};
  constexpr int npt = K / 128;

  STGMX(0, 0);
  STGMX(1, 128);

  #pragma unroll
  for (int pt = 0; pt < npt - 1; ++pt) {
    WAITV4(); BAR();
    const unsigned char* as = ldsb + (pt & 1) * 16384;
    const unsigned char* bs = ldsb + 32768 + (pt & 1) * 16384;
    i32x8 af[4], bf[2];
    #pragma unroll
    for (int i = 0; i < 4; i++)
      af[i] = ld_frag128(as, wr * 64 + i * 16 + lr, g, lrm7);
    #pragma unroll
    for (int j = 0; j < 2; j++)
      bf[j] = ld_frag128(bs, wc * 32 + j * 16 + lr, g, lrm7);
    WAITL();
    BAR();
    if (pt + 2 < npt) STGMX(pt & 1, (pt + 2) * 128);
    __builtin_amdgcn_s_setprio(1);
    #pragma unroll
    for (int i = 0; i < 4; i++)
      #pragma unroll
      for (int j = 0; j < 2; j++)
        acc[i][j] = __builtin_amdgcn_mfma_scale_f32_16x16x128_f8f6f4(
            af[i], bf[j], acc[i][j], 0, 0, 0, SCALE1, 0, SCALE1);
    __builtin_amdgcn_s_setprio(0);
  }
  {
    WAITV0(); BAR();
    const unsigned char* as = ldsb + ((npt - 1) & 1) * 16384;
    const unsigned char* bs = ldsb + 32768 + ((npt - 1) & 1) * 16384;
    i32x8 af[4], bf[2];
    #pragma unroll
    for (int i = 0; i < 4; i++)
      af[i] = ld_frag128(as, wr * 64 + i * 16 + lr, g, lrm7);
    #pragma unroll
    for (int j = 0; j < 2; j++)
      bf[j] = ld_frag128(bs, wc * 32 + j * 16 + lr, g, lrm7);
    WAITL();
    #pragma unroll
    for (int i = 0; i < 4; i++)
      #pragma unroll
      for (int j = 0; j < 2; j++)
        acc[i][j] = __builtin_amdgcn_mfma_scale_f32_16x16x128_f8f6f4(
            af[i], bf[j], acc[i][j], 0, 0, 0, SCALE1, 0, SCALE1);
  }
#undef STGMX

  // ---- epilogue: 2 passes of 64 rows x 128 cols via LDS restage ----
  {
    const float SC = 0.03125f;
    float* eps = (float*)ldsb;              // 64*132*4 = 33.8KB < 64KB
    const int erow = t >> 3;                // 0..63
    const int cb = (t & 7) * 16;            // 16 consecutive cols per thread
    float4 bv4[4];
    #pragma unroll
    for (int c4 = 0; c4 < 4; c4++)
      bv4[c4] = *(const float4*)&bias[bn + cb + c4 * 4];
    #pragma unroll
    for (int p = 0; p < 2; p++) {
      __syncthreads();
      if (wr == p) {
        #pragma unroll
        for (int i = 0; i < 4; i++)
          #pragma unroll
          for (int j = 0; j < 2; j++)
            #pragma unroll
            for (int r = 0; r < 4; r++)
              eps[(i * 16 + g * 4 + r) * 132 + wc * 32 + j * 16 + lr] = acc[i][j][r];
      }
      __syncthreads();
      const size_t rowoff = (size_t)(bm + p * 64 + erow) * N + bn + cb;
      if (MODE == 1) {
        #pragma unroll
        for (int c4 = 0; c4 < 4; c4++) {
          float4 vv = *(const float4*)&eps[erow * 132 + cb + c4 * 4];
          float4 rv = *(const float4*)&res[rowoff + c4 * 4];
          float4 ov;
          ov.x = vv.x * SC + bv4[c4].x + rv.x;
          ov.y = vv.y * SC + bv4[c4].y + rv.y;
          ov.z = vv.z * SC + bv4[c4].z + rv.z;
          ov.w = vv.w * SC + bv4[c4].w + rv.w;
          *(float4*)&outF[rowoff + c4 * 4] = ov;
        }
      } else {
        uint32_t ob32[4];
        #pragma unroll
        for (int c4 = 0; c4 < 4; c4++) {
          float4 vv = *(const float4*)&eps[erow * 132 + cb + c4 * 4];
          float v0 = vv.x * SC + bv4[c4].x;
          float v1 = vv.y * SC + bv4[c4].y;
          float v2 = vv.z * SC + bv4[c4].z;
          float v3 = vv.w * SC + bv4[c4].w;
          if (MODE == 2) {
            float vin[4] = {v0, v1, v2, v3};
            float gvv[4];
            #pragma unroll
            for (int e = 0; e < 4; e++) {
              float v = vin[e];
              float a2 = v * v;
              float w = v * fmaf(a2, -0.1029436f, -2.3024849f);
              float sg = __builtin_amdgcn_rcpf(1.f + __builtin_amdgcn_exp2f(w));
              gvv[e] = v * sg;
            }
            ob32[c4] = (uint32_t)cvt4_fp8(gvv[0], gvv[1], gvv[2], gvv[3]);
          } else {
            ob32[c4] = (uint32_t)cvt4_fp8(v0, v1, v2, v3);
          }
        }
        *(uint4*)&outB8[rowoff] = *(uint4*)&ob32[0];
      }
    }
  }
}

// -------- fp8 MFMA window attention: 1 wave per (window, head), all-fp8 IO -------
#define WNS8 72   // byte stride: 64B data + 8 pad, 8-aligned

__global__ __launch_bounds__(64) void attn_mfma8_kernel(
    const unsigned char* __restrict__ qkv, unsigned char* __restrict__ out) {
  __shared__ unsigned char VT[64 * WNS8];   // V^T: [d][k] fp8
  __shared__ unsigned char Ps[64 * WNS8];   // P:   [q][k] fp8
  const int task = blockIdx.x;
  const int win = task >> 3, h = task & 7;
  const int b = win >> 8, wy = (win >> 4) & 15, wx = win & 15;
  const int lane = threadIdx.x;
  const int lr = lane & 15, g = lane >> 4;

  auto tokof = [&](int r) {
    int rr = r > 48 ? 48 : r;
    int y = rr / 7, x2 = rr - y * 7;
    return (size_t)(b * LLEN + (wy * 7 + y) * WW + wx * 7 + x2);
  };

  {
    size_t vbase = tokof(lane) * 1536 + 1024 + h * 64;
    bool valid = lane <= 48;
    #pragma unroll
    for (int c = 0; c < 4; c++) {
      uint4 v = *(const uint4*)(&qkv[vbase + c * 16]);
      const unsigned char* pv = (const unsigned char*)&v;
      #pragma unroll
      for (int e = 0; e < 16; e++)
        VT[(c * 16 + e) * WNS8 + lane] = valid ? pv[e] : (unsigned char)0;
    }
  }

  size_t tok[4];
  #pragma unroll
  for (int i2 = 0; i2 < 4; i2++) tok[i2] = tokof(i2 * 16 + lr);
  i64 Qf[4][2], Kf[4][2];
  #pragma unroll
  for (int i2 = 0; i2 < 4; i2++) {
    size_t base = tok[i2] * 1536 + h * 64 + g * 8;
    #pragma unroll
    for (int ks = 0; ks < 2; ks++) {
      Qf[i2][ks] = *(const i64*)(&qkv[base + ks * 32]);
      Kf[i2][ks] = *(const i64*)(&qkv[base + 512 + ks * 32]);
    }
  }

  f32x4 acc[4][4] = {};
  #pragma unroll
  for (int ks = 0; ks < 2; ks++)
    #pragma unroll
    for (int i2 = 0; i2 < 4; i2++)
      #pragma unroll
      for (int j = 0; j < 4; j++)
        acc[i2][j] = __builtin_amdgcn_mfma_f32_16x16x32_fp8_fp8(Kf[i2][ks], Qf[j][ks], acc[i2][j], 0, 0, 0);

  #pragma unroll
  for (int j = 0; j < 4; j++) {
    float mx = -1e30f;
    #pragma unroll
    for (int i2 = 0; i2 < 4; i2++)
      #pragma unroll
      for (int r = 0; r < 4; r++) {
        int k = 16 * i2 + 4 * g + r;
        mx = fmaxf(mx, (k <= 48) ? acc[i2][j][r] : -1e30f);
      }
    mx = fmaxf(mx, __shfl_xor(mx, 16, 64));
    mx = fmaxf(mx, __shfl_xor(mx, 32, 64));
    float p[4][4];
    float sum = 0.f;
    #pragma unroll
    for (int i2 = 0; i2 < 4; i2++)
      #pragma unroll
      for (int r = 0; r < 4; r++) {
        int k = 16 * i2 + 4 * g + r;
        float e = (k <= 48) ? __expf(0.125f * (acc[i2][j][r] - mx)) : 0.f;
        p[i2][r] = e; sum += e;
      }
    sum += __shfl_xor(sum, 16, 64);
    sum += __shfl_xor(sum, 32, 64);
    float inv = 1.f / sum;
    int q = 16 * j + lr;
    #pragma unroll
    for (int i2 = 0; i2 < 4; i2++) {
      uint32_t w = (uint32_t)cvt4_fp8(p[i2][0] * inv, p[i2][1] * inv,
                                      p[i2][2] * inv, p[i2][3] * inv);
      *(uint32_t*)(&Ps[q * WNS8 + 16 * i2 + 4 * g]) = w;
    }
  }

  __syncthreads();

  f32x4 o[4][4] = {};
  #pragma unroll
  for (int ks = 0; ks < 2; ks++) {
    i64 Pf[4], Vf[4];
    #pragma unroll
    for (int i2 = 0; i2 < 4; i2++)
      Pf[i2] = *(const i64*)(&Ps[(16 * i2 + lr) * WNS8 + ks * 32 + g * 8]);
    #pragma unroll
    for (int j = 0; j < 4; j++)
      Vf[j] = *(const i64*)(&VT[(16 * j + lr) * WNS8 + ks * 32 + g * 8]);
    #pragma unroll
    for (int i2 = 0; i2 < 4; i2++)
      #pragma unroll
      for (int j = 0; j < 4; j++)
        o[i2][j] = __builtin_amdgcn_mfma_f32_16x16x32_fp8_fp8(Pf[i2], Vf[j], o[i2][j], 0, 0, 0);
  }

  #pragma unroll
  for (int i2 = 0; i2 < 4; i2++)
    #pragma unroll
    for (int r = 0; r < 4; r++) {
      int q = 16 * i2 + 4 * g + r;
      if (q <= 48) {
        size_t obase = tokof(q) * 512 + h * 64 + lr;
        #pragma unroll
        for (int j = 0; j < 4; j++) {
          float v = o[i2][j][r];
          int rr = __builtin_amdgcn_cvt_pk_fp8_f32(v, v, 0, false);
          out[obase + 16 * j] = (unsigned char)rr;
        }
      }
    }
}

extern "C" void kernel_launch(void* const* d_in, const int* in_sizes, int n_in,
                              void* d_out, int out_size, void* d_ws, size_t ws_size,
                              hipStream_t stream) {
  const float* x      = (const float*)d_in[0];
  const float* cpe0_w = (const float*)d_in[1];
  const float* cpe0_b = (const float*)d_in[2];
  const float* cpe1_w = (const float*)d_in[3];
  const float* cpe1_b = (const float*)d_in[4];
  const float* ln1_g  = (const float*)d_in[5];
  const float* ln1_b  = (const float*)d_in[6];
  const float* ln2_g  = (const float*)d_in[7];
  const float* ln2_b  = (const float*)d_in[8];
  const float* qkv_w  = (const float*)d_in[9];
  const float* qkv_b  = (const float*)d_in[10];
  const float* proj_w = (const float*)d_in[11];
  const float* proj_b = (const float*)d_in[12];
  const float* fc1_w  = (const float*)d_in[13];
  const float* fc1_b  = (const float*)d_in[14];
  const float* fc2_w  = (const float*)d_in[15];
  const float* fc2_b  = (const float*)d_in[16];
  float* out = (float*)d_out;
  char* ws = (char*)d_ws;

  unsigned char*  qkvwT8 = (unsigned char*)(ws + 0);            // 1536x512 fp8
  unsigned char*  projwT8 = (unsigned char*)(ws + 1048576);     // 512x512 fp8
  unsigned char*  fc1wT8 = (unsigned char*)(ws + 2097152);      // 2048x512 fp8
  unsigned char*  fc2wT8 = (unsigned char*)(ws + 4194304);      // 512x2048 fp8
  unsigned short* shortcB = (unsigned short*)(ws + 6291456);    // 50176x512 bf16
  unsigned char*  lnb8   = (unsigned char*)(ws + 109051904);    // 50176x512 fp8
  unsigned char*  qkvb8  = (unsigned char*)(ws + 160432128);    // 50176x1536 fp8
  unsigned char*  attnb8 = (unsigned char*)(ws + 314572800);    // 50176x512 fp8
  unsigned char*  gelub8 = (unsigned char*)(ws + 160432128);    // overlay qkvb8
  float* h2 = out;                 // d_out doubles as h2 (f32)

  wtranspose8_kernel<<<(512 * 1536 + 255) / 256, 256, 0, stream>>>(qkv_w, qkvwT8, 512, 1536);
  wtranspose8_kernel<<<(512 * 512 + 255) / 256, 256, 0, stream>>>(proj_w, projwT8, 512, 512);
  wtranspose8_kernel<<<(512 * 2048 + 255) / 256, 256, 0, stream>>>(fc1_w, fc1wT8, 512, 2048);
  wtranspose8_kernel<<<(2048 * 512 + 255) / 256, 256, 0, stream>>>(fc2_w, fc2wT8, 2048, 512);

  // shortcut = x + dwconv(x) -> bf16 ; fused ln1 -> fp8   (1 wave/pixel)
  cpe_ln_kernel<0, 1><<<dim3(28, 112, BB), 256, 0, stream>>>(x, cpe0_w, cpe0_b,
      ln1_g, ln1_b, shortcB, lnb8);
  // qkv (MX fp8): fp8 out
  gemm8mx_kernel<0, 512><<<dim3(12, 392), 512, 0, stream>>>(lnb8, qkvwT8, qkv_b, nullptr,
      nullptr, qkvb8, NTOK, 1536);
  // window attention, all-fp8
  attn_mfma8_kernel<<<8192, 64, 0, stream>>>(qkvb8, attnb8);
  // h = shortcut + attn@proj_w + b  (fp8 A, bf16 res/out in-place)
  gemm8_kernel<3, 512><<<dim3(4, 196), 512, 0, stream>>>(attnb8, projwT8, proj_b,
      shortcB, shortcB, NTOK, 512);
  // h2 = h + dwconv(h) -> f32 (d_out) ; fused ln2 -> fp8   (1 wave/pixel)
  cpe_ln_kernel<1, 0><<<dim3(28, 112, BB), 256, 0, stream>>>(shortcB, cpe1_w, cpe1_b,
      ln2_g, ln2_b, h2, lnb8);
  // fc1 (MX fp8): gelu -> fp8
  gemm8mx_kernel<2, 512><<<dim3(16, 392), 512, 0, stream>>>(lnb8, fc1wT8, fc1_b, nullptr,
      nullptr, gelub8, NTOK, 2048);
  // fc2 (MX fp8): f32 out + h2 residual
  gemm8mx_kernel<1, 2048><<<dim3(4, 392), 512, 0, stream>>>(gelub8, fc2wT8, fc2_b, h2,
      out, nullptr, NTOK, 512);
}

// Round 16
// 515.317 us; speedup vs baseline: 1.3545x; 1.0344x over previous
//
#include <hip/hip_runtime.h>
#include <stdint.h>

#define HH 112
#define WW 112
#define CC 512
#define BB 4
#define LLEN (HH*WW)
#define NTOK (BB*LLEN)   // 50176
#define NHEADS 8
#define HD 64
#define HIDDEN 2048

typedef __bf16 bf16x8 __attribute__((ext_vector_type(8)));
typedef float f32x4 __attribute__((ext_vector_type(4)));
typedef int i32x8 __attribute__((ext_vector_type(8)));
typedef long i64;

__device__ __forceinline__ unsigned short f2bf(float x) {
  uint32_t u = __float_as_uint(x);
  u += 0x7fffu + ((u >> 16) & 1u);
  return (unsigned short)(u >> 16);
}
__device__ __forceinline__ float bf2f(unsigned short h) {
  return __uint_as_float((uint32_t)h << 16);
}
__device__ __forceinline__ int cvt4_fp8(float a, float b, float c, float d) {
  int r = 0;
  r = __builtin_amdgcn_cvt_pk_fp8_f32(a, b, r, false);
  r = __builtin_amdgcn_cvt_pk_fp8_f32(c, d, r, true);
  return r;
}

__device__ __forceinline__ void gload16(const void* gptr, void* lptr) {
  __builtin_amdgcn_global_load_lds(
      (const __attribute__((address_space(1))) void*)gptr,
      (__attribute__((address_space(3))) void*)lptr,
      16, 0, 0);
}

#define WAITV3() asm volatile("s_waitcnt vmcnt(3)" ::: "memory")
#define WAITV4() asm volatile("s_waitcnt vmcnt(4)" ::: "memory")
#define WAITV0() asm volatile("s_waitcnt vmcnt(0)" ::: "memory")
#define BAR() __builtin_amdgcn_s_barrier()
#define WAITL() do { asm volatile("s_waitcnt lgkmcnt(0)" ::: "memory"); \
                     __builtin_amdgcn_sched_barrier(0); } while (0)

// ------- ALL weight transposes (K,N) f32 -> (N,K) fp8 x32, one launch -------
__global__ __launch_bounds__(256) void wtall_kernel(
    const float* __restrict__ qkv_w, const float* __restrict__ proj_w,
    const float* __restrict__ fc1_w, const float* __restrict__ fc2_w,
    unsigned char* __restrict__ o0, unsigned char* __restrict__ o1,
    unsigned char* __restrict__ o2, unsigned char* __restrict__ o3) {
  int idx = blockIdx.x * 256 + threadIdx.x;
  const float* w; unsigned char* o; int K, N;
  if (idx < 786432)        { w = qkv_w;  o = o0; K = 512;  N = 1536; }
  else if (idx < 1048576)  { w = proj_w; o = o1; K = 512;  N = 512;  idx -= 786432; }
  else if (idx < 2097152)  { w = fc1_w;  o = o2; K = 512;  N = 2048; idx -= 1048576; }
  else                     { w = fc2_w;  o = o3; K = 2048; N = 512;  idx -= 2097152; }
  int n = idx / K, k = idx - n * K;
  float v = w[(size_t)k * N + n] * 32.f;
  int r = __builtin_amdgcn_cvt_pk_fp8_f32(v, v, 0, false);
  o[idx] = (unsigned char)r;
}

// ==== FUSED depthwise 3x3 conv + residual + LayerNorm ====
// One wave = one pixel; 8 channels/thread. grid (28,112,BB), block 256 (4 pixels).
// Conv+res output always bf16; also emits fp8 LN(conv+res).
template <int INBF>
__global__ __launch_bounds__(256) void cpe_ln_kernel(
    const void* __restrict__ xin, const float* __restrict__ w,
    const float* __restrict__ bias, const float* __restrict__ lng,
    const float* __restrict__ lnb, unsigned short* __restrict__ outB,
    unsigned char* __restrict__ ln8) {
  const int wid = threadIdx.x >> 6;
  const int lane = threadIdx.x & 63;
  const int xx = blockIdx.x * 4 + wid;    // 0..111
  const int yy = blockIdx.y;
  const int bb = blockIdx.z;
  const int c = lane * 8;                 // 8 channels per thread

  float acc[8];
  {
    float4 b0 = *(const float4*)(&bias[c]);
    float4 b1 = *(const float4*)(&bias[c + 4]);
    acc[0] = b0.x; acc[1] = b0.y; acc[2] = b0.z; acc[3] = b0.w;
    acc[4] = b1.x; acc[5] = b1.y; acc[6] = b1.z; acc[7] = b1.w;
  }
  float xv[8];   // center value (residual), captured at ky=kx=1

  #pragma unroll
  for (int ky = 0; ky < 3; ky++) {
    int y = yy + ky - 1;
    bool yok = (unsigned)y < (unsigned)HH;
    #pragma unroll
    for (int kx = 0; kx < 3; kx++) {
      int x2 = xx + kx - 1;
      bool ok = yok && ((unsigned)x2 < (unsigned)WW);
      float v[8];
      if (ok) {
        size_t eo = (((size_t)bb * HH + y) * WW + x2) * CC + c;
        if (INBF) {
          uint4 u = *(const uint4*)(&((const unsigned short*)xin)[eo]);
          v[0] = bf2f((unsigned short)(u.x & 0xffff)); v[1] = bf2f((unsigned short)(u.x >> 16));
          v[2] = bf2f((unsigned short)(u.y & 0xffff)); v[3] = bf2f((unsigned short)(u.y >> 16));
          v[4] = bf2f((unsigned short)(u.z & 0xffff)); v[5] = bf2f((unsigned short)(u.z >> 16));
          v[6] = bf2f((unsigned short)(u.w & 0xffff)); v[7] = bf2f((unsigned short)(u.w >> 16));
        } else {
          float4 a = *(const float4*)(&((const float*)xin)[eo]);
          float4 b = *(const float4*)(&((const float*)xin)[eo + 4]);
          v[0] = a.x; v[1] = a.y; v[2] = a.z; v[3] = a.w;
          v[4] = b.x; v[5] = b.y; v[6] = b.z; v[7] = b.w;
        }
      } else {
        #pragma unroll
        for (int e = 0; e < 8; e++) v[e] = 0.f;
      }
      if (ky == 1 && kx == 1) {
        #pragma unroll
        for (int e = 0; e < 8; e++) xv[e] = v[e];
      }
      float4 w0 = *(const float4*)(&w[(ky * 3 + kx) * CC + c]);
      float4 w1 = *(const float4*)(&w[(ky * 3 + kx) * CC + c + 4]);
      acc[0] = fmaf(v[0], w0.x, acc[0]); acc[1] = fmaf(v[1], w0.y, acc[1]);
      acc[2] = fmaf(v[2], w0.z, acc[2]); acc[3] = fmaf(v[3], w0.w, acc[3]);
      acc[4] = fmaf(v[4], w1.x, acc[4]); acc[5] = fmaf(v[5], w1.y, acc[5]);
      acc[6] = fmaf(v[6], w1.z, acc[6]); acc[7] = fmaf(v[7], w1.w, acc[7]);
    }
  }

  float r[8];
  #pragma unroll
  for (int e = 0; e < 8; e++) r[e] = xv[e] + acc[e];

  const size_t o = (((size_t)bb * HH + yy) * WW + xx) * CC + c;
  {
    uint4 pk;
    pk.x = (uint32_t)f2bf(r[0]) | ((uint32_t)f2bf(r[1]) << 16);
    pk.y = (uint32_t)f2bf(r[2]) | ((uint32_t)f2bf(r[3]) << 16);
    pk.z = (uint32_t)f2bf(r[4]) | ((uint32_t)f2bf(r[5]) << 16);
    pk.w = (uint32_t)f2bf(r[6]) | ((uint32_t)f2bf(r[7]) << 16);
    *(uint4*)(&outB[o]) = pk;
  }

  // LayerNorm across the wave (512 ch = 64 lanes x 8)
  float s = 0.f, ss = 0.f;
  #pragma unroll
  for (int e = 0; e < 8; e++) { s += r[e]; ss += r[e] * r[e]; }
  #pragma unroll
  for (int of = 32; of; of >>= 1) {
    s += __shfl_xor(s, of, 64);
    ss += __shfl_xor(ss, of, 64);
  }
  float mu = s * (1.f / CC);
  float var = ss * (1.f / CC) - mu * mu;
  float rsd = rsqrtf(var + 1e-5f);
  float4 g0 = *(const float4*)(&lng[c]);
  float4 g1 = *(const float4*)(&lng[c + 4]);
  float4 b0 = *(const float4*)(&lnb[c]);
  float4 b1 = *(const float4*)(&lnb[c + 4]);
  float gv[8] = {g0.x, g0.y, g0.z, g0.w, g1.x, g1.y, g1.z, g1.w};
  float bv[8] = {b0.x, b0.y, b0.z, b0.w, b1.x, b1.y, b1.z, b1.w};
  float ov[8];
  #pragma unroll
  for (int e = 0; e < 8; e++) ov[e] = (r[e] - mu) * rsd * gv[e] + bv[e];
  uint2 pk8;
  pk8.x = (uint32_t)cvt4_fp8(ov[0], ov[1], ov[2], ov[3]);
  pk8.y = (uint32_t)cvt4_fp8(ov[4], ov[5], ov[6], ov[7]);
  *(uint2*)(&ln8[o]) = pk8;
}

// ==== fp8 GEMM (non-MX), BM256/BN128/BK64 — proj (MODE 3 only), K templated ====
#define BM 256
#define BN 128
#define BK8 64

template <int MODE, int K>
__global__ __launch_bounds__(512) void gemm8_kernel(
    const unsigned char* __restrict__ A, const unsigned char* __restrict__ BT,
    const float* __restrict__ bias, const unsigned short* __restrict__ resB,
    unsigned short* __restrict__ outB16, int M, int N) {
  __shared__ unsigned char ldsb[49152];
  int nwg = gridDim.x * gridDim.y;
  int flat = blockIdx.y * gridDim.x + blockIdx.x;
  int swz = (flat & 7) * (nwg >> 3) + (flat >> 3);
  int bx = swz % gridDim.x, by = swz / gridDim.x;
  const int bm = by * BM, bn = bx * BN;
  const int t = threadIdx.x;
  const int wid = t >> 6, lane = t & 63;
  const int wr = wid >> 1, wc = wid & 1;
  const int lr = lane & 15, g = lane >> 4;
  const int swr = (lr >> 1) & 3;
  const int rb0 = (((g >> 1)      ) ^ swr) * 16 + (g & 1) * 8;
  const int rb1 = (((g >> 1) + 2) ^ swr) * 16 + (g & 1) * 8;
  const int srow = t >> 2;
  const int scol = (((t & 3) ^ ((t >> 3) & 3)) & 3) * 16;
  const size_t arow0 = (size_t)(bm + srow) * K + scol;
  const size_t arow1 = (size_t)(bm + 128 + srow) * K + scol;
  const size_t brow  = (size_t)(bn + srow) * K + scol;
  const int ldso = wid * 1024;

#define STG8(b, kt) do { \
    gload16(&A[arow0 + (kt)], ldsb + (b) * 16384 + ldso); \
    gload16(&A[arow1 + (kt)], ldsb + (b) * 16384 + 8192 + ldso); \
    gload16(&BT[brow + (kt)], ldsb + 32768 + (b) * 8192 + ldso); } while (0)

  f32x4 acc[4][4] = {};
  constexpr int nt = K / BK8;

  STG8(0, 0);
  STG8(1, BK8);

  #pragma unroll
  for (int tile = 0; tile < nt - 1; ++tile) {
    WAITV3(); BAR();
    const unsigned char* as = ldsb + (tile & 1) * 16384;
    const unsigned char* bs = ldsb + 32768 + (tile & 1) * 8192;
    i64 af0[4], af1[4], bf0[4], bf1[4];
    #pragma unroll
    for (int i = 0; i < 4; i++) {
      const unsigned char* p = &as[(wr * 64 + i * 16 + lr) * BK8];
      af0[i] = *(const i64*)(p + rb0);
      af1[i] = *(const i64*)(p + rb1);
    }
    #pragma unroll
    for (int j = 0; j < 4; j++) {
      const unsigned char* p = &bs[(wc * 64 + j * 16 + lr) * BK8];
      bf0[j] = *(const i64*)(p + rb0);
      bf1[j] = *(const i64*)(p + rb1);
    }
    WAITL();
    BAR();
    if (tile + 2 < nt) STG8(tile & 1, (tile + 2) * BK8);
    __builtin_amdgcn_s_setprio(1);
    #pragma unroll
    for (int i = 0; i < 4; i++)
      #pragma unroll
      for (int j = 0; j < 4; j++) {
        acc[i][j] = __builtin_amdgcn_mfma_f32_16x16x32_fp8_fp8(af0[i], bf0[j], acc[i][j], 0, 0, 0);
        acc[i][j] = __builtin_amdgcn_mfma_f32_16x16x32_fp8_fp8(af1[i], bf1[j], acc[i][j], 0, 0, 0);
      }
    __builtin_amdgcn_s_setprio(0);
  }
  {
    WAITV0(); BAR();
    const unsigned char* as = ldsb + ((nt - 1) & 1) * 16384;
    const unsigned char* bs = ldsb + 32768 + ((nt - 1) & 1) * 8192;
    i64 af0[4], af1[4], bf0[4], bf1[4];
    #pragma unroll
    for (int i = 0; i < 4; i++) {
      const unsigned char* p = &as[(wr * 64 + i * 16 + lr) * BK8];
      af0[i] = *(const i64*)(p + rb0);
      af1[i] = *(const i64*)(p + rb1);
    }
    #pragma unroll
    for (int j = 0; j < 4; j++) {
      const unsigned char* p = &bs[(wc * 64 + j * 16 + lr) * BK8];
      bf0[j] = *(const i64*)(p + rb0);
      bf1[j] = *(const i64*)(p + rb1);
    }
    WAITL();
    #pragma unroll
    for (int i = 0; i < 4; i++)
      #pragma unroll
      for (int j = 0; j < 4; j++) {
        acc[i][j] = __builtin_amdgcn_mfma_f32_16x16x32_fp8_fp8(af0[i], bf0[j], acc[i][j], 0, 0, 0);
        acc[i][j] = __builtin_amdgcn_mfma_f32_16x16x32_fp8_fp8(af1[i], bf1[j], acc[i][j], 0, 0, 0);
      }
  }
#undef STG8

  // ---- epilogue (restaged): MODE 3: out bf16 = acc/32 + bias + res_bf16 ----
  {
    const float SC = 0.03125f;
    float* eps = (float*)ldsb;
    const int erow = t >> 3;
    const int ecol0 = (t & 7) * 16;
    const int wrow = wr * 16 + (lane >> 4) * 4;
    const int wcol = wc * 64 + lr;
    const int gr_base = bm + (erow >> 4) * 64 + (erow & 15);
    const int gc0 = bn + ecol0;
    float bv[16];
    #pragma unroll
    for (int c4 = 0; c4 < 4; c4++)
      *(float4*)&bv[c4 * 4] = *(const float4*)&bias[gc0 + c4 * 4];
    #pragma unroll
    for (int i = 0; i < 4; i++) {
      __syncthreads();
      #pragma unroll
      for (int j = 0; j < 4; j++)
        #pragma unroll
        for (int r = 0; r < 4; r++)
          eps[(wrow + r) * 132 + wcol + j * 16] = acc[i][j][r];
      __syncthreads();
      float vv[16];
      #pragma unroll
      for (int c4 = 0; c4 < 4; c4++)
        *(float4*)&vv[c4 * 4] = *(const float4*)&eps[erow * 132 + ecol0 + c4 * 4];
      const size_t off = (size_t)(gr_base + i * 16) * N + gc0;
      uint4 r0 = *(const uint4*)&resB[off];
      uint4 r1 = *(const uint4*)&resB[off + 8];
      unsigned short ob[16];
      const uint32_t* rp = (const uint32_t*)&r0;
      #pragma unroll
      for (int c = 0; c < 8; c++) {
        uint32_t u = rp[c >> 1];
        float rv = bf2f((unsigned short)((c & 1) ? (u >> 16) : (u & 0xffff)));
        ob[c] = f2bf(vv[c] * SC + bv[c] + rv);
      }
      const uint32_t* rp1 = (const uint32_t*)&r1;
      #pragma unroll
      for (int c = 0; c < 8; c++) {
        uint32_t u = rp1[c >> 1];
        float rv = bf2f((unsigned short)((c & 1) ? (u >> 16) : (u & 0xffff)));
        ob[8 + c] = f2bf(vv[8 + c] * SC + bv[8 + c] + rv);
      }
      *(uint4*)&outB16[off]     = *(uint4*)&ob[0];
      *(uint4*)&outB16[off + 8] = *(uint4*)&ob[8];
    }
  }
}

// ==== MX-scaled fp8 GEMM: 16x16x128 f8f6f4, 512 thr = 8 waves (2Mx4N) ====
// MODE 0: fp8 out (qkv); MODE 2: fp8 gelu (fc1); MODE 4: f32 out + bf16 res (fc2)
__device__ __forceinline__ i32x8 ld_frag128(const unsigned char* base, int row, int g, int lrm7) {
  const uint4 lo = *(const uint4*)(base + row * 128 + (((2 * g)     ^ lrm7) * 16));
  const uint4 hi = *(const uint4*)(base + row * 128 + (((2 * g + 1) ^ lrm7) * 16));
  i32x8 r;
  r[0] = lo.x; r[1] = lo.y; r[2] = lo.z; r[3] = lo.w;
  r[4] = hi.x; r[5] = hi.y; r[6] = hi.z; r[7] = hi.w;
  return r;
}

template <int MODE, int K>
__global__ __launch_bounds__(512) void gemm8mx_kernel(
    const unsigned char* __restrict__ A, const unsigned char* __restrict__ BT,
    const float* __restrict__ bias, const unsigned short* __restrict__ resB,
    float* __restrict__ outF, unsigned char* __restrict__ outB8,
    int M, int N) {
  __shared__ unsigned char ldsb[65536];   // A bufs @0,16K ; B bufs @32K,48K
  const int SCALE1 = 0x7F7F7F7F;          // e8m0 127 in every byte = x1.0
  int nwg = gridDim.x * gridDim.y;
  int flat = blockIdx.y * gridDim.x + blockIdx.x;
  int swz = (flat & 7) * (nwg >> 3) + (flat >> 3);
  int bx = swz % gridDim.x, by = swz / gridDim.x;
  const int bm = by * 128, bn = bx * 128;
  const int t = threadIdx.x;
  const int wid = t >> 6, lane = t & 63;
  const int wr = wid >> 2, wc = wid & 3;          // 2M x 4N wave grid
  const int lr = lane & 15, g = lane >> 4, lrm7 = lane & 7;
  const int srow8 = lane >> 3;                    // 0..7
  const int schunk = ((lane & 7) ^ srow8) * 16;
  const size_t aBase = (size_t)(bm + wid * 16 + srow8) * K + schunk;
  const size_t bBase = (size_t)(bn + wid * 16 + srow8) * K + schunk;
  const size_t row8K = (size_t)8 * K;
  const int ldsl = wid * 2048;                    // 2 slices x 1KB per wave

#define STGMX(p, kt) do { \
    gload16(&A[aBase + (kt)],          ldsb + (p) * 16384 + ldsl); \
    gload16(&A[aBase + row8K + (kt)],  ldsb + (p) * 16384 + ldsl + 1024); \
    gload16(&BT[bBase + (kt)],         ldsb + 32768 + (p) * 16384 + ldsl); \
    gload16(&BT[bBase + row8K + (kt)], ldsb + 32768 + (p) * 16384 + ldsl + 1024); } while (0)

  f32x4 acc[4][2] = {};
  constexpr int npt = K / 128;

  STGMX(0, 0);
  STGMX(1, 128);

  #pragma unroll
  for (int pt = 0; pt < npt - 1; ++pt) {
    WAITV4(); BAR();
    const unsigned char* as = ldsb + (pt & 1) * 16384;
    const unsigned char* bs = ldsb + 32768 + (pt & 1) * 16384;
    i32x8 af[4], bf[2];
    #pragma unroll
    for (int i = 0; i < 4; i++)
      af[i] = ld_frag128(as, wr * 64 + i * 16 + lr, g, lrm7);
    #pragma unroll
    for (int j = 0; j < 2; j++)
      bf[j] = ld_frag128(bs, wc * 32 + j * 16 + lr, g, lrm7);
    WAITL();
    BAR();
    if (pt + 2 < npt) STGMX(pt & 1, (pt + 2) * 128);
    __builtin_amdgcn_s_setprio(1);
    #pragma unroll
    for (int i = 0; i < 4; i++)
      #pragma unroll
      for (int j = 0; j < 2; j++)
        acc[i][j] = __builtin_amdgcn_mfma_scale_f32_16x16x128_f8f6f4(
            af[i], bf[j], acc[i][j], 0, 0, 0, SCALE1, 0, SCALE1);
    __builtin_amdgcn_s_setprio(0);
  }
  {
    WAITV0(); BAR();
    const unsigned char* as = ldsb + ((npt - 1) & 1) * 16384;
    const unsigned char* bs = ldsb + 32768 + ((npt - 1) & 1) * 16384;
    i32x8 af[4], bf[2];
    #pragma unroll
    for (int i = 0; i < 4; i++)
      af[i] = ld_frag128(as, wr * 64 + i * 16 + lr, g, lrm7);
    #pragma unroll
    for (int j = 0; j < 2; j++)
      bf[j] = ld_frag128(bs, wc * 32 + j * 16 + lr, g, lrm7);
    WAITL();
    #pragma unroll
    for (int i = 0; i < 4; i++)
      #pragma unroll
      for (int j = 0; j < 2; j++)
        acc[i][j] = __builtin_amdgcn_mfma_scale_f32_16x16x128_f8f6f4(
            af[i], bf[j], acc[i][j], 0, 0, 0, SCALE1, 0, SCALE1);
  }
#undef STGMX

  // ---- epilogue: 2 passes of 64 rows x 128 cols via LDS restage ----
  {
    const float SC = 0.03125f;
    float* eps = (float*)ldsb;              // 64*132*4 = 33.8KB < 64KB
    const int erow = t >> 3;                // 0..63
    const int cb = (t & 7) * 16;            // 16 consecutive cols per thread
    float4 bv4[4];
    #pragma unroll
    for (int c4 = 0; c4 < 4; c4++)
      bv4[c4] = *(const float4*)&bias[bn + cb + c4 * 4];
    #pragma unroll
    for (int p = 0; p < 2; p++) {
      __syncthreads();
      if (wr == p) {
        #pragma unroll
        for (int i = 0; i < 4; i++)
          #pragma unroll
          for (int j = 0; j < 2; j++)
            #pragma unroll
            for (int r = 0; r < 4; r++)
              eps[(i * 16 + g * 4 + r) * 132 + wc * 32 + j * 16 + lr] = acc[i][j][r];
      }
      __syncthreads();
      const size_t rowoff = (size_t)(bm + p * 64 + erow) * N + bn + cb;
      if (MODE == 4) {
        uint4 r0 = *(const uint4*)&resB[rowoff];       // 8 bf16
        uint4 r1 = *(const uint4*)&resB[rowoff + 8];   // 8 bf16
        float rvv[16];
        const uint32_t* rp0 = (const uint32_t*)&r0;
        const uint32_t* rp1 = (const uint32_t*)&r1;
        #pragma unroll
        for (int c = 0; c < 8; c++) {
          uint32_t u = rp0[c >> 1];
          rvv[c] = bf2f((unsigned short)((c & 1) ? (u >> 16) : (u & 0xffff)));
        }
        #pragma unroll
        for (int c = 0; c < 8; c++) {
          uint32_t u = rp1[c >> 1];
          rvv[8 + c] = bf2f((unsigned short)((c & 1) ? (u >> 16) : (u & 0xffff)));
        }
        #pragma unroll
        for (int c4 = 0; c4 < 4; c4++) {
          float4 vv = *(const float4*)&eps[erow * 132 + cb + c4 * 4];
          float4 ov;
          ov.x = vv.x * SC + bv4[c4].x + rvv[c4 * 4 + 0];
          ov.y = vv.y * SC + bv4[c4].y + rvv[c4 * 4 + 1];
          ov.z = vv.z * SC + bv4[c4].z + rvv[c4 * 4 + 2];
          ov.w = vv.w * SC + bv4[c4].w + rvv[c4 * 4 + 3];
          *(float4*)&outF[rowoff + c4 * 4] = ov;
        }
      } else {
        uint32_t ob32[4];
        #pragma unroll
        for (int c4 = 0; c4 < 4; c4++) {
          float4 vv = *(const float4*)&eps[erow * 132 + cb + c4 * 4];
          float v0 = vv.x * SC + bv4[c4].x;
          float v1 = vv.y * SC + bv4[c4].y;
          float v2 = vv.z * SC + bv4[c4].z;
          float v3 = vv.w * SC + bv4[c4].w;
          if (MODE == 2) {
            float vin[4] = {v0, v1, v2, v3};
            float gvv[4];
            #pragma unroll
            for (int e = 0; e < 4; e++) {
              float v = vin[e];
              float a2 = v * v;
              float w = v * fmaf(a2, -0.1029436f, -2.3024849f);
              float sg = __builtin_amdgcn_rcpf(1.f + __builtin_amdgcn_exp2f(w));
              gvv[e] = v * sg;
            }
            ob32[c4] = (uint32_t)cvt4_fp8(gvv[0], gvv[1], gvv[2], gvv[3]);
          } else {
            ob32[c4] = (uint32_t)cvt4_fp8(v0, v1, v2, v3);
          }
        }
        *(uint4*)&outB8[rowoff] = *(uint4*)&ob32[0];
      }
    }
  }
}

// -------- fp8 MFMA window attention: 1 wave per (window, head), all-fp8 IO -------
#define WNS8 72   // byte stride: 64B data + 8 pad, 8-aligned

__global__ __launch_bounds__(64) void attn_mfma8_kernel(
    const unsigned char* __restrict__ qkv, unsigned char* __restrict__ out) {
  __shared__ unsigned char VT[64 * WNS8];   // V^T: [d][k] fp8
  __shared__ unsigned char Ps[64 * WNS8];   // P:   [q][k] fp8
  const int task = blockIdx.x;
  const int win = task >> 3, h = task & 7;
  const int b = win >> 8, wy = (win >> 4) & 15, wx = win & 15;
  const int lane = threadIdx.x;
  const int lr = lane & 15, g = lane >> 4;

  auto tokof = [&](int r) {
    int rr = r > 48 ? 48 : r;
    int y = rr / 7, x2 = rr - y * 7;
    return (size_t)(b * LLEN + (wy * 7 + y) * WW + wx * 7 + x2);
  };

  {
    size_t vbase = tokof(lane) * 1536 + 1024 + h * 64;
    bool valid = lane <= 48;
    #pragma unroll
    for (int c = 0; c < 4; c++) {
      uint4 v = *(const uint4*)(&qkv[vbase + c * 16]);
      const unsigned char* pv = (const unsigned char*)&v;
      #pragma unroll
      for (int e = 0; e < 16; e++)
        VT[(c * 16 + e) * WNS8 + lane] = valid ? pv[e] : (unsigned char)0;
    }
  }

  size_t tok[4];
  #pragma unroll
  for (int i2 = 0; i2 < 4; i2++) tok[i2] = tokof(i2 * 16 + lr);
  i64 Qf[4][2], Kf[4][2];
  #pragma unroll
  for (int i2 = 0; i2 < 4; i2++) {
    size_t base = tok[i2] * 1536 + h * 64 + g * 8;
    #pragma unroll
    for (int ks = 0; ks < 2; ks++) {
      Qf[i2][ks] = *(const i64*)(&qkv[base + ks * 32]);
      Kf[i2][ks] = *(const i64*)(&qkv[base + 512 + ks * 32]);
    }
  }

  f32x4 acc[4][4] = {};
  #pragma unroll
  for (int ks = 0; ks < 2; ks++)
    #pragma unroll
    for (int i2 = 0; i2 < 4; i2++)
      #pragma unroll
      for (int j = 0; j < 4; j++)
        acc[i2][j] = __builtin_amdgcn_mfma_f32_16x16x32_fp8_fp8(Kf[i2][ks], Qf[j][ks], acc[i2][j], 0, 0, 0);

  #pragma unroll
  for (int j = 0; j < 4; j++) {
    float mx = -1e30f;
    #pragma unroll
    for (int i2 = 0; i2 < 4; i2++)
      #pragma unroll
      for (int r = 0; r < 4; r++) {
        int k = 16 * i2 + 4 * g + r;
        mx = fmaxf(mx, (k <= 48) ? acc[i2][j][r] : -1e30f);
      }
    mx = fmaxf(mx, __shfl_xor(mx, 16, 64));
    mx = fmaxf(mx, __shfl_xor(mx, 32, 64));
    float p[4][4];
    float sum = 0.f;
    #pragma unroll
    for (int i2 = 0; i2 < 4; i2++)
      #pragma unroll
      for (int r = 0; r < 4; r++) {
        int k = 16 * i2 + 4 * g + r;
        float e = (k <= 48) ? __expf(0.125f * (acc[i2][j][r] - mx)) : 0.f;
        p[i2][r] = e; sum += e;
      }
    sum += __shfl_xor(sum, 16, 64);
    sum += __shfl_xor(sum, 32, 64);
    float inv = 1.f / sum;
    int q = 16 * j + lr;
    #pragma unroll
    for (int i2 = 0; i2 < 4; i2++) {
      uint32_t w = (uint32_t)cvt4_fp8(p[i2][0] * inv, p[i2][1] * inv,
                                      p[i2][2] * inv, p[i2][3] * inv);
      *(uint32_t*)(&Ps[q * WNS8 + 16 * i2 + 4 * g]) = w;
    }
  }

  __syncthreads();

  f32x4 o[4][4] = {};
  #pragma unroll
  for (int ks = 0; ks < 2; ks++) {
    i64 Pf[4], Vf[4];
    #pragma unroll
    for (int i2 = 0; i2 < 4; i2++)
      Pf[i2] = *(const i64*)(&Ps[(16 * i2 + lr) * WNS8 + ks * 32 + g * 8]);
    #pragma unroll
    for (int j = 0; j < 4; j++)
      Vf[j] = *(const i64*)(&VT[(16 * j + lr) * WNS8 + ks * 32 + g * 8]);
    #pragma unroll
    for (int i2 = 0; i2 < 4; i2++)
      #pragma unroll
      for (int j = 0; j < 4; j++)
        o[i2][j] = __builtin_amdgcn_mfma_f32_16x16x32_fp8_fp8(Pf[i2], Vf[j], o[i2][j], 0, 0, 0);
  }

  #pragma unroll
  for (int i2 = 0; i2 < 4; i2++)
    #pragma unroll
    for (int r = 0; r < 4; r++) {
      int q = 16 * i2 + 4 * g + r;
      if (q <= 48) {
        size_t obase = tokof(q) * 512 + h * 64 + lr;
        #pragma unroll
        for (int j = 0; j < 4; j++) {
          float v = o[i2][j][r];
          int rr = __builtin_amdgcn_cvt_pk_fp8_f32(v, v, 0, false);
          out[obase + 16 * j] = (unsigned char)rr;
        }
      }
    }
}

extern "C" void kernel_launch(void* const* d_in, const int* in_sizes, int n_in,
                              void* d_out, int out_size, void* d_ws, size_t ws_size,
                              hipStream_t stream) {
  const float* x      = (const float*)d_in[0];
  const float* cpe0_w = (const float*)d_in[1];
  const float* cpe0_b = (const float*)d_in[2];
  const float* cpe1_w = (const float*)d_in[3];
  const float* cpe1_b = (const float*)d_in[4];
  const float* ln1_g  = (const float*)d_in[5];
  const float* ln1_b  = (const float*)d_in[6];
  const float* ln2_g  = (const float*)d_in[7];
  const float* ln2_b  = (const float*)d_in[8];
  const float* qkv_w  = (const float*)d_in[9];
  const float* qkv_b  = (const float*)d_in[10];
  const float* proj_w = (const float*)d_in[11];
  const float* proj_b = (const float*)d_in[12];
  const float* fc1_w  = (const float*)d_in[13];
  const float* fc1_b  = (const float*)d_in[14];
  const float* fc2_w  = (const float*)d_in[15];
  const float* fc2_b  = (const float*)d_in[16];
  float* out = (float*)d_out;
  char* ws = (char*)d_ws;

  unsigned char*  qkvwT8  = (unsigned char*)(ws + 0);            // 1536x512 fp8
  unsigned char*  projwT8 = (unsigned char*)(ws + 1048576);      // 512x512 fp8
  unsigned char*  fc1wT8  = (unsigned char*)(ws + 2097152);      // 2048x512 fp8
  unsigned char*  fc2wT8  = (unsigned char*)(ws + 4194304);      // 512x2048 fp8
  unsigned short* shortcB = (unsigned short*)(ws + 6291456);     // 50176x512 bf16
  unsigned char*  lnb8    = (unsigned char*)(ws + 109051904);    // 50176x512 fp8
  unsigned char*  qkvb8   = (unsigned char*)(ws + 160432128);    // 50176x1536 fp8
  unsigned char*  attnb8  = (unsigned char*)(ws + 314572800);    // 50176x512 fp8
  unsigned char*  gelub8  = (unsigned char*)(ws + 160432128);    // overlay qkvb8
  unsigned short* h2B     = (unsigned short*)(ws + 314572800);   // overlay attnb8 (dead after proj)

  wtall_kernel<<<12288, 256, 0, stream>>>(qkv_w, proj_w, fc1_w, fc2_w,
                                          qkvwT8, projwT8, fc1wT8, fc2wT8);

  // shortcut = x + dwconv(x) -> bf16 ; fused ln1 -> fp8   (1 wave/pixel)
  cpe_ln_kernel<0><<<dim3(28, 112, BB), 256, 0, stream>>>(x, cpe0_w, cpe0_b,
      ln1_g, ln1_b, shortcB, lnb8);
  // qkv (MX fp8): fp8 out
  gemm8mx_kernel<0, 512><<<dim3(12, 392), 512, 0, stream>>>(lnb8, qkvwT8, qkv_b,
      nullptr, nullptr, qkvb8, NTOK, 1536);
  // window attention, all-fp8
  attn_mfma8_kernel<<<8192, 64, 0, stream>>>(qkvb8, attnb8);
  // h = shortcut + attn@proj_w + b  (fp8 A, bf16 res/out in-place)
  gemm8_kernel<3, 512><<<dim3(4, 196), 512, 0, stream>>>(attnb8, projwT8, proj_b,
      shortcB, shortcB, NTOK, 512);
  // h2 = h + dwconv(h) -> bf16 (ws) ; fused ln2 -> fp8   (1 wave/pixel)
  cpe_ln_kernel<1><<<dim3(28, 112, BB), 256, 0, stream>>>(shortcB, cpe1_w, cpe1_b,
      ln2_g, ln2_b, h2B, lnb8);
  // fc1 (MX fp8): gelu -> fp8
  gemm8mx_kernel<2, 512><<<dim3(16, 392), 512, 0, stream>>>(lnb8, fc1wT8, fc1_b,
      nullptr, nullptr, gelub8, NTOK, 2048);
  // fc2 (MX fp8): out f32 = acc + bias + h2(bf16)
  gemm8mx_kernel<4, 2048><<<dim3(4, 392), 512, 0, stream>>>(gelub8, fc2wT8, fc2_b,
      h2B, out, nullptr, NTOK, 512);
}